// Round 7
// baseline (966.600 us; speedup 1.0000x reference)
//
#include <hip/hip_runtime.h>
#include <math.h>

typedef __attribute__((ext_vector_type(8))) short short8;
typedef __attribute__((ext_vector_type(16))) short short16;
typedef __attribute__((ext_vector_type(4))) short sh4;
typedef __attribute__((ext_vector_type(4))) float floatx4;
typedef __attribute__((ext_vector_type(2))) _Float16 half2v;
typedef unsigned short ush;

__device__ __forceinline__ ush f2bf(float f) {
    unsigned u = __builtin_bit_cast(unsigned, f);
    u += 0x7FFFu + ((u >> 16) & 1u);   // RNE
    return (ush)(u >> 16);
}
__device__ __forceinline__ float bf2f(short s) {
    return __builtin_bit_cast(float, ((unsigned)(ush)s) << 16);
}

// ---------------------------------------------------------------------------
// Weights pre-converted ONCE per launch into bf16 tiles in the EXACT swizzled
// LDS image (R7). perm=1: stage-1 main k = r*4+ci (pad ci==3). perm=2:
// k = r*CIN + ci (NHWC convs: one tap r per 64-k step, contiguous channels).
// ---------------------------------------------------------------------------
#define NWT 10
struct PrepAll {
    const float* src[NWT];
    unsigned int dstOff[NWT];
    int M[NWT], Ktot[NWT], KT[NWT], Mblk[NWT], srcK[NWT], perm[NWT], cin[NWT];
    int startG[NWT + 1];
};

__global__ __launch_bounds__(256) void prep_all_k(PrepAll d, ush* __restrict__ P)
{
    const int t = blockIdx.x * 256 + threadIdx.x;
    if (t >= d.startG[NWT]) return;
    int wi = 0;
#pragma unroll
    for (int i = 1; i < NWT; ++i) wi += (t >= d.startG[i]);
    const int g8   = t - d.startG[wi];
    const int Mblk = d.Mblk[wi];
    const int ksC  = d.KT[wi] >> 6;
    const int g    = g8 & 7;
    int rest = g8 >> 3;
    const int row = rest % Mblk; rest /= Mblk;
    const int ks  = rest % ksC;
    const int mb  = rest / ksC;
    const int kchunk = g ^ (row & 7);
    const int gm  = mb * Mblk + row;
    const int M = d.M[wi], Ktot = d.Ktot[wi], srcK = d.srcK[wi];
    const int prm = d.perm[wi], cin = d.cin[wi];
    const float* __restrict__ src = d.src[wi];
    short8 v;
#pragma unroll
    for (int j = 0; j < 8; ++j) {
        int gk = ks * 64 + kchunk * 8 + j;
        bool ok = (gm < M) && (gk < Ktot);
        int gs = gk;
        if (prm == 1) { int ci = gk & 3, rr = gk >> 2; ok = ok && (ci < 3); gs = ci * 49 + rr; }
        if (prm == 2) { int ci = gk % cin, rr = gk / cin; gs = ci * (Ktot / cin) + rr; }
        float f = ok ? src[(size_t)gm * srcK + gs] : 0.f;
        v[j] = (short)f2bf(f);
    }
    *(short8*)(P + d.dstOff[wi] + (size_t)g8 * 8) = v;
}

// Implicit-GEMM conv on bf16 MFMA. MODE 0 zero-pad / 1 reflect / 2 deform.
// Tile BM=64*MT, BN=64, BK=64; 256 threads = 4 waves.
// R9: LDS meta once/block. R10: NKS K-split. R11: LAYT NHWC. R12: bf16 NHWC
// activations + ZSWZ XCD z-locality.
// R13 (T14 async-STAGE): 1-deep register pipeline for the B-operand.
// LOADB(k+1) (meta read + global loads into scoped regs) is issued right
// after CONVERT(k) consumed the previous set, so load latency spans
// [ds_write, barrier, MFMA, barrier, A-DMA] instead of the critical path.
template<int CIN,int KH,int KW,int STR,int PAD,int H,int W,int HO,int WO,
         int MODE,int MT,int PERM=0,int NKS=1,int LAYT=0,int ONHWC=0,int ZSWZ=0>
__global__ __launch_bounds__(256) void conv_mfma(
    const ush* __restrict__ Aprep,
    const float* __restrict__ X,      // NCHW fp32, or NHWC bf16 when LAYT
    const float* __restrict__ OM,     // [Z][3*Kk][HO][WO] (deform only)
    const float* __restrict__ bias,
    float* __restrict__ Out,          // [Z][M][HO*WO] (or NKS partials / NHWC)
    int M)
{
    constexpr int Kk   = KH*KW;
    constexpr int Ktot = PERM == 1 ? 4*Kk : CIN*Kk;
    constexpr int HWc  = H*W;
    constexpr int HOWO = HO*WO;
    constexpr int KT   = (Ktot + 63) & ~63;
    constexpr int KSC  = KT >> 6;
    constexpr int KSLICE = KT / NKS;
    constexpr bool KGUARD = (Ktot % 64 != 0);
    // live B-path selectors
    constexpr bool BP_L2  = LAYT && (MODE == 2);            // NHWC bf16 deform
    constexpr bool BP_L0  = LAYT && (MODE == 0);            // NHWC bf16 zero-pad
    constexpr bool BP_M2P = (MODE == 2) && (PERM == 1);     // stage-1 deform
    constexpr bool BP_LUT = !LAYT && (MODE == 1 || MODE == 0); // NCHW im2col
    static_assert(BP_L2 || BP_L0 || BP_M2P || BP_LUT, "");
    constexpr bool META2 = BP_L2;                           // packed deform meta
    constexpr bool MLUTB = BP_L0 || BP_LUT;                 // idx LUT
    constexpr int KPAD = (Kk % 2 == 0) ? Kk + 1 : Kk;
    static_assert(KT % (64 * NKS) == 0, "");
    static_assert(PERM != 1 || (MODE == 2 && CIN == 3 && Kk == 49), "");
    static_assert(!LAYT || (CIN % 64 == 0 && Kk == 16), "");
    static_assert(!ONHWC || (MT == 1 && NKS == 1), "");

    // ---- optional XCD-locality remap (bijective; needs gz%8==0, total%8==0)
    int bx = blockIdx.x, by = blockIdx.y, bz = blockIdx.z;
    if constexpr (ZSWZ) {
        const int gx = gridDim.x, gy = gridDim.y, gz = gridDim.z;
        const int gxy = gx * gy;
        int flat = bx + gx * (by + gy * bz);
        int xcd = flat & 7, rank = flat >> 3;
        int zloc = rank / gxy, rem = rank - zloc * gxy;
        bz = xcd * (gz >> 3) + zloc;
        by = rem / gx; bx = rem - (rem / gx) * gx;
    }

    const int z = bz;
    const float* __restrict__ Xb  = LAYT ? nullptr : (X + (size_t)z * CIN * HWc);
    const ush*   __restrict__ Xh  = LAYT ? ((const ush*)X + (size_t)z * CIN * HWc) : nullptr;
    const float* __restrict__ OMb = (MODE == 2) ? (OM + (size_t)z * 3 * Kk * HOWO) : nullptr;

    const int mtiles = gridDim.y / NKS;
    const int my = (NKS > 1) ? (by % mtiles) : by;
    const int ks = (NKS > 1) ? (by / mtiles) : 0;

    float* __restrict__ Outb;
    if constexpr (NKS > 1) {
        const size_t PS = (size_t)gridDim.z * (size_t)M * HOWO;
        Outb = Out + (size_t)ks * PS + (size_t)z * (size_t)M * HOWO;
    } else {
        Outb = Out + (size_t)z * (size_t)M * HOWO;
    }

    const int n0   = bx * 64;
    const int tid  = threadIdx.x;
    const int lane = tid & 63;
    const int wave = tid >> 6;
    const int quad = lane >> 4;
    const int l16  = lane & 15;

    const int bn2 = tid & 63;
    const int bkc = tid >> 6;
    const int gn2 = n0 + bn2;
    const int ho2 = gn2 / WO, wo2 = gn2 % WO;

    // ---- shared memory carve (Ts for ONHWC aliases As+Bs)
    constexpr int AB_BYTES = 64*MT*64*2 + 64*64*2;
    constexpr int TS_BYTES = ONHWC ? 64*64*4 : 0;
    constexpr int BASE_BYTES = AB_BYTES > TS_BYTES ? AB_BYTES : TS_BYTES;
    constexpr int MIB_OFF = BASE_BYTES;
    constexpr int MWH_OFF = MIB_OFF + (META2 ? 64*KPAD*4 : 0);
    constexpr int MI0_OFF = MWH_OFF + (META2 ? 64*KPAD*8 : 0);
    constexpr int SMEM_TOT = MI0_OFF + (MLUTB ? 64*KPAD*4 : 0);
    __shared__ __align__(16) char smem[SMEM_TOT];
    ush (*As)[64] = reinterpret_cast<ush(*)[64]>(smem);
    ush (*Bs)[64] = reinterpret_cast<ush(*)[64]>(smem + 64*MT*64*2);
    int*   MIb = reinterpret_cast<int*>(smem + MIB_OFF);
    uint2* MWh = reinterpret_cast<uint2*>(smem + MWH_OFF);
    int*   MI0 = reinterpret_cast<int*>(smem + MI0_OFF);
    float* Ts  = reinterpret_cast<float*>(smem);

    // ---- one-time LDS meta (deform Kk==16). n = e&63 -> coalesced OM reads.
    if constexpr (META2) {
        for (int e = tid; e < 64 * Kk; e += 256) {
            int n = e & 63, r = e >> 6;
            int gn = n0 + n, ho = gn / WO, wo = gn % WO;
            int ky = r / KW, kx = r % KW;
            float offy = OMb[(size_t)(2 * r) * HOWO + gn];
            float offx = OMb[(size_t)(2 * r + 1) * HOWO + gn];
            float ml   = OMb[(size_t)(2 * Kk + r) * HOWO + gn];
            float mask = 1.f / (1.f + expf(-ml));
            float ys = (float)(ho * STR - PAD + ky) + offy;
            float xs = (float)(wo * STR - PAD + kx) + offx;
            float y0f = floorf(ys), x0f = floorf(xs);
            float dy = ys - y0f, dx = xs - x0f;
            int y0 = (int)y0f, x0 = (int)x0f;
            int yc0 = min(max(y0, 0), H - 1);
            int yc1 = min(max(y0 + 1, 0), H - 1);
            int xc0 = min(max(x0, 0), W - 1);
            int xc1 = min(max(x0 + 1, 0), W - 1);
            bool y0ok = (y0 >= 0) & (y0 < H), y1ok = (y0 + 1 >= 0) & (y0 + 1 < H);
            bool x0ok = (x0 >= 0) & (x0 < W), x1ok = (x0 + 1 >= 0) & (x0 + 1 < W);
            half2v w01, w23;
            w01[0] = (_Float16)((y0ok && x0ok) ? (1.f - dy) * (1.f - dx) * mask : 0.f);
            w01[1] = (_Float16)((y0ok && x1ok) ? (1.f - dy) * dx * mask : 0.f);
            w23[0] = (_Float16)((y1ok && x0ok) ? dy * (1.f - dx) * mask : 0.f);
            w23[1] = (_Float16)((y1ok && x1ok) ? dy * dx * mask : 0.f);
            MIb[n * KPAD + r] = (yc0 * W + xc0) | ((xc1 - xc0) << 24) | ((yc1 - yc0) << 25);
            MWh[n * KPAD + r] = make_uint2(__builtin_bit_cast(unsigned, w01),
                                           __builtin_bit_cast(unsigned, w23));
        }
        __syncthreads();
    }
    if constexpr (MLUTB) {
        for (int e = tid; e < 64 * Kk; e += 256) {
            int n = e & 63, r = e >> 6;
            int gn = n0 + n, ho = gn / WO, wo = gn % WO;
            int ky = r / KW, kx = r % KW;
            int idx;
            if constexpr (MODE == 0) {
                int iy = ho * STR - PAD + ky;
                int ix = wo * STR - PAD + kx;
                idx = (iy >= 0 && iy < H && ix >= 0 && ix < W) ? iy * W + ix : -1;
            } else {
                int iy = ho - PAD + ky; iy = iy < 0 ? -iy : (iy >= H ? 2 * H - 2 - iy : iy);
                int ix = wo - PAD + kx; ix = ix < 0 ? -ix : (ix >= W ? 2 * W - 2 - ix : ix);
                idx = iy * W + ix;
            }
            MI0[n * KPAD + r] = idx;
        }
        __syncthreads();
    }

    floatx4 acc[MT][4];
#pragma unroll
    for (int s = 0; s < MT; ++s)
#pragma unroll
        for (int t = 0; t < 4; ++t) acc[s][t] = (floatx4){0.f, 0.f, 0.f, 0.f};

    // ---- B prefetch register state (1-deep pipeline)
    short16 pb0, pb1, pb2, pb3;            // BP_L2 corners / BP_L0 uses pb0
    unsigned pwx = 0, pwy = 0;             // BP_L2 weights
    int      pidx = 0;                     // BP_L0
    float    pom[BP_M2P ? 12 : 1];
    int      pidxs[BP_LUT ? 16 : 1];
    float    praw[BP_LUT ? 16 : 1];

    auto LOADB = [&](int k0) {
        if constexpr (BP_L2) {
            const int r   = k0 / CIN;                 // wave-uniform
            const int ci0 = (k0 % CIN) + bkc * 16;
            int packed = MIb[bn2 * KPAD + r];
            uint2 ww   = MWh[bn2 * KPAD + r];
            pwx = ww.x; pwy = ww.y;
            int base = packed & 0xFFFFFF;
            int dX = ((packed >> 24) & 1) ? CIN : 0;
            int dY = ((packed >> 25) & 1) ? W * CIN : 0;
            const ush* p00 = Xh + (size_t)base * CIN + ci0;
            pb0 = *(const short16*)(p00);
            pb1 = *(const short16*)(p00 + dX);
            pb2 = *(const short16*)(p00 + dY);
            pb3 = *(const short16*)(p00 + dY + dX);
        } else if constexpr (BP_L0) {
            const int r   = k0 / CIN;
            const int ci0 = (k0 % CIN) + bkc * 16;
            pidx = MI0[bn2 * KPAD + r];
            const ush* p0 = Xh + (size_t)(pidx < 0 ? 0 : pidx) * CIN + ci0;
            pb0 = *(const short16*)p0;
        } else if constexpr (BP_M2P) {
            const int rbase = (k0 + bkc * 16) >> 2;
#pragma unroll
            for (int u = 0; u < 4; ++u) {
                int r = rbase + u;
                if (r < Kk) {
                    pom[u * 3 + 0] = OMb[(size_t)(2 * r) * HOWO + gn2];
                    pom[u * 3 + 1] = OMb[(size_t)(2 * r + 1) * HOWO + gn2];
                    pom[u * 3 + 2] = OMb[(size_t)(2 * Kk + r) * HOWO + gn2];
                }
            }
        } else {   // BP_LUT
#pragma unroll
            for (int j = 0; j < 16; ++j) {
                int gk = k0 + bkc * 16 + j;
                int ci = gk / Kk;
                int r  = gk - ci * Kk;
                int idx = MI0[bn2 * KPAD + r];
                if (KGUARD && gk >= Ktot) idx = -1;
                pidxs[j] = idx;
                praw[j] = Xb[(size_t)ci * HWc + (idx < 0 ? 0 : idx)];
            }
        }
    };

    auto CONVB = [&](int k0, short8& s0, short8& s1) {
        if constexpr (BP_L2) {
            half2v w01 = __builtin_bit_cast(half2v, pwx);
            half2v w23 = __builtin_bit_cast(half2v, pwy);
            float W00 = (float)w01[0], W01 = (float)w01[1];
            float W10 = (float)w23[0], W11 = (float)w23[1];
#pragma unroll
            for (int j = 0; j < 8; ++j) {
                s0[j] = (short)f2bf(W00 * bf2f(pb0[j]) + W01 * bf2f(pb1[j])
                                  + W10 * bf2f(pb2[j]) + W11 * bf2f(pb3[j]));
                s1[j] = (short)f2bf(W00 * bf2f(pb0[8 + j]) + W01 * bf2f(pb1[8 + j])
                                  + W10 * bf2f(pb2[8 + j]) + W11 * bf2f(pb3[8 + j]));
            }
        } else if constexpr (BP_L0) {
            if (pidx < 0) {
#pragma unroll
                for (int j = 0; j < 8; ++j) { s0[j] = 0; s1[j] = 0; }
            } else {
#pragma unroll
                for (int j = 0; j < 8; ++j) { s0[j] = pb0[j]; s1[j] = pb0[8 + j]; }
            }
        } else if constexpr (BP_M2P) {
            ush tmp[16];
            const int rbase = (k0 + bkc * 16) >> 2;
#pragma unroll
            for (int u = 0; u < 4; ++u) {
                const int r = rbase + u;
                float v0 = 0.f, v1 = 0.f, v2 = 0.f;
                if (r < Kk) {
                    const int ky = r / KW, kx = r - ky * KW;
                    float offy = pom[u * 3 + 0];
                    float offx = pom[u * 3 + 1];
                    float ml   = pom[u * 3 + 2];
                    float mask = 1.f / (1.f + expf(-ml));
                    float ys = (float)(ho2 * STR - PAD + ky) + offy;
                    float xs = (float)(wo2 * STR - PAD + kx) + offx;
                    float y0f = floorf(ys), x0f = floorf(xs);
                    float dy = ys - y0f, dx = xs - x0f;
                    int y0 = (int)y0f, x0 = (int)x0f;
                    int yc0 = min(max(y0, 0), H - 1);
                    int yc1 = min(max(y0 + 1, 0), H - 1);
                    int xc0 = min(max(x0, 0), W - 1);
                    int xc1 = min(max(x0 + 1, 0), W - 1);
                    bool y0ok = (y0 >= 0) & (y0 < H), y1ok = (y0 + 1 >= 0) & (y0 + 1 < H);
                    bool x0ok = (x0 >= 0) & (x0 < W), x1ok = (x0 + 1 >= 0) & (x0 + 1 < W);
                    float w00 = (y0ok && x0ok) ? (1.f - dy) * (1.f - dx) * mask : 0.f;
                    float w01 = (y0ok && x1ok) ? (1.f - dy) * dx * mask : 0.f;
                    float w10 = (y1ok && x0ok) ? dy * (1.f - dx) * mask : 0.f;
                    float w11 = (y1ok && x1ok) ? dy * dx * mask : 0.f;
                    int base = yc0 * W + xc0;
                    int dxs  = xc1 - xc0;
                    int dys  = (yc1 - yc0) ? W : 0;
                    float cc[12];
#pragma unroll
                    for (int ci = 0; ci < 3; ++ci) {
                        const float* img = Xb + (size_t)ci * HWc;
                        cc[ci * 4 + 0] = img[base];
                        cc[ci * 4 + 1] = img[base + dxs];
                        cc[ci * 4 + 2] = img[base + dys];
                        cc[ci * 4 + 3] = img[base + dys + dxs];
                    }
                    v0 = w00 * cc[0] + w01 * cc[1] + w10 * cc[2]  + w11 * cc[3];
                    v1 = w00 * cc[4] + w01 * cc[5] + w10 * cc[6]  + w11 * cc[7];
                    v2 = w00 * cc[8] + w01 * cc[9] + w10 * cc[10] + w11 * cc[11];
                }
                tmp[u * 4 + 0] = f2bf(v0);
                tmp[u * 4 + 1] = f2bf(v1);
                tmp[u * 4 + 2] = f2bf(v2);
                tmp[u * 4 + 3] = 0;
            }
#pragma unroll
            for (int j = 0; j < 8; ++j) { s0[j] = (short)tmp[j]; s1[j] = (short)tmp[8 + j]; }
        } else {   // BP_LUT
#pragma unroll
            for (int j = 0; j < 8; ++j) {
                s0[j] = (short)(pidxs[j]     < 0 ? (ush)0 : f2bf(praw[j]));
                s1[j] = (short)(pidxs[8 + j] < 0 ? (ush)0 : f2bf(praw[8 + j]));
            }
        }
    };

    const int kbeg = ks * KSLICE, kend = kbeg + KSLICE;
    LOADB(kbeg);   // prologue (after meta barriers)

    for (int k0 = kbeg; k0 < kend; k0 += 64) {
        // ---- stage A: async DMA from pre-swizzled bf16 tiles (issued first)
        {
            const ush* At =
                Aprep + ((size_t)my * KSC + (k0 >> 6)) * (size_t)(64 * MT * 64);
#pragma unroll
            for (int c = 0; c < 2 * MT; ++c) {
                const int chunk = c * 4 + wave;
                __builtin_amdgcn_global_load_lds(
                    (const __attribute__((address_space(1))) void*)(At + (size_t)chunk * 512 + lane * 8),
                    (__attribute__((address_space(3))) void*)(&As[0][0] + chunk * 512),
                    16, 0, 0);
            }
        }

        // ---- consume prefetched B, then issue next-step loads (T14)
        short8 s0, s1;
        CONVB(k0, s0, s1);
        if (k0 + 64 < kend) LOADB(k0 + 64);
        const int g0 = (bkc * 2)     ^ (bn2 & 7);
        const int g1 = (bkc * 2 + 1) ^ (bn2 & 7);
        *(short8*)&Bs[bn2][g0 * 8] = s0;
        *(short8*)&Bs[bn2][g1 * 8] = s1;
        __syncthreads();

        // ---- MFMA: wave computes MT x 16(m) x 64(n), K=64
        {
            const int mrow = wave * 16 + l16;
#pragma unroll
            for (int kk = 0; kk < 2; ++kk) {
                const int kg = kk * 4 + quad;
                short8 a[MT];
#pragma unroll
                for (int s = 0; s < MT; ++s)
                    a[s] = *(const short8*)&As[s * 64 + mrow][((kg ^ (mrow & 7)) * 8)];
#pragma unroll
                for (int t = 0; t < 4; ++t) {
                    const int ncol = t * 16 + l16;
                    short8 b = *(const short8*)&Bs[ncol][((kg ^ (ncol & 7)) * 8)];
#pragma unroll
                    for (int s = 0; s < MT; ++s)
                        acc[s][t] = __builtin_amdgcn_mfma_f32_16x16x32_bf16(a[s], b, acc[s][t], 0, 0, 0);
                }
            }
        }
        __syncthreads();
    }

    // ---- epilogue
    if constexpr (ONHWC) {
        // LDS transpose -> coalesced NHWC store (M==64, full tile)
#pragma unroll
        for (int t = 0; t < 4; ++t) {
            int n = t * 16 + l16;
#pragma unroll
            for (int i = 0; i < 4; ++i) {
                int m = wave * 16 + quad * 4 + i;
                Ts[n * 64 + (m ^ ((n & 7) << 3))] = acc[0][t][i] + bias[m];
            }
        }
        __syncthreads();
        float* Outc = Out + ((size_t)z * HOWO + n0) * 64;
        for (int e = tid; e < 1024; e += 256) {
            int n = e >> 4, m4 = (e & 15) * 4;
            float4 v = *(float4*)&Ts[n * 64 + (m4 ^ ((n & 7) << 3))];
            *(float4*)(Outc + n * 64 + m4) = v;
        }
    } else {
#pragma unroll
        for (int s = 0; s < MT; ++s) {
#pragma unroll
            for (int t = 0; t < 4; ++t) {
                const int ng = n0 + t * 16 + l16;
#pragma unroll
                for (int i = 0; i < 4; ++i) {
                    int mg = my * (64 * MT) + s * 64 + wave * 16 + quad * 4 + i;
                    if (mg < M) {
                        float v = acc[s][t][i];
                        if constexpr (NKS == 1) v += bias[mg];
                        Outb[(size_t)mg * HOWO + ng] = v;
                    }
                }
            }
        }
    }
}

// Sum NP partial planes (stride PS) + bias -> out. One block per (z,m) row.
template<int NP>
__global__ __launch_bounds__(256) void reduce_bias_k(
    const float* __restrict__ P, size_t PS, const float* __restrict__ bias,
    float* __restrict__ out, int M, int HOWO)
{
    const int bc = blockIdx.x;
    const int m  = bc % M;
    const float b = bias[m];
    const size_t off = (size_t)bc * HOWO;
    for (int i = threadIdx.x * 4; i < HOWO; i += 1024) {
        float4 a = *(const float4*)(P + off + i);
#pragma unroll
        for (int p = 1; p < NP; ++p) {
            float4 c = *(const float4*)(P + (size_t)p * PS + off + i);
            a.x += c.x; a.y += c.y; a.z += c.z; a.w += c.w;
        }
        a.x += b; a.y += b; a.z += b; a.w += b;
        *(float4*)(out + off + i) = a;
    }
}

// NCHW instance norm (per (b,c) over HW); optional ReLU/dual/add-in. float4.
template<bool RELU, bool DUAL, bool ADDIN>
__global__ __launch_bounds__(256) void instnorm_k(
    const float* __restrict__ in, float* __restrict__ out,
    float* __restrict__ out2, int HW)
{
    const int bc = blockIdx.x;
    const float4* p4 = (const float4*)(in + (size_t)bc * HW);
    const int n4 = HW >> 2;
    float s = 0.f, ss = 0.f;
    for (int i = threadIdx.x; i < n4; i += 256) {
        float4 v = p4[i];
        s  += v.x + v.y + v.z + v.w;
        ss += v.x * v.x + v.y * v.y + v.z * v.z + v.w * v.w;
    }
    __shared__ float rs[256], rq[256];
    rs[threadIdx.x] = s; rq[threadIdx.x] = ss;
    __syncthreads();
    for (int o = 128; o > 0; o >>= 1) {
        if (threadIdx.x < o) { rs[threadIdx.x] += rs[threadIdx.x + o]; rq[threadIdx.x] += rq[threadIdx.x + o]; }
        __syncthreads();
    }
    float mean = rs[0] / (float)HW;
    float var  = rq[0] / (float)HW - mean * mean;
    float inv  = rsqrtf(var + 1e-5f);
    float4* q4  = (float4*)(out + (size_t)bc * HW);
    float4* q24 = DUAL ? (float4*)(out2 + (size_t)bc * HW) : nullptr;
    for (int i = threadIdx.x; i < n4; i += 256) {
        float4 v = p4[i];
        v.x = (v.x - mean) * inv; v.y = (v.y - mean) * inv;
        v.z = (v.z - mean) * inv; v.w = (v.w - mean) * inv;
        if (RELU) {
            v.x = fmaxf(v.x, 0.f); v.y = fmaxf(v.y, 0.f);
            v.z = fmaxf(v.z, 0.f); v.w = fmaxf(v.w, 0.f);
        }
        if (ADDIN) {
            float4 o = q4[i];
            o.x += v.x; o.y += v.y; o.z += v.z; o.w += v.w;
            q4[i] = o;
        } else {
            q4[i] = v;
            if (DUAL) q24[i] = v;
        }
    }
}

// NHWC instance-norm stats: per (z, chunk of 1024 hw) partial s/ss per channel.
__global__ __launch_bounds__(256) void in_stats_nhwc(
    const float* __restrict__ X, float2* __restrict__ P, int HW)
{
    const int z = blockIdx.x, chunk = blockIdx.y;
    const int tid = threadIdx.x;
    const int cg = tid & 15, seg = tid >> 4;
    const int c0 = cg * 4;
    float4 s4 = make_float4(0.f, 0.f, 0.f, 0.f);
    float4 q4 = make_float4(0.f, 0.f, 0.f, 0.f);
    const float* base = X + ((size_t)z * HW + chunk * 1024) * 64;
    for (int hw = seg; hw < 1024; hw += 16) {
        float4 v = *(const float4*)(base + (size_t)hw * 64 + c0);
        s4.x += v.x; s4.y += v.y; s4.z += v.z; s4.w += v.w;
        q4.x += v.x * v.x; q4.y += v.y * v.y; q4.z += v.z * v.z; q4.w += v.w * v.w;
    }
    __shared__ float4 rs[256], rq[256];
    rs[tid] = s4; rq[tid] = q4;
    __syncthreads();
    if (tid < 16) {
        float4 S = rs[tid], Q = rq[tid];
        for (int g = 1; g < 16; ++g) {
            float4 a = rs[g * 16 + tid], b = rq[g * 16 + tid];
            S.x += a.x; S.y += a.y; S.z += a.z; S.w += a.w;
            Q.x += b.x; Q.y += b.y; Q.z += b.z; Q.w += b.w;
        }
        float2* po = P + ((size_t)z * 16 + chunk) * 64 + tid * 4;
        po[0] = make_float2(S.x, Q.x);
        po[1] = make_float2(S.y, Q.y);
        po[2] = make_float2(S.z, Q.z);
        po[3] = make_float2(S.w, Q.w);
    }
}

// NHWC normalize + ReLU, fp32 in -> bf16 out. grid (Z, 64 chunks of 256 hw).
__global__ __launch_bounds__(256) void in_norm_nhwc_bf16(
    const float2* __restrict__ P, const float* __restrict__ X,
    ush* __restrict__ Y, int HW)
{
    const int z = blockIdx.x, chunk = blockIdx.y;
    const int tid = threadIdx.x;
    __shared__ float2 mi[64];
    if (tid < 64) {
        float s = 0.f, q = 0.f;
        for (int g = 0; g < 16; ++g) {
            float2 p = P[((size_t)z * 16 + g) * 64 + tid];
            s += p.x; q += p.y;
        }
        float mean = s / (float)HW;
        float var  = q / (float)HW - mean * mean;
        mi[tid] = make_float2(mean, rsqrtf(var + 1e-5f));
    }
    __syncthreads();
    const float* bi = X + ((size_t)z * HW + chunk * 256) * 64;
    ush* bo = Y + ((size_t)z * HW + chunk * 256) * 64;
    for (int e = tid; e < 4096; e += 256) {
        int c0 = (e & 15) * 4;
        float4 v = *(const float4*)(bi + (size_t)e * 4);
        float2 m0 = mi[c0], m1 = mi[c0 + 1], m2 = mi[c0 + 2], m3 = mi[c0 + 3];
        sh4 o;
        o[0] = (short)f2bf(fmaxf((v.x - m0.x) * m0.y, 0.f));
        o[1] = (short)f2bf(fmaxf((v.y - m1.x) * m1.y, 0.f));
        o[2] = (short)f2bf(fmaxf((v.z - m2.x) * m2.y, 0.f));
        o[3] = (short)f2bf(fmaxf((v.w - m3.x) * m3.y, 0.f));
        *(sh4*)(bo + (size_t)e * 4) = o;
    }
}

// Tiled NCHW fp32 [Z][C][HW] -> NHWC bf16 [Z][HW][C]. grid (HW/64, C/64, Z).
__global__ __launch_bounds__(256) void transpose_chw_hwc_bf16(
    const float* __restrict__ src, ush* __restrict__ dst, int C, int HW)
{
    __shared__ float T[64][65];
    const int z = blockIdx.z, cb = blockIdx.y * 64, hb = blockIdx.x * 64;
    const int tid = threadIdx.x;
    for (int e = tid; e < 1024; e += 256) {
        int c = e >> 4, h4 = (e & 15) * 4;
        float4 v = *(const float4*)(src + ((size_t)z * C + cb + c) * HW + hb + h4);
        T[c][h4] = v.x; T[c][h4 + 1] = v.y; T[c][h4 + 2] = v.z; T[c][h4 + 3] = v.w;
    }
    __syncthreads();
    for (int e = tid; e < 1024; e += 256) {
        int h = e >> 4, c4 = (e & 15) * 4;
        sh4 o;
        o[0] = (short)f2bf(T[c4][h]);     o[1] = (short)f2bf(T[c4 + 1][h]);
        o[2] = (short)f2bf(T[c4 + 2][h]); o[3] = (short)f2bf(T[c4 + 3][h]);
        *(sh4*)(dst + ((size_t)z * HW + hb + h) * C + cb + c4) = o;
    }
}

extern "C" void kernel_launch(void* const* d_in, const int* in_sizes, int n_in,
                              void* d_out, int out_size, void* d_ws, size_t ws_size,
                              hipStream_t stream)
{
    const float* x      = (const float*)d_in[0];
    const float* w_off1 = (const float*)d_in[1];
    const float* b_off1 = (const float*)d_in[2];
    const float* w1     = (const float*)d_in[3];
    const float* b1     = (const float*)d_in[4];
    const float* w_off2 = (const float*)d_in[5];
    const float* b_off2 = (const float*)d_in[6];
    const float* w2     = (const float*)d_in[7];
    const float* b2     = (const float*)d_in[8];
    const float* w_off3 = (const float*)d_in[9];
    const float* b_off3 = (const float*)d_in[10];
    const float* w3     = (const float*)d_in[11];
    const float* b3     = (const float*)d_in[12];
    const float* rwa[2] = {(const float*)d_in[13], (const float*)d_in[17]};
    const float* rba[2] = {(const float*)d_in[14], (const float*)d_in[18]};
    const float* rwb[2] = {(const float*)d_in[15], (const float*)d_in[19]};
    const float* rbb[2] = {(const float*)d_in[16], (const float*)d_in[20]};

    float* out   = (float*)d_out;
    float* h_out = out;                         // [16,256,32,32]
    float* skip2 = out + 4194304;               // [16,128,64,64]
    float* skip3 = out + 4194304 + 8388608;     // [16,256,32,32]

    // workspace (floats), time-multiplexed (identical to R12):
    float*  wsf    = (float*)d_ws;
    float*  h1     = wsf;
    float*  om2    = wsf + 8388608;
    ush*    skip2t = (ush*)wsf;
    float*  kp     = wsf + 8388608;
    float*  pool   = wsf + 16777216;
    float*  om1    = pool;
    ush*    h1b    = (ush*)pool;
    float*  om3    = pool + 8388608;
    float*  y1     = pool;
    float*  y2     = pool + 4194304;
    ush*    wprep  = (ush*)(pool + 9633792);
    float2* Pst    = (float2*)(pool + 11272192);

    // ---- Weight prep
    {
        PrepAll pd;
        const float* srcs[NWT] = {w_off1, w1, w_off2, w2, w_off3, w3,
                                  rwa[0], rwb[0], rwa[1], rwb[1]};
        const int Ms  [NWT] = {147, 64, 48, 128, 48, 256, 256, 256, 256, 256};
        const int Kts [NWT] = {147, 196, 1024, 1024, 2048, 2048, 2304, 2304, 2304, 2304};
        const int KTs [NWT] = {192, 256, 1024, 1024, 2048, 2048, 2304, 2304, 2304, 2304};
        const int Mbs [NWT] = {128, 64, 64, 128, 64, 128, 128, 128, 128, 128};
        const int sKs [NWT] = {147, 147, 1024, 1024, 2048, 2048, 2304, 2304, 2304, 2304};
        const int prm [NWT] = {0, 1, 2, 2, 2, 2, 0, 0, 0, 0};
        const int cns [NWT] = {3, 3, 64, 64, 128, 128, 256, 256, 256, 256};
        int sg = 0;
        pd.startG[0] = 0;
        for (int i = 0; i < NWT; ++i) {
            pd.src[i] = srcs[i];
            pd.M[i] = Ms[i]; pd.Ktot[i] = Kts[i]; pd.KT[i] = KTs[i];
            pd.Mblk[i] = Mbs[i]; pd.srcK[i] = sKs[i]; pd.perm[i] = prm[i];
            pd.cin[i] = cns[i];
            pd.dstOff[i] = (unsigned)sg * 8u;
            int mb = (Ms[i] + Mbs[i] - 1) / Mbs[i];
            sg += mb * (KTs[i] >> 6) * Mbs[i] * 8;
            pd.startG[i + 1] = sg;
        }
        prep_all_k<<<dim3((sg + 255) / 256), 256, 0, stream>>>(pd, wprep);
    }
    const ush* pw_off1 = wprep + 0;
    const ush* pw1     = wprep + 49152;
    const ush* pw_off2 = wprep + 65536;
    const ush* pw2     = wprep + 131072;
    const ush* pw_off3 = wprep + 262144;
    const ush* pw3     = wprep + 393216;
    const ush* prwa[2] = {wprep + 917504,  wprep + 2097152};
    const ush* prwb[2] = {wprep + 1507328, wprep + 2686976};

    // ---- Stage 1: 7x7 s1 p3, 3 -> 64ch @128x128; h1 written NHWC fp32
    for (int c = 0; c < 4; ++c) {
        const float* xc = x + (size_t)c * 4 * 3 * 16384;
        conv_mfma<3,7,7,1,3,128,128,128,128,0,2><<<dim3(256, 2, 4), 256, 0, stream>>>(
            pw_off1, xc, nullptr, b_off1, om1, 147);
        conv_mfma<3,7,7,1,3,128,128,128,128,2,1,1,1,0,1><<<dim3(256, 1, 4), 256, 0, stream>>>(
            pw1, xc, om1, b1, h1 + (size_t)c * 4 * 16384 * 64, 64);
    }
    in_stats_nhwc<<<dim3(16, 16), 256, 0, stream>>>(h1, Pst, 16384);
    in_norm_nhwc_bf16<<<dim3(16, 64), 256, 0, stream>>>(Pst, h1, h1b, 16384);

    // ---- Stage 2: 4x4 s2 p1, 64 -> 128ch @64x64 (NHWC bf16 input, z-swizzle)
    conv_mfma<64,4,4,2,1,128,128,64,64,0,1,0,1,1,0,1><<<dim3(64, 1, 16), 256, 0, stream>>>(
        pw_off2, (const float*)h1b, nullptr, b_off2, om2, 48);
    conv_mfma<64,4,4,2,1,128,128,64,64,2,2,0,1,1,0,1><<<dim3(64, 1, 16), 256, 0, stream>>>(
        pw2, (const float*)h1b, om2, b2, skip2, 128);
    instnorm_k<true,false,false><<<16 * 128, 256, 0, stream>>>(skip2, skip2, nullptr, 4096);
    transpose_chw_hwc_bf16<<<dim3(64, 2, 16), 256, 0, stream>>>(skip2, skip2t, 128, 4096);

    // ---- Stage 3: 4x4 s2 p1, 128 -> 256ch @32x32 (NHWC bf16, K-split, z-swz)
    conv_mfma<128,4,4,2,1,64,64,32,32,0,1,0,4,1,0,1><<<dim3(16, 4, 16), 256, 0, stream>>>(
        pw_off3, (const float*)skip2t, nullptr, b_off3, kp, 48);
    reduce_bias_k<4><<<16 * 48, 256, 0, stream>>>(kp, 786432, b_off3, om3, 48, 1024);
    conv_mfma<128,4,4,2,1,64,64,32,32,2,2,0,2,1,0,1><<<dim3(16, 4, 16), 256, 0, stream>>>(
        pw3, (const float*)skip2t, om3, b3, kp, 256);
    reduce_bias_k<2><<<16 * 256, 256, 0, stream>>>(kp, 4194304, b3, skip3, 256, 1024);
    instnorm_k<true,true,false><<<16 * 256, 256, 0, stream>>>(skip3, skip3, h_out, 1024);

    // ---- Residual blocks: reflect 3x3, 256ch @32x32 (NCHW, K-split 2, z-swz)
    for (int r = 0; r < 2; ++r) {
        conv_mfma<256,3,3,1,1,32,32,32,32,1,2,0,2,0,0,1><<<dim3(16, 4, 16), 256, 0, stream>>>(
            prwa[r], h_out, nullptr, rba[r], kp, 256);
        reduce_bias_k<2><<<16 * 256, 256, 0, stream>>>(kp, 4194304, rba[r], y1, 256, 1024);
        instnorm_k<true,false,false><<<16 * 256, 256, 0, stream>>>(y1, y1, nullptr, 1024);
        conv_mfma<256,3,3,1,1,32,32,32,32,1,2,0,2,0,0,1><<<dim3(16, 4, 16), 256, 0, stream>>>(
            prwb[r], y1, nullptr, rbb[r], kp, 256);
        reduce_bias_k<2><<<16 * 256, 256, 0, stream>>>(kp, 4194304, rbb[r], y2, 256, 1024);
        instnorm_k<false,false,true><<<16 * 256, 256, 0, stream>>>(y2, h_out, nullptr, 1024);
    }
}

// Round 8
// 958.189 us; speedup vs baseline: 1.0088x; 1.0088x over previous
//
#include <hip/hip_runtime.h>
#include <math.h>

typedef __attribute__((ext_vector_type(8))) short short8;
typedef __attribute__((ext_vector_type(16))) short short16;
typedef __attribute__((ext_vector_type(4))) short sh4;
typedef __attribute__((ext_vector_type(4))) float floatx4;
typedef __attribute__((ext_vector_type(2))) _Float16 half2v;
typedef unsigned short ush;

__device__ __forceinline__ ush f2bf(float f) {
    unsigned u = __builtin_bit_cast(unsigned, f);
    u += 0x7FFFu + ((u >> 16) & 1u);   // RNE
    return (ush)(u >> 16);
}
__device__ __forceinline__ float bf2f(short s) {
    return __builtin_bit_cast(float, ((unsigned)(ush)s) << 16);
}

// ---------------------------------------------------------------------------
// Weights pre-converted ONCE per launch into bf16 tiles in the EXACT swizzled
// LDS image (R7). perm=1: stage-1 main k = r*4+ci (pad ci==3). perm=2:
// k = r*CIN + ci (NHWC convs: one tap r per 64-k step, contiguous channels).
// ---------------------------------------------------------------------------
#define NWT 10
struct PrepAll {
    const float* src[NWT];
    unsigned int dstOff[NWT];
    int M[NWT], Ktot[NWT], KT[NWT], Mblk[NWT], srcK[NWT], perm[NWT], cin[NWT];
    int startG[NWT + 1];
};

__global__ __launch_bounds__(256) void prep_all_k(PrepAll d, ush* __restrict__ P)
{
    const int t = blockIdx.x * 256 + threadIdx.x;
    if (t >= d.startG[NWT]) return;
    int wi = 0;
#pragma unroll
    for (int i = 1; i < NWT; ++i) wi += (t >= d.startG[i]);
    const int g8   = t - d.startG[wi];
    const int Mblk = d.Mblk[wi];
    const int ksC  = d.KT[wi] >> 6;
    const int g    = g8 & 7;
    int rest = g8 >> 3;
    const int row = rest % Mblk; rest /= Mblk;
    const int ks  = rest % ksC;
    const int mb  = rest / ksC;
    const int kchunk = g ^ (row & 7);
    const int gm  = mb * Mblk + row;
    const int M = d.M[wi], Ktot = d.Ktot[wi], srcK = d.srcK[wi];
    const int prm = d.perm[wi], cin = d.cin[wi];
    const float* __restrict__ src = d.src[wi];
    short8 v;
#pragma unroll
    for (int j = 0; j < 8; ++j) {
        int gk = ks * 64 + kchunk * 8 + j;
        bool ok = (gm < M) && (gk < Ktot);
        int gs = gk;
        if (prm == 1) { int ci = gk & 3, rr = gk >> 2; ok = ok && (ci < 3); gs = ci * 49 + rr; }
        if (prm == 2) { int ci = gk % cin, rr = gk / cin; gs = ci * (Ktot / cin) + rr; }
        float f = ok ? src[(size_t)gm * srcK + gs] : 0.f;
        v[j] = (short)f2bf(f);
    }
    *(short8*)(P + d.dstOff[wi] + (size_t)g8 * 8) = v;
}

// Implicit-GEMM conv on bf16 MFMA. MODE 0 zero-pad / 1 reflect / 2 deform.
// Tile BM=64*MT, BN=64, BK=64; 256 threads = 4 waves.
// R14: counted-vmcnt pipeline for NHWC paths (BP_L2/BP_L0). R13's prefetch was
// defeated by __syncthreads' vmcnt(0) drain; now raw s_barrier + manual
// s_waitcnt vmcnt(NB) keeps the NB B-loads for step k+1 in flight ACROSS the
// barrier and the MFMA phase (NB = 8 deform / 2 zero-pad: exact vmem op count
// of LOADB; A-DMA ops are older so vmcnt(NB) drains them before MFMA reads As).
// BP_M2P / BP_LUT reverted to R12 inline staging (R13's prefetch there cost
// VGPR/occupancy with no cover).
template<int CIN,int KH,int KW,int STR,int PAD,int H,int W,int HO,int WO,
         int MODE,int MT,int PERM=0,int NKS=1,int LAYT=0,int ONHWC=0,int ZSWZ=0>
__global__ __launch_bounds__(256) void conv_mfma(
    const ush* __restrict__ Aprep,
    const float* __restrict__ X,      // NCHW fp32, or NHWC bf16 when LAYT
    const float* __restrict__ OM,     // [Z][3*Kk][HO][WO] (deform only)
    const float* __restrict__ bias,
    float* __restrict__ Out,          // [Z][M][HO*WO] (or NKS partials / NHWC)
    int M)
{
    constexpr int Kk   = KH*KW;
    constexpr int Ktot = PERM == 1 ? 4*Kk : CIN*Kk;
    constexpr int HWc  = H*W;
    constexpr int HOWO = HO*WO;
    constexpr int KT   = (Ktot + 63) & ~63;
    constexpr int KSC  = KT >> 6;
    constexpr int KSLICE = KT / NKS;
    constexpr bool KGUARD = (Ktot % 64 != 0);
    // live B-path selectors
    constexpr bool BP_L2  = LAYT && (MODE == 2);            // NHWC bf16 deform
    constexpr bool BP_L0  = LAYT && (MODE == 0);            // NHWC bf16 zero-pad
    constexpr bool BP_M2P = (MODE == 2) && (PERM == 1);     // stage-1 deform
    constexpr bool BP_LUT = !LAYT && (MODE == 1 || MODE == 0); // NCHW im2col
    static_assert(BP_L2 || BP_L0 || BP_M2P || BP_LUT, "");
    constexpr bool PIPE  = BP_L2 || BP_L0;                  // counted-vmcnt loop
    constexpr bool META2 = BP_L2;                           // packed deform meta
    constexpr bool MLUTB = BP_L0 || BP_LUT;                 // idx LUT
    constexpr int KPAD = (Kk % 2 == 0) ? Kk + 1 : Kk;
    static_assert(KT % (64 * NKS) == 0, "");
    static_assert(PERM != 1 || (MODE == 2 && CIN == 3 && Kk == 49), "");
    static_assert(!LAYT || (CIN % 64 == 0 && Kk == 16), "");
    static_assert(!ONHWC || (MT == 1 && NKS == 1 && !PIPE), "");

    // ---- optional XCD-locality remap (bijective; needs gz%8==0, total%8==0)
    int bx = blockIdx.x, by = blockIdx.y, bz = blockIdx.z;
    if constexpr (ZSWZ) {
        const int gx = gridDim.x, gy = gridDim.y, gz = gridDim.z;
        const int gxy = gx * gy;
        int flat = bx + gx * (by + gy * bz);
        int xcd = flat & 7, rank = flat >> 3;
        int zloc = rank / gxy, rem = rank - zloc * gxy;
        bz = xcd * (gz >> 3) + zloc;
        by = rem / gx; bx = rem - (rem / gx) * gx;
    }

    const int z = bz;
    const float* __restrict__ Xb  = LAYT ? nullptr : (X + (size_t)z * CIN * HWc);
    const ush*   __restrict__ Xh  = LAYT ? ((const ush*)X + (size_t)z * CIN * HWc) : nullptr;
    const float* __restrict__ OMb = (MODE == 2) ? (OM + (size_t)z * 3 * Kk * HOWO) : nullptr;

    const int mtiles = gridDim.y / NKS;
    const int my = (NKS > 1) ? (by % mtiles) : by;
    const int ks = (NKS > 1) ? (by / mtiles) : 0;

    float* __restrict__ Outb;
    if constexpr (NKS > 1) {
        const size_t PS = (size_t)gridDim.z * (size_t)M * HOWO;
        Outb = Out + (size_t)ks * PS + (size_t)z * (size_t)M * HOWO;
    } else {
        Outb = Out + (size_t)z * (size_t)M * HOWO;
    }

    const int n0   = bx * 64;
    const int tid  = threadIdx.x;
    const int lane = tid & 63;
    const int wave = tid >> 6;
    const int quad = lane >> 4;
    const int l16  = lane & 15;

    const int bn2 = tid & 63;
    const int bkc = tid >> 6;
    const int gn2 = n0 + bn2;
    const int ho2 = gn2 / WO, wo2 = gn2 % WO;

    // ---- shared memory carve (Ts for ONHWC aliases As+Bs)
    constexpr int AB_BYTES = 64*MT*64*2 + 64*64*2;
    constexpr int TS_BYTES = ONHWC ? 64*64*4 : 0;
    constexpr int BASE_BYTES = AB_BYTES > TS_BYTES ? AB_BYTES : TS_BYTES;
    constexpr int MIB_OFF = BASE_BYTES;
    constexpr int MWH_OFF = MIB_OFF + (META2 ? 64*KPAD*4 : 0);
    constexpr int MI0_OFF = MWH_OFF + (META2 ? 64*KPAD*8 : 0);
    constexpr int SMEM_TOT = MI0_OFF + (MLUTB ? 64*KPAD*4 : 0);
    __shared__ __align__(16) char smem[SMEM_TOT];
    ush (*As)[64] = reinterpret_cast<ush(*)[64]>(smem);
    ush (*Bs)[64] = reinterpret_cast<ush(*)[64]>(smem + 64*MT*64*2);
    int*   MIb = reinterpret_cast<int*>(smem + MIB_OFF);
    uint2* MWh = reinterpret_cast<uint2*>(smem + MWH_OFF);
    int*   MI0 = reinterpret_cast<int*>(smem + MI0_OFF);
    float* Ts  = reinterpret_cast<float*>(smem);

    // ---- one-time LDS meta (deform Kk==16). n = e&63 -> coalesced OM reads.
    if constexpr (META2) {
        for (int e = tid; e < 64 * Kk; e += 256) {
            int n = e & 63, r = e >> 6;
            int gn = n0 + n, ho = gn / WO, wo = gn % WO;
            int ky = r / KW, kx = r % KW;
            float offy = OMb[(size_t)(2 * r) * HOWO + gn];
            float offx = OMb[(size_t)(2 * r + 1) * HOWO + gn];
            float ml   = OMb[(size_t)(2 * Kk + r) * HOWO + gn];
            float mask = 1.f / (1.f + expf(-ml));
            float ys = (float)(ho * STR - PAD + ky) + offy;
            float xs = (float)(wo * STR - PAD + kx) + offx;
            float y0f = floorf(ys), x0f = floorf(xs);
            float dy = ys - y0f, dx = xs - x0f;
            int y0 = (int)y0f, x0 = (int)x0f;
            int yc0 = min(max(y0, 0), H - 1);
            int yc1 = min(max(y0 + 1, 0), H - 1);
            int xc0 = min(max(x0, 0), W - 1);
            int xc1 = min(max(x0 + 1, 0), W - 1);
            bool y0ok = (y0 >= 0) & (y0 < H), y1ok = (y0 + 1 >= 0) & (y0 + 1 < H);
            bool x0ok = (x0 >= 0) & (x0 < W), x1ok = (x0 + 1 >= 0) & (x0 + 1 < W);
            half2v w01, w23;
            w01[0] = (_Float16)((y0ok && x0ok) ? (1.f - dy) * (1.f - dx) * mask : 0.f);
            w01[1] = (_Float16)((y0ok && x1ok) ? (1.f - dy) * dx * mask : 0.f);
            w23[0] = (_Float16)((y1ok && x0ok) ? dy * (1.f - dx) * mask : 0.f);
            w23[1] = (_Float16)((y1ok && x1ok) ? dy * dx * mask : 0.f);
            MIb[n * KPAD + r] = (yc0 * W + xc0) | ((xc1 - xc0) << 24) | ((yc1 - yc0) << 25);
            MWh[n * KPAD + r] = make_uint2(__builtin_bit_cast(unsigned, w01),
                                           __builtin_bit_cast(unsigned, w23));
        }
        __syncthreads();
    }
    if constexpr (MLUTB) {
        for (int e = tid; e < 64 * Kk; e += 256) {
            int n = e & 63, r = e >> 6;
            int gn = n0 + n, ho = gn / WO, wo = gn % WO;
            int ky = r / KW, kx = r % KW;
            int idx;
            if constexpr (MODE == 0) {
                int iy = ho * STR - PAD + ky;
                int ix = wo * STR - PAD + kx;
                idx = (iy >= 0 && iy < H && ix >= 0 && ix < W) ? iy * W + ix : -1;
            } else {
                int iy = ho - PAD + ky; iy = iy < 0 ? -iy : (iy >= H ? 2 * H - 2 - iy : iy);
                int ix = wo - PAD + kx; ix = ix < 0 ? -ix : (ix >= W ? 2 * W - 2 - ix : ix);
                idx = iy * W + ix;
            }
            MI0[n * KPAD + r] = idx;
        }
        __syncthreads();
    }

    floatx4 acc[MT][4];
#pragma unroll
    for (int s = 0; s < MT; ++s)
#pragma unroll
        for (int t = 0; t < 4; ++t) acc[s][t] = (floatx4){0.f, 0.f, 0.f, 0.f};

    const int kbeg = ks * KSLICE, kend = kbeg + KSLICE;

    // A-DMA helper (issues 2*MT global_load_lds, vmem ops)
    auto ADMA = [&](int k0) {
        const ush* At =
            Aprep + ((size_t)my * KSC + (k0 >> 6)) * (size_t)(64 * MT * 64);
#pragma unroll
        for (int c = 0; c < 2 * MT; ++c) {
            const int chunk = c * 4 + wave;
            __builtin_amdgcn_global_load_lds(
                (const __attribute__((address_space(1))) void*)(At + (size_t)chunk * 512 + lane * 8),
                (__attribute__((address_space(3))) void*)(&As[0][0] + chunk * 512),
                16, 0, 0);
        }
    };

    auto MFMA_PHASE = [&]() {
        const int mrow = wave * 16 + l16;
#pragma unroll
        for (int kk = 0; kk < 2; ++kk) {
            const int kg = kk * 4 + quad;
            short8 a[MT];
#pragma unroll
            for (int s = 0; s < MT; ++s)
                a[s] = *(const short8*)&As[s * 64 + mrow][((kg ^ (mrow & 7)) * 8)];
#pragma unroll
            for (int t = 0; t < 4; ++t) {
                const int ncol = t * 16 + l16;
                short8 b = *(const short8*)&Bs[ncol][((kg ^ (ncol & 7)) * 8)];
#pragma unroll
                for (int s = 0; s < MT; ++s)
                    acc[s][t] = __builtin_amdgcn_mfma_f32_16x16x32_bf16(a[s], b, acc[s][t], 0, 0, 0);
            }
        }
    };

    if constexpr (PIPE) {
        // ---- counted-vmcnt pipeline (NHWC bf16 paths)
        short16 pb0, pb1, pb2, pb3;        // BP_L2 corners / BP_L0 uses pb0
        unsigned pwx = 0, pwy = 0;
        int pidx = 0;

        auto LOADB = [&](int k0) {
            if constexpr (BP_L2) {
                const int r   = k0 / CIN;              // wave-uniform
                const int ci0 = (k0 % CIN) + bkc * 16;
                int packed = MIb[bn2 * KPAD + r];
                uint2 ww   = MWh[bn2 * KPAD + r];
                pwx = ww.x; pwy = ww.y;
                int base = packed & 0xFFFFFF;
                int dX = ((packed >> 24) & 1) ? CIN : 0;
                int dY = ((packed >> 25) & 1) ? W * CIN : 0;
                const ush* p00 = Xh + (size_t)base * CIN + ci0;
                pb0 = *(const short16*)(p00);
                pb1 = *(const short16*)(p00 + dX);
                pb2 = *(const short16*)(p00 + dY);
                pb3 = *(const short16*)(p00 + dY + dX);
            } else {
                const int r   = k0 / CIN;
                const int ci0 = (k0 % CIN) + bkc * 16;
                pidx = MI0[bn2 * KPAD + r];
                const ush* p0 = Xh + (size_t)(pidx < 0 ? 0 : pidx) * CIN + ci0;
                pb0 = *(const short16*)p0;
            }
        };
        auto CONVB = [&](short8& s0, short8& s1) {
            if constexpr (BP_L2) {
                half2v w01 = __builtin_bit_cast(half2v, pwx);
                half2v w23 = __builtin_bit_cast(half2v, pwy);
                float W00 = (float)w01[0], W01 = (float)w01[1];
                float W10 = (float)w23[0], W11 = (float)w23[1];
#pragma unroll
                for (int j = 0; j < 8; ++j) {
                    s0[j] = (short)f2bf(W00 * bf2f(pb0[j]) + W01 * bf2f(pb1[j])
                                      + W10 * bf2f(pb2[j]) + W11 * bf2f(pb3[j]));
                    s1[j] = (short)f2bf(W00 * bf2f(pb0[8 + j]) + W01 * bf2f(pb1[8 + j])
                                      + W10 * bf2f(pb2[8 + j]) + W11 * bf2f(pb3[8 + j]));
                }
            } else {
                if (pidx < 0) {
#pragma unroll
                    for (int j = 0; j < 8; ++j) { s0[j] = 0; s1[j] = 0; }
                } else {
#pragma unroll
                    for (int j = 0; j < 8; ++j) { s0[j] = pb0[j]; s1[j] = pb0[8 + j]; }
                }
            }
        };

        LOADB(kbeg);
        for (int k0 = kbeg; k0 < kend; k0 += 64) {
            ADMA(k0);
            asm volatile("" ::: "memory");          // IR fence: B-loads stay below
            __builtin_amdgcn_sched_barrier(0);      // MIR fence

            short8 s0, s1;
            CONVB(s0, s1);                          // compiler waits pb* itself
            const bool more = (k0 + 64 < kend);
            if (more) LOADB(k0 + 64);               // NB vmem ops, youngest
            const int g0 = (bkc * 2)     ^ (bn2 & 7);
            const int g1 = (bkc * 2 + 1) ^ (bn2 & 7);
            *(short8*)&Bs[bn2][g0 * 8] = s0;
            *(short8*)&Bs[bn2][g1 * 8] = s1;

            // barrier #1: ds_writes visible + A-DMA landed; B(k+1) stays in flight
            if (more) {
                if constexpr (BP_L2)
                    asm volatile("s_waitcnt vmcnt(8) lgkmcnt(0)" ::: "memory");
                else
                    asm volatile("s_waitcnt vmcnt(2) lgkmcnt(0)" ::: "memory");
            } else {
                asm volatile("s_waitcnt vmcnt(0) lgkmcnt(0)" ::: "memory");
            }
            __builtin_amdgcn_sched_barrier(0);
            __builtin_amdgcn_s_barrier();
            __builtin_amdgcn_sched_barrier(0);
            asm volatile("" ::: "memory");

            MFMA_PHASE();

            // barrier #2: own ds_reads complete before Bs/As overwritten
            asm volatile("s_waitcnt lgkmcnt(0)" ::: "memory");
            __builtin_amdgcn_sched_barrier(0);
            __builtin_amdgcn_s_barrier();
            __builtin_amdgcn_sched_barrier(0);
            asm volatile("" ::: "memory");
        }
    } else {
        // ---- R12-style loop (__syncthreads), inline staging
        for (int k0 = kbeg; k0 < kend; k0 += 64) {
            ADMA(k0);
            {
                ush tmp[16];
                if constexpr (BP_M2P) {
                    // stage-1 deform, perm'd K: 4 slots share one r (3 planes + pad)
                    const int kbase = k0 + bkc * 16;
                    const int rbase = kbase >> 2;
#pragma unroll
                    for (int u = 0; u < 4; ++u) {
                        const int r = rbase + u;
                        float v0 = 0.f, v1 = 0.f, v2 = 0.f;
                        if (r < Kk) {
                            const int ky = r / KW, kx = r - ky * KW;
                            float offy = OMb[(size_t)(2 * r) * HOWO + gn2];
                            float offx = OMb[(size_t)(2 * r + 1) * HOWO + gn2];
                            float ml   = OMb[(size_t)(2 * Kk + r) * HOWO + gn2];
                            float mask = 1.f / (1.f + expf(-ml));
                            float ys = (float)(ho2 * STR - PAD + ky) + offy;
                            float xs = (float)(wo2 * STR - PAD + kx) + offx;
                            float y0f = floorf(ys), x0f = floorf(xs);
                            float dy = ys - y0f, dx = xs - x0f;
                            int y0 = (int)y0f, x0 = (int)x0f;
                            int yc0 = min(max(y0, 0), H - 1);
                            int yc1 = min(max(y0 + 1, 0), H - 1);
                            int xc0 = min(max(x0, 0), W - 1);
                            int xc1 = min(max(x0 + 1, 0), W - 1);
                            bool y0ok = (y0 >= 0) & (y0 < H), y1ok = (y0 + 1 >= 0) & (y0 + 1 < H);
                            bool x0ok = (x0 >= 0) & (x0 < W), x1ok = (x0 + 1 >= 0) & (x0 + 1 < W);
                            float w00 = (y0ok && x0ok) ? (1.f - dy) * (1.f - dx) * mask : 0.f;
                            float w01 = (y0ok && x1ok) ? (1.f - dy) * dx * mask : 0.f;
                            float w10 = (y1ok && x0ok) ? dy * (1.f - dx) * mask : 0.f;
                            float w11 = (y1ok && x1ok) ? dy * dx * mask : 0.f;
                            int base = yc0 * W + xc0;
                            int dxs  = xc1 - xc0;
                            int dys  = (yc1 - yc0) ? W : 0;
                            float cc[12];
#pragma unroll
                            for (int ci = 0; ci < 3; ++ci) {
                                const float* img = Xb + (size_t)ci * HWc;
                                cc[ci * 4 + 0] = img[base];
                                cc[ci * 4 + 1] = img[base + dxs];
                                cc[ci * 4 + 2] = img[base + dys];
                                cc[ci * 4 + 3] = img[base + dys + dxs];
                            }
                            v0 = w00 * cc[0] + w01 * cc[1] + w10 * cc[2]  + w11 * cc[3];
                            v1 = w00 * cc[4] + w01 * cc[5] + w10 * cc[6]  + w11 * cc[7];
                            v2 = w00 * cc[8] + w01 * cc[9] + w10 * cc[10] + w11 * cc[11];
                        }
                        tmp[u * 4 + 0] = f2bf(v0);
                        tmp[u * 4 + 1] = f2bf(v1);
                        tmp[u * 4 + 2] = f2bf(v2);
                        tmp[u * 4 + 3] = 0;
                    }
                } else {
                    // BP_LUT: batched idx reads then unconditional clamped gathers
                    int idxs[16];
                    float raw[16];
#pragma unroll
                    for (int j = 0; j < 16; ++j) {
                        int gk = k0 + bkc * 16 + j;
                        int ci = gk / Kk;
                        int r  = gk - ci * Kk;
                        int idx = MI0[bn2 * KPAD + r];
                        if (KGUARD && gk >= Ktot) idx = -1;
                        idxs[j] = idx;
                    }
#pragma unroll
                    for (int j = 0; j < 16; ++j) {
                        int gk = k0 + bkc * 16 + j;
                        int ci = gk / Kk;
                        raw[j] = Xb[(size_t)ci * HWc + (idxs[j] < 0 ? 0 : idxs[j])];
                    }
#pragma unroll
                    for (int j = 0; j < 16; ++j)
                        tmp[j] = idxs[j] < 0 ? (ush)0 : f2bf(raw[j]);
                }
                short8 s0, s1;
#pragma unroll
                for (int j = 0; j < 8; ++j) { s0[j] = (short)tmp[j]; s1[j] = (short)tmp[8 + j]; }
                const int g0 = (bkc * 2)     ^ (bn2 & 7);
                const int g1 = (bkc * 2 + 1) ^ (bn2 & 7);
                *(short8*)&Bs[bn2][g0 * 8] = s0;
                *(short8*)&Bs[bn2][g1 * 8] = s1;
            }
            __syncthreads();
            MFMA_PHASE();
            __syncthreads();
        }
    }

    // ---- epilogue
    if constexpr (ONHWC) {
        // LDS transpose -> coalesced NHWC store (M==64, full tile)
#pragma unroll
        for (int t = 0; t < 4; ++t) {
            int n = t * 16 + l16;
#pragma unroll
            for (int i = 0; i < 4; ++i) {
                int m = wave * 16 + quad * 4 + i;
                Ts[n * 64 + (m ^ ((n & 7) << 3))] = acc[0][t][i] + bias[m];
            }
        }
        __syncthreads();
        float* Outc = Out + ((size_t)z * HOWO + n0) * 64;
        for (int e = tid; e < 1024; e += 256) {
            int n = e >> 4, m4 = (e & 15) * 4;
            float4 v = *(float4*)&Ts[n * 64 + (m4 ^ ((n & 7) << 3))];
            *(float4*)(Outc + n * 64 + m4) = v;
        }
    } else {
#pragma unroll
        for (int s = 0; s < MT; ++s) {
#pragma unroll
            for (int t = 0; t < 4; ++t) {
                const int ng = n0 + t * 16 + l16;
#pragma unroll
                for (int i = 0; i < 4; ++i) {
                    int mg = my * (64 * MT) + s * 64 + wave * 16 + quad * 4 + i;
                    if (mg < M) {
                        float v = acc[s][t][i];
                        if constexpr (NKS == 1) v += bias[mg];
                        Outb[(size_t)mg * HOWO + ng] = v;
                    }
                }
            }
        }
    }
}

// Sum NP partial planes (stride PS) + bias -> out. One block per (z,m) row.
template<int NP>
__global__ __launch_bounds__(256) void reduce_bias_k(
    const float* __restrict__ P, size_t PS, const float* __restrict__ bias,
    float* __restrict__ out, int M, int HOWO)
{
    const int bc = blockIdx.x;
    const int m  = bc % M;
    const float b = bias[m];
    const size_t off = (size_t)bc * HOWO;
    for (int i = threadIdx.x * 4; i < HOWO; i += 1024) {
        float4 a = *(const float4*)(P + off + i);
#pragma unroll
        for (int p = 1; p < NP; ++p) {
            float4 c = *(const float4*)(P + (size_t)p * PS + off + i);
            a.x += c.x; a.y += c.y; a.z += c.z; a.w += c.w;
        }
        a.x += b; a.y += b; a.z += b; a.w += b;
        *(float4*)(out + off + i) = a;
    }
}

// NCHW instance norm (per (b,c) over HW); optional ReLU/dual/add-in. float4.
template<bool RELU, bool DUAL, bool ADDIN>
__global__ __launch_bounds__(256) void instnorm_k(
    const float* __restrict__ in, float* __restrict__ out,
    float* __restrict__ out2, int HW)
{
    const int bc = blockIdx.x;
    const float4* p4 = (const float4*)(in + (size_t)bc * HW);
    const int n4 = HW >> 2;
    float s = 0.f, ss = 0.f;
    for (int i = threadIdx.x; i < n4; i += 256) {
        float4 v = p4[i];
        s  += v.x + v.y + v.z + v.w;
        ss += v.x * v.x + v.y * v.y + v.z * v.z + v.w * v.w;
    }
    __shared__ float rs[256], rq[256];
    rs[threadIdx.x] = s; rq[threadIdx.x] = ss;
    __syncthreads();
    for (int o = 128; o > 0; o >>= 1) {
        if (threadIdx.x < o) { rs[threadIdx.x] += rs[threadIdx.x + o]; rq[threadIdx.x] += rq[threadIdx.x + o]; }
        __syncthreads();
    }
    float mean = rs[0] / (float)HW;
    float var  = rq[0] / (float)HW - mean * mean;
    float inv  = rsqrtf(var + 1e-5f);
    float4* q4  = (float4*)(out + (size_t)bc * HW);
    float4* q24 = DUAL ? (float4*)(out2 + (size_t)bc * HW) : nullptr;
    for (int i = threadIdx.x; i < n4; i += 256) {
        float4 v = p4[i];
        v.x = (v.x - mean) * inv; v.y = (v.y - mean) * inv;
        v.z = (v.z - mean) * inv; v.w = (v.w - mean) * inv;
        if (RELU) {
            v.x = fmaxf(v.x, 0.f); v.y = fmaxf(v.y, 0.f);
            v.z = fmaxf(v.z, 0.f); v.w = fmaxf(v.w, 0.f);
        }
        if (ADDIN) {
            float4 o = q4[i];
            o.x += v.x; o.y += v.y; o.z += v.z; o.w += v.w;
            q4[i] = o;
        } else {
            q4[i] = v;
            if (DUAL) q24[i] = v;
        }
    }
}

// NHWC instance-norm stats: per (z, chunk of 1024 hw) partial s/ss per channel.
__global__ __launch_bounds__(256) void in_stats_nhwc(
    const float* __restrict__ X, float2* __restrict__ P, int HW)
{
    const int z = blockIdx.x, chunk = blockIdx.y;
    const int tid = threadIdx.x;
    const int cg = tid & 15, seg = tid >> 4;
    const int c0 = cg * 4;
    float4 s4 = make_float4(0.f, 0.f, 0.f, 0.f);
    float4 q4 = make_float4(0.f, 0.f, 0.f, 0.f);
    const float* base = X + ((size_t)z * HW + chunk * 1024) * 64;
    for (int hw = seg; hw < 1024; hw += 16) {
        float4 v = *(const float4*)(base + (size_t)hw * 64 + c0);
        s4.x += v.x; s4.y += v.y; s4.z += v.z; s4.w += v.w;
        q4.x += v.x * v.x; q4.y += v.y * v.y; q4.z += v.z * v.z; q4.w += v.w * v.w;
    }
    __shared__ float4 rs[256], rq[256];
    rs[tid] = s4; rq[tid] = q4;
    __syncthreads();
    if (tid < 16) {
        float4 S = rs[tid], Q = rq[tid];
        for (int g = 1; g < 16; ++g) {
            float4 a = rs[g * 16 + tid], b = rq[g * 16 + tid];
            S.x += a.x; S.y += a.y; S.z += a.z; S.w += a.w;
            Q.x += b.x; Q.y += b.y; Q.z += b.z; Q.w += b.w;
        }
        float2* po = P + ((size_t)z * 16 + chunk) * 64 + tid * 4;
        po[0] = make_float2(S.x, Q.x);
        po[1] = make_float2(S.y, Q.y);
        po[2] = make_float2(S.z, Q.z);
        po[3] = make_float2(S.w, Q.w);
    }
}

// NHWC normalize + ReLU, fp32 in -> bf16 out. grid (Z, 64 chunks of 256 hw).
__global__ __launch_bounds__(256) void in_norm_nhwc_bf16(
    const float2* __restrict__ P, const float* __restrict__ X,
    ush* __restrict__ Y, int HW)
{
    const int z = blockIdx.x, chunk = blockIdx.y;
    const int tid = threadIdx.x;
    __shared__ float2 mi[64];
    if (tid < 64) {
        float s = 0.f, q = 0.f;
        for (int g = 0; g < 16; ++g) {
            float2 p = P[((size_t)z * 16 + g) * 64 + tid];
            s += p.x; q += p.y;
        }
        float mean = s / (float)HW;
        float var  = q / (float)HW - mean * mean;
        mi[tid] = make_float2(mean, rsqrtf(var + 1e-5f));
    }
    __syncthreads();
    const float* bi = X + ((size_t)z * HW + chunk * 256) * 64;
    ush* bo = Y + ((size_t)z * HW + chunk * 256) * 64;
    for (int e = tid; e < 4096; e += 256) {
        int c0 = (e & 15) * 4;
        float4 v = *(const float4*)(bi + (size_t)e * 4);
        float2 m0 = mi[c0], m1 = mi[c0 + 1], m2 = mi[c0 + 2], m3 = mi[c0 + 3];
        sh4 o;
        o[0] = (short)f2bf(fmaxf((v.x - m0.x) * m0.y, 0.f));
        o[1] = (short)f2bf(fmaxf((v.y - m1.x) * m1.y, 0.f));
        o[2] = (short)f2bf(fmaxf((v.z - m2.x) * m2.y, 0.f));
        o[3] = (short)f2bf(fmaxf((v.w - m3.x) * m3.y, 0.f));
        *(sh4*)(bo + (size_t)e * 4) = o;
    }
}

// Tiled NCHW fp32 [Z][C][HW] -> NHWC bf16 [Z][HW][C]. grid (HW/64, C/64, Z).
__global__ __launch_bounds__(256) void transpose_chw_hwc_bf16(
    const float* __restrict__ src, ush* __restrict__ dst, int C, int HW)
{
    __shared__ float T[64][65];
    const int z = blockIdx.z, cb = blockIdx.y * 64, hb = blockIdx.x * 64;
    const int tid = threadIdx.x;
    for (int e = tid; e < 1024; e += 256) {
        int c = e >> 4, h4 = (e & 15) * 4;
        float4 v = *(const float4*)(src + ((size_t)z * C + cb + c) * HW + hb + h4);
        T[c][h4] = v.x; T[c][h4 + 1] = v.y; T[c][h4 + 2] = v.z; T[c][h4 + 3] = v.w;
    }
    __syncthreads();
    for (int e = tid; e < 1024; e += 256) {
        int h = e >> 4, c4 = (e & 15) * 4;
        sh4 o;
        o[0] = (short)f2bf(T[c4][h]);     o[1] = (short)f2bf(T[c4 + 1][h]);
        o[2] = (short)f2bf(T[c4 + 2][h]); o[3] = (short)f2bf(T[c4 + 3][h]);
        *(sh4*)(dst + ((size_t)z * HW + hb + h) * C + cb + c4) = o;
    }
}

extern "C" void kernel_launch(void* const* d_in, const int* in_sizes, int n_in,
                              void* d_out, int out_size, void* d_ws, size_t ws_size,
                              hipStream_t stream)
{
    const float* x      = (const float*)d_in[0];
    const float* w_off1 = (const float*)d_in[1];
    const float* b_off1 = (const float*)d_in[2];
    const float* w1     = (const float*)d_in[3];
    const float* b1     = (const float*)d_in[4];
    const float* w_off2 = (const float*)d_in[5];
    const float* b_off2 = (const float*)d_in[6];
    const float* w2     = (const float*)d_in[7];
    const float* b2     = (const float*)d_in[8];
    const float* w_off3 = (const float*)d_in[9];
    const float* b_off3 = (const float*)d_in[10];
    const float* w3     = (const float*)d_in[11];
    const float* b3     = (const float*)d_in[12];
    const float* rwa[2] = {(const float*)d_in[13], (const float*)d_in[17]};
    const float* rba[2] = {(const float*)d_in[14], (const float*)d_in[18]};
    const float* rwb[2] = {(const float*)d_in[15], (const float*)d_in[19]};
    const float* rbb[2] = {(const float*)d_in[16], (const float*)d_in[20]};

    float* out   = (float*)d_out;
    float* h_out = out;                         // [16,256,32,32]
    float* skip2 = out + 4194304;               // [16,128,64,64]
    float* skip3 = out + 4194304 + 8388608;     // [16,256,32,32]

    // workspace (floats), time-multiplexed (identical to R12):
    float*  wsf    = (float*)d_ws;
    float*  h1     = wsf;
    float*  om2    = wsf + 8388608;
    ush*    skip2t = (ush*)wsf;
    float*  kp     = wsf + 8388608;
    float*  pool   = wsf + 16777216;
    float*  om1    = pool;
    ush*    h1b    = (ush*)pool;
    float*  om3    = pool + 8388608;
    float*  y1     = pool;
    float*  y2     = pool + 4194304;
    ush*    wprep  = (ush*)(pool + 9633792);
    float2* Pst    = (float2*)(pool + 11272192);

    // ---- Weight prep
    {
        PrepAll pd;
        const float* srcs[NWT] = {w_off1, w1, w_off2, w2, w_off3, w3,
                                  rwa[0], rwb[0], rwa[1], rwb[1]};
        const int Ms  [NWT] = {147, 64, 48, 128, 48, 256, 256, 256, 256, 256};
        const int Kts [NWT] = {147, 196, 1024, 1024, 2048, 2048, 2304, 2304, 2304, 2304};
        const int KTs [NWT] = {192, 256, 1024, 1024, 2048, 2048, 2304, 2304, 2304, 2304};
        const int Mbs [NWT] = {128, 64, 64, 128, 64, 128, 128, 128, 128, 128};
        const int sKs [NWT] = {147, 147, 1024, 1024, 2048, 2048, 2304, 2304, 2304, 2304};
        const int prm [NWT] = {0, 1, 2, 2, 2, 2, 0, 0, 0, 0};
        const int cns [NWT] = {3, 3, 64, 64, 128, 128, 256, 256, 256, 256};
        int sg = 0;
        pd.startG[0] = 0;
        for (int i = 0; i < NWT; ++i) {
            pd.src[i] = srcs[i];
            pd.M[i] = Ms[i]; pd.Ktot[i] = Kts[i]; pd.KT[i] = KTs[i];
            pd.Mblk[i] = Mbs[i]; pd.srcK[i] = sKs[i]; pd.perm[i] = prm[i];
            pd.cin[i] = cns[i];
            pd.dstOff[i] = (unsigned)sg * 8u;
            int mb = (Ms[i] + Mbs[i] - 1) / Mbs[i];
            sg += mb * (KTs[i] >> 6) * Mbs[i] * 8;
            pd.startG[i + 1] = sg;
        }
        prep_all_k<<<dim3((sg + 255) / 256), 256, 0, stream>>>(pd, wprep);
    }
    const ush* pw_off1 = wprep + 0;
    const ush* pw1     = wprep + 49152;
    const ush* pw_off2 = wprep + 65536;
    const ush* pw2     = wprep + 131072;
    const ush* pw_off3 = wprep + 262144;
    const ush* pw3     = wprep + 393216;
    const ush* prwa[2] = {wprep + 917504,  wprep + 2097152};
    const ush* prwb[2] = {wprep + 1507328, wprep + 2686976};

    // ---- Stage 1: 7x7 s1 p3, 3 -> 64ch @128x128; h1 written NHWC fp32
    for (int c = 0; c < 4; ++c) {
        const float* xc = x + (size_t)c * 4 * 3 * 16384;
        conv_mfma<3,7,7,1,3,128,128,128,128,0,2><<<dim3(256, 2, 4), 256, 0, stream>>>(
            pw_off1, xc, nullptr, b_off1, om1, 147);
        conv_mfma<3,7,7,1,3,128,128,128,128,2,1,1,1,0,1><<<dim3(256, 1, 4), 256, 0, stream>>>(
            pw1, xc, om1, b1, h1 + (size_t)c * 4 * 16384 * 64, 64);
    }
    in_stats_nhwc<<<dim3(16, 16), 256, 0, stream>>>(h1, Pst, 16384);
    in_norm_nhwc_bf16<<<dim3(16, 64), 256, 0, stream>>>(Pst, h1, h1b, 16384);

    // ---- Stage 2: 4x4 s2 p1, 64 -> 128ch @64x64 (NHWC bf16 input, z-swizzle)
    conv_mfma<64,4,4,2,1,128,128,64,64,0,1,0,1,1,0,1><<<dim3(64, 1, 16), 256, 0, stream>>>(
        pw_off2, (const float*)h1b, nullptr, b_off2, om2, 48);
    conv_mfma<64,4,4,2,1,128,128,64,64,2,2,0,1,1,0,1><<<dim3(64, 1, 16), 256, 0, stream>>>(
        pw2, (const float*)h1b, om2, b2, skip2, 128);
    instnorm_k<true,false,false><<<16 * 128, 256, 0, stream>>>(skip2, skip2, nullptr, 4096);
    transpose_chw_hwc_bf16<<<dim3(64, 2, 16), 256, 0, stream>>>(skip2, skip2t, 128, 4096);

    // ---- Stage 3: 4x4 s2 p1, 128 -> 256ch @32x32 (NHWC bf16, K-split, z-swz)
    conv_mfma<128,4,4,2,1,64,64,32,32,0,1,0,4,1,0,1><<<dim3(16, 4, 16), 256, 0, stream>>>(
        pw_off3, (const float*)skip2t, nullptr, b_off3, kp, 48);
    reduce_bias_k<4><<<16 * 48, 256, 0, stream>>>(kp, 786432, b_off3, om3, 48, 1024);
    conv_mfma<128,4,4,2,1,64,64,32,32,2,2,0,2,1,0,1><<<dim3(16, 4, 16), 256, 0, stream>>>(
        pw3, (const float*)skip2t, om3, b3, kp, 256);
    reduce_bias_k<2><<<16 * 256, 256, 0, stream>>>(kp, 4194304, b3, skip3, 256, 1024);
    instnorm_k<true,true,false><<<16 * 256, 256, 0, stream>>>(skip3, skip3, h_out, 1024);

    // ---- Residual blocks: reflect 3x3, 256ch @32x32 (NCHW, K-split 2, z-swz)
    for (int r = 0; r < 2; ++r) {
        conv_mfma<256,3,3,1,1,32,32,32,32,1,2,0,2,0,0,1><<<dim3(16, 4, 16), 256, 0, stream>>>(
            prwa[r], h_out, nullptr, rba[r], kp, 256);
        reduce_bias_k<2><<<16 * 256, 256, 0, stream>>>(kp, 4194304, rba[r], y1, 256, 1024);
        instnorm_k<true,false,false><<<16 * 256, 256, 0, stream>>>(y1, y1, nullptr, 1024);
        conv_mfma<256,3,3,1,1,32,32,32,32,1,2,0,2,0,0,1><<<dim3(16, 4, 16), 256, 0, stream>>>(
            prwb[r], y1, nullptr, rbb[r], kp, 256);
        reduce_bias_k<2><<<16 * 256, 256, 0, stream>>>(kp, 4194304, rbb[r], y2, 256, 1024);
        instnorm_k<false,false,true><<<16 * 256, 256, 0, stream>>>(y2, h_out, nullptr, 1024);
    }
}

// Round 9
// 937.988 us; speedup vs baseline: 1.0305x; 1.0215x over previous
//
#include <hip/hip_runtime.h>
#include <math.h>

typedef __attribute__((ext_vector_type(8))) short short8;
typedef __attribute__((ext_vector_type(16))) short short16;
typedef __attribute__((ext_vector_type(4))) short sh4;
typedef __attribute__((ext_vector_type(4))) float floatx4;
typedef __attribute__((ext_vector_type(2))) _Float16 half2v;
typedef unsigned short ush;

__device__ __forceinline__ ush f2bf(float f) {
    unsigned u = __builtin_bit_cast(unsigned, f);
    u += 0x7FFFu + ((u >> 16) & 1u);   // RNE
    return (ush)(u >> 16);
}
__device__ __forceinline__ float bf2f(short s) {
    return __builtin_bit_cast(float, ((unsigned)(ush)s) << 16);
}

// ---------------------------------------------------------------------------
// Weights pre-converted ONCE per launch into bf16 tiles in the EXACT swizzled
// LDS image (R7). perm=1: stage-1 main k = r*4+ci (pad ci==3). perm=2:
// k = r*CIN + ci (NHWC convs: one tap r per 64-k step, contiguous channels).
// ---------------------------------------------------------------------------
#define NWT 10
struct PrepAll {
    const float* src[NWT];
    unsigned int dstOff[NWT];
    int M[NWT], Ktot[NWT], KT[NWT], Mblk[NWT], srcK[NWT], perm[NWT], cin[NWT];
    int startG[NWT + 1];
};

__global__ __launch_bounds__(256) void prep_all_k(PrepAll d, ush* __restrict__ P)
{
    const int t = blockIdx.x * 256 + threadIdx.x;
    if (t >= d.startG[NWT]) return;
    int wi = 0;
#pragma unroll
    for (int i = 1; i < NWT; ++i) wi += (t >= d.startG[i]);
    const int g8   = t - d.startG[wi];
    const int Mblk = d.Mblk[wi];
    const int ksC  = d.KT[wi] >> 6;
    const int g    = g8 & 7;
    int rest = g8 >> 3;
    const int row = rest % Mblk; rest /= Mblk;
    const int ks  = rest % ksC;
    const int mb  = rest / ksC;
    const int kchunk = g ^ (row & 7);
    const int gm  = mb * Mblk + row;
    const int M = d.M[wi], Ktot = d.Ktot[wi], srcK = d.srcK[wi];
    const int prm = d.perm[wi], cin = d.cin[wi];
    const float* __restrict__ src = d.src[wi];
    short8 v;
#pragma unroll
    for (int j = 0; j < 8; ++j) {
        int gk = ks * 64 + kchunk * 8 + j;
        bool ok = (gm < M) && (gk < Ktot);
        int gs = gk;
        if (prm == 1) { int ci = gk & 3, rr = gk >> 2; ok = ok && (ci < 3); gs = ci * 49 + rr; }
        if (prm == 2) { int ci = gk % cin, rr = gk / cin; gs = ci * (Ktot / cin) + rr; }
        float f = ok ? src[(size_t)gm * srcK + gs] : 0.f;
        v[j] = (short)f2bf(f);
    }
    *(short8*)(P + d.dstOff[wi] + (size_t)g8 * 8) = v;
}

// Implicit-GEMM conv on bf16 MFMA. MODE 0 zero-pad / 1 reflect / 2 deform.
// Tile BM=64*MT, BN=64, BK=64; 256 threads = 4 waves.
// R14: counted-vmcnt pipeline (raw s_barrier + s_waitcnt vmcnt(8)) keeps the
// 8 B-corner loads for step k+1 in flight across the barrier + MFMA phase.
// R15: PIPE restricted to BP_L2 only — wrapping the trivial BP_L0 copy path
// in the fence apparatus regressed it (m141 order-pinning); BP_L0 back to the
// plain __syncthreads loop.
template<int CIN,int KH,int KW,int STR,int PAD,int H,int W,int HO,int WO,
         int MODE,int MT,int PERM=0,int NKS=1,int LAYT=0,int ONHWC=0,int ZSWZ=0>
__global__ __launch_bounds__(256) void conv_mfma(
    const ush* __restrict__ Aprep,
    const float* __restrict__ X,      // NCHW fp32, or NHWC bf16 when LAYT
    const float* __restrict__ OM,     // [Z][3*Kk][HO][WO] (deform only)
    const float* __restrict__ bias,
    float* __restrict__ Out,          // [Z][M][HO*WO] (or NKS partials / NHWC)
    int M)
{
    constexpr int Kk   = KH*KW;
    constexpr int Ktot = PERM == 1 ? 4*Kk : CIN*Kk;
    constexpr int HWc  = H*W;
    constexpr int HOWO = HO*WO;
    constexpr int KT   = (Ktot + 63) & ~63;
    constexpr int KSC  = KT >> 6;
    constexpr int KSLICE = KT / NKS;
    constexpr bool KGUARD = (Ktot % 64 != 0);
    // live B-path selectors
    constexpr bool BP_L2  = LAYT && (MODE == 2);            // NHWC bf16 deform
    constexpr bool BP_L0  = LAYT && (MODE == 0);            // NHWC bf16 zero-pad
    constexpr bool BP_M2P = (MODE == 2) && (PERM == 1);     // stage-1 deform
    constexpr bool BP_LUT = !LAYT && (MODE == 1 || MODE == 0); // NCHW im2col
    static_assert(BP_L2 || BP_L0 || BP_M2P || BP_LUT, "");
    constexpr bool PIPE  = BP_L2;                           // counted-vmcnt loop
    constexpr bool META2 = BP_L2;                           // packed deform meta
    constexpr bool MLUTB = BP_L0 || BP_LUT;                 // idx LUT
    constexpr int KPAD = (Kk % 2 == 0) ? Kk + 1 : Kk;
    static_assert(KT % (64 * NKS) == 0, "");
    static_assert(PERM != 1 || (MODE == 2 && CIN == 3 && Kk == 49), "");
    static_assert(!LAYT || (CIN % 64 == 0 && Kk == 16), "");
    static_assert(!ONHWC || (MT == 1 && NKS == 1 && !PIPE), "");

    // ---- optional XCD-locality remap (bijective; needs gz%8==0, total%8==0)
    int bx = blockIdx.x, by = blockIdx.y, bz = blockIdx.z;
    if constexpr (ZSWZ) {
        const int gx = gridDim.x, gy = gridDim.y, gz = gridDim.z;
        const int gxy = gx * gy;
        int flat = bx + gx * (by + gy * bz);
        int xcd = flat & 7, rank = flat >> 3;
        int zloc = rank / gxy, rem = rank - zloc * gxy;
        bz = xcd * (gz >> 3) + zloc;
        by = rem / gx; bx = rem - (rem / gx) * gx;
    }

    const int z = bz;
    const float* __restrict__ Xb  = LAYT ? nullptr : (X + (size_t)z * CIN * HWc);
    const ush*   __restrict__ Xh  = LAYT ? ((const ush*)X + (size_t)z * CIN * HWc) : nullptr;
    const float* __restrict__ OMb = (MODE == 2) ? (OM + (size_t)z * 3 * Kk * HOWO) : nullptr;

    const int mtiles = gridDim.y / NKS;
    const int my = (NKS > 1) ? (by % mtiles) : by;
    const int ks = (NKS > 1) ? (by / mtiles) : 0;

    float* __restrict__ Outb;
    if constexpr (NKS > 1) {
        const size_t PS = (size_t)gridDim.z * (size_t)M * HOWO;
        Outb = Out + (size_t)ks * PS + (size_t)z * (size_t)M * HOWO;
    } else {
        Outb = Out + (size_t)z * (size_t)M * HOWO;
    }

    const int n0   = bx * 64;
    const int tid  = threadIdx.x;
    const int lane = tid & 63;
    const int wave = tid >> 6;
    const int quad = lane >> 4;
    const int l16  = lane & 15;

    const int bn2 = tid & 63;
    const int bkc = tid >> 6;
    const int gn2 = n0 + bn2;
    const int ho2 = gn2 / WO, wo2 = gn2 % WO;

    // ---- shared memory carve (Ts for ONHWC aliases As+Bs)
    constexpr int AB_BYTES = 64*MT*64*2 + 64*64*2;
    constexpr int TS_BYTES = ONHWC ? 64*64*4 : 0;
    constexpr int BASE_BYTES = AB_BYTES > TS_BYTES ? AB_BYTES : TS_BYTES;
    constexpr int MIB_OFF = BASE_BYTES;
    constexpr int MWH_OFF = MIB_OFF + (META2 ? 64*KPAD*4 : 0);
    constexpr int MI0_OFF = MWH_OFF + (META2 ? 64*KPAD*8 : 0);
    constexpr int SMEM_TOT = MI0_OFF + (MLUTB ? 64*KPAD*4 : 0);
    __shared__ __align__(16) char smem[SMEM_TOT];
    ush (*As)[64] = reinterpret_cast<ush(*)[64]>(smem);
    ush (*Bs)[64] = reinterpret_cast<ush(*)[64]>(smem + 64*MT*64*2);
    int*   MIb = reinterpret_cast<int*>(smem + MIB_OFF);
    uint2* MWh = reinterpret_cast<uint2*>(smem + MWH_OFF);
    int*   MI0 = reinterpret_cast<int*>(smem + MI0_OFF);
    float* Ts  = reinterpret_cast<float*>(smem);

    // ---- one-time LDS meta (deform Kk==16). n = e&63 -> coalesced OM reads.
    if constexpr (META2) {
        for (int e = tid; e < 64 * Kk; e += 256) {
            int n = e & 63, r = e >> 6;
            int gn = n0 + n, ho = gn / WO, wo = gn % WO;
            int ky = r / KW, kx = r % KW;
            float offy = OMb[(size_t)(2 * r) * HOWO + gn];
            float offx = OMb[(size_t)(2 * r + 1) * HOWO + gn];
            float ml   = OMb[(size_t)(2 * Kk + r) * HOWO + gn];
            float mask = 1.f / (1.f + expf(-ml));
            float ys = (float)(ho * STR - PAD + ky) + offy;
            float xs = (float)(wo * STR - PAD + kx) + offx;
            float y0f = floorf(ys), x0f = floorf(xs);
            float dy = ys - y0f, dx = xs - x0f;
            int y0 = (int)y0f, x0 = (int)x0f;
            int yc0 = min(max(y0, 0), H - 1);
            int yc1 = min(max(y0 + 1, 0), H - 1);
            int xc0 = min(max(x0, 0), W - 1);
            int xc1 = min(max(x0 + 1, 0), W - 1);
            bool y0ok = (y0 >= 0) & (y0 < H), y1ok = (y0 + 1 >= 0) & (y0 + 1 < H);
            bool x0ok = (x0 >= 0) & (x0 < W), x1ok = (x0 + 1 >= 0) & (x0 + 1 < W);
            half2v w01, w23;
            w01[0] = (_Float16)((y0ok && x0ok) ? (1.f - dy) * (1.f - dx) * mask : 0.f);
            w01[1] = (_Float16)((y0ok && x1ok) ? (1.f - dy) * dx * mask : 0.f);
            w23[0] = (_Float16)((y1ok && x0ok) ? dy * (1.f - dx) * mask : 0.f);
            w23[1] = (_Float16)((y1ok && x1ok) ? dy * dx * mask : 0.f);
            MIb[n * KPAD + r] = (yc0 * W + xc0) | ((xc1 - xc0) << 24) | ((yc1 - yc0) << 25);
            MWh[n * KPAD + r] = make_uint2(__builtin_bit_cast(unsigned, w01),
                                           __builtin_bit_cast(unsigned, w23));
        }
        __syncthreads();
    }
    if constexpr (MLUTB) {
        for (int e = tid; e < 64 * Kk; e += 256) {
            int n = e & 63, r = e >> 6;
            int gn = n0 + n, ho = gn / WO, wo = gn % WO;
            int ky = r / KW, kx = r % KW;
            int idx;
            if constexpr (MODE == 0) {
                int iy = ho * STR - PAD + ky;
                int ix = wo * STR - PAD + kx;
                idx = (iy >= 0 && iy < H && ix >= 0 && ix < W) ? iy * W + ix : -1;
            } else {
                int iy = ho - PAD + ky; iy = iy < 0 ? -iy : (iy >= H ? 2 * H - 2 - iy : iy);
                int ix = wo - PAD + kx; ix = ix < 0 ? -ix : (ix >= W ? 2 * W - 2 - ix : ix);
                idx = iy * W + ix;
            }
            MI0[n * KPAD + r] = idx;
        }
        __syncthreads();
    }

    floatx4 acc[MT][4];
#pragma unroll
    for (int s = 0; s < MT; ++s)
#pragma unroll
        for (int t = 0; t < 4; ++t) acc[s][t] = (floatx4){0.f, 0.f, 0.f, 0.f};

    const int kbeg = ks * KSLICE, kend = kbeg + KSLICE;

    // A-DMA helper (issues 2*MT global_load_lds, vmem ops)
    auto ADMA = [&](int k0) {
        const ush* At =
            Aprep + ((size_t)my * KSC + (k0 >> 6)) * (size_t)(64 * MT * 64);
#pragma unroll
        for (int c = 0; c < 2 * MT; ++c) {
            const int chunk = c * 4 + wave;
            __builtin_amdgcn_global_load_lds(
                (const __attribute__((address_space(1))) void*)(At + (size_t)chunk * 512 + lane * 8),
                (__attribute__((address_space(3))) void*)(&As[0][0] + chunk * 512),
                16, 0, 0);
        }
    };

    auto MFMA_PHASE = [&]() {
        const int mrow = wave * 16 + l16;
#pragma unroll
        for (int kk = 0; kk < 2; ++kk) {
            const int kg = kk * 4 + quad;
            short8 a[MT];
#pragma unroll
            for (int s = 0; s < MT; ++s)
                a[s] = *(const short8*)&As[s * 64 + mrow][((kg ^ (mrow & 7)) * 8)];
#pragma unroll
            for (int t = 0; t < 4; ++t) {
                const int ncol = t * 16 + l16;
                short8 b = *(const short8*)&Bs[ncol][((kg ^ (ncol & 7)) * 8)];
#pragma unroll
                for (int s = 0; s < MT; ++s)
                    acc[s][t] = __builtin_amdgcn_mfma_f32_16x16x32_bf16(a[s], b, acc[s][t], 0, 0, 0);
            }
        }
    };

    if constexpr (PIPE) {
        // ---- counted-vmcnt pipeline (NHWC bf16 deform)
        short16 pb0, pb1, pb2, pb3;
        unsigned pwx = 0, pwy = 0;

        auto LOADB = [&](int k0) {
            const int r   = k0 / CIN;              // wave-uniform
            const int ci0 = (k0 % CIN) + bkc * 16;
            int packed = MIb[bn2 * KPAD + r];
            uint2 ww   = MWh[bn2 * KPAD + r];
            pwx = ww.x; pwy = ww.y;
            int base = packed & 0xFFFFFF;
            int dX = ((packed >> 24) & 1) ? CIN : 0;
            int dY = ((packed >> 25) & 1) ? W * CIN : 0;
            const ush* p00 = Xh + (size_t)base * CIN + ci0;
            pb0 = *(const short16*)(p00);
            pb1 = *(const short16*)(p00 + dX);
            pb2 = *(const short16*)(p00 + dY);
            pb3 = *(const short16*)(p00 + dY + dX);
        };
        auto CONVB = [&](short8& s0, short8& s1) {
            half2v w01 = __builtin_bit_cast(half2v, pwx);
            half2v w23 = __builtin_bit_cast(half2v, pwy);
            float W00 = (float)w01[0], W01 = (float)w01[1];
            float W10 = (float)w23[0], W11 = (float)w23[1];
#pragma unroll
            for (int j = 0; j < 8; ++j) {
                s0[j] = (short)f2bf(W00 * bf2f(pb0[j]) + W01 * bf2f(pb1[j])
                                  + W10 * bf2f(pb2[j]) + W11 * bf2f(pb3[j]));
                s1[j] = (short)f2bf(W00 * bf2f(pb0[8 + j]) + W01 * bf2f(pb1[8 + j])
                                  + W10 * bf2f(pb2[8 + j]) + W11 * bf2f(pb3[8 + j]));
            }
        };

        LOADB(kbeg);
        for (int k0 = kbeg; k0 < kend; k0 += 64) {
            ADMA(k0);
            asm volatile("" ::: "memory");          // IR fence: B-loads stay below
            __builtin_amdgcn_sched_barrier(0);      // MIR fence

            short8 s0, s1;
            CONVB(s0, s1);                          // compiler waits pb* itself
            const bool more = (k0 + 64 < kend);
            if (more) LOADB(k0 + 64);               // 8 vmem ops, youngest
            const int g0 = (bkc * 2)     ^ (bn2 & 7);
            const int g1 = (bkc * 2 + 1) ^ (bn2 & 7);
            *(short8*)&Bs[bn2][g0 * 8] = s0;
            *(short8*)&Bs[bn2][g1 * 8] = s1;

            // barrier #1: ds_writes visible + A-DMA landed; B(k+1) stays in flight
            if (more)
                asm volatile("s_waitcnt vmcnt(8) lgkmcnt(0)" ::: "memory");
            else
                asm volatile("s_waitcnt vmcnt(0) lgkmcnt(0)" ::: "memory");
            __builtin_amdgcn_sched_barrier(0);
            __builtin_amdgcn_s_barrier();
            __builtin_amdgcn_sched_barrier(0);
            asm volatile("" ::: "memory");

            MFMA_PHASE();

            // barrier #2: own ds_reads complete before Bs/As overwritten
            asm volatile("s_waitcnt lgkmcnt(0)" ::: "memory");
            __builtin_amdgcn_sched_barrier(0);
            __builtin_amdgcn_s_barrier();
            __builtin_amdgcn_sched_barrier(0);
            asm volatile("" ::: "memory");
        }
    } else {
        // ---- plain loop (__syncthreads), inline staging
        for (int k0 = kbeg; k0 < kend; k0 += 64) {
            ADMA(k0);
            {
                short8 s0, s1;
                if constexpr (BP_L0) {
                    // NHWC bf16 zero-pad: direct copy, one dwordx4
                    const int r   = k0 / CIN;
                    const int ci0 = (k0 % CIN) + bkc * 16;
                    int idx = MI0[bn2 * KPAD + r];
                    const ush* p0 = Xh + (size_t)(idx < 0 ? 0 : idx) * CIN + ci0;
                    short16 v = *(const short16*)p0;
#pragma unroll
                    for (int j = 0; j < 8; ++j) { s0[j] = v[j]; s1[j] = v[8 + j]; }
                    if (idx < 0) {
#pragma unroll
                        for (int j = 0; j < 8; ++j) { s0[j] = 0; s1[j] = 0; }
                    }
                } else if constexpr (BP_M2P) {
                    // stage-1 deform, perm'd K: 4 slots share one r (3 planes + pad)
                    ush tmp[16];
                    const int kbase = k0 + bkc * 16;
                    const int rbase = kbase >> 2;
#pragma unroll
                    for (int u = 0; u < 4; ++u) {
                        const int r = rbase + u;
                        float v0 = 0.f, v1 = 0.f, v2 = 0.f;
                        if (r < Kk) {
                            const int ky = r / KW, kx = r - ky * KW;
                            float offy = OMb[(size_t)(2 * r) * HOWO + gn2];
                            float offx = OMb[(size_t)(2 * r + 1) * HOWO + gn2];
                            float ml   = OMb[(size_t)(2 * Kk + r) * HOWO + gn2];
                            float mask = 1.f / (1.f + expf(-ml));
                            float ys = (float)(ho2 * STR - PAD + ky) + offy;
                            float xs = (float)(wo2 * STR - PAD + kx) + offx;
                            float y0f = floorf(ys), x0f = floorf(xs);
                            float dy = ys - y0f, dx = xs - x0f;
                            int y0 = (int)y0f, x0 = (int)x0f;
                            int yc0 = min(max(y0, 0), H - 1);
                            int yc1 = min(max(y0 + 1, 0), H - 1);
                            int xc0 = min(max(x0, 0), W - 1);
                            int xc1 = min(max(x0 + 1, 0), W - 1);
                            bool y0ok = (y0 >= 0) & (y0 < H), y1ok = (y0 + 1 >= 0) & (y0 + 1 < H);
                            bool x0ok = (x0 >= 0) & (x0 < W), x1ok = (x0 + 1 >= 0) & (x0 + 1 < W);
                            float w00 = (y0ok && x0ok) ? (1.f - dy) * (1.f - dx) * mask : 0.f;
                            float w01 = (y0ok && x1ok) ? (1.f - dy) * dx * mask : 0.f;
                            float w10 = (y1ok && x0ok) ? dy * (1.f - dx) * mask : 0.f;
                            float w11 = (y1ok && x1ok) ? dy * dx * mask : 0.f;
                            int base = yc0 * W + xc0;
                            int dxs  = xc1 - xc0;
                            int dys  = (yc1 - yc0) ? W : 0;
                            float cc[12];
#pragma unroll
                            for (int ci = 0; ci < 3; ++ci) {
                                const float* img = Xb + (size_t)ci * HWc;
                                cc[ci * 4 + 0] = img[base];
                                cc[ci * 4 + 1] = img[base + dxs];
                                cc[ci * 4 + 2] = img[base + dys];
                                cc[ci * 4 + 3] = img[base + dys + dxs];
                            }
                            v0 = w00 * cc[0] + w01 * cc[1] + w10 * cc[2]  + w11 * cc[3];
                            v1 = w00 * cc[4] + w01 * cc[5] + w10 * cc[6]  + w11 * cc[7];
                            v2 = w00 * cc[8] + w01 * cc[9] + w10 * cc[10] + w11 * cc[11];
                        }
                        tmp[u * 4 + 0] = f2bf(v0);
                        tmp[u * 4 + 1] = f2bf(v1);
                        tmp[u * 4 + 2] = f2bf(v2);
                        tmp[u * 4 + 3] = 0;
                    }
#pragma unroll
                    for (int j = 0; j < 8; ++j) { s0[j] = (short)tmp[j]; s1[j] = (short)tmp[8 + j]; }
                } else {
                    // BP_LUT: batched idx reads then unconditional clamped gathers
                    ush tmp[16];
                    int idxs[16];
                    float raw[16];
#pragma unroll
                    for (int j = 0; j < 16; ++j) {
                        int gk = k0 + bkc * 16 + j;
                        int ci = gk / Kk;
                        int r  = gk - ci * Kk;
                        int idx = MI0[bn2 * KPAD + r];
                        if (KGUARD && gk >= Ktot) idx = -1;
                        idxs[j] = idx;
                    }
#pragma unroll
                    for (int j = 0; j < 16; ++j) {
                        int gk = k0 + bkc * 16 + j;
                        int ci = gk / Kk;
                        raw[j] = Xb[(size_t)ci * HWc + (idxs[j] < 0 ? 0 : idxs[j])];
                    }
#pragma unroll
                    for (int j = 0; j < 16; ++j)
                        tmp[j] = idxs[j] < 0 ? (ush)0 : f2bf(raw[j]);
#pragma unroll
                    for (int j = 0; j < 8; ++j) { s0[j] = (short)tmp[j]; s1[j] = (short)tmp[8 + j]; }
                }
                const int g0 = (bkc * 2)     ^ (bn2 & 7);
                const int g1 = (bkc * 2 + 1) ^ (bn2 & 7);
                *(short8*)&Bs[bn2][g0 * 8] = s0;
                *(short8*)&Bs[bn2][g1 * 8] = s1;
            }
            __syncthreads();
            MFMA_PHASE();
            __syncthreads();
        }
    }

    // ---- epilogue
    if constexpr (ONHWC) {
        // LDS transpose -> coalesced NHWC store (M==64, full tile)
#pragma unroll
        for (int t = 0; t < 4; ++t) {
            int n = t * 16 + l16;
#pragma unroll
            for (int i = 0; i < 4; ++i) {
                int m = wave * 16 + quad * 4 + i;
                Ts[n * 64 + (m ^ ((n & 7) << 3))] = acc[0][t][i] + bias[m];
            }
        }
        __syncthreads();
        float* Outc = Out + ((size_t)z * HOWO + n0) * 64;
        for (int e = tid; e < 1024; e += 256) {
            int n = e >> 4, m4 = (e & 15) * 4;
            float4 v = *(float4*)&Ts[n * 64 + (m4 ^ ((n & 7) << 3))];
            *(float4*)(Outc + n * 64 + m4) = v;
        }
    } else {
#pragma unroll
        for (int s = 0; s < MT; ++s) {
#pragma unroll
            for (int t = 0; t < 4; ++t) {
                const int ng = n0 + t * 16 + l16;
#pragma unroll
                for (int i = 0; i < 4; ++i) {
                    int mg = my * (64 * MT) + s * 64 + wave * 16 + quad * 4 + i;
                    if (mg < M) {
                        float v = acc[s][t][i];
                        if constexpr (NKS == 1) v += bias[mg];
                        Outb[(size_t)mg * HOWO + ng] = v;
                    }
                }
            }
        }
    }
}

// Sum NP partial planes (stride PS) + bias -> out. One block per (z,m) row.
template<int NP>
__global__ __launch_bounds__(256) void reduce_bias_k(
    const float* __restrict__ P, size_t PS, const float* __restrict__ bias,
    float* __restrict__ out, int M, int HOWO)
{
    const int bc = blockIdx.x;
    const int m  = bc % M;
    const float b = bias[m];
    const size_t off = (size_t)bc * HOWO;
    for (int i = threadIdx.x * 4; i < HOWO; i += 1024) {
        float4 a = *(const float4*)(P + off + i);
#pragma unroll
        for (int p = 1; p < NP; ++p) {
            float4 c = *(const float4*)(P + (size_t)p * PS + off + i);
            a.x += c.x; a.y += c.y; a.z += c.z; a.w += c.w;
        }
        a.x += b; a.y += b; a.z += b; a.w += b;
        *(float4*)(out + off + i) = a;
    }
}

// NCHW instance norm (per (b,c) over HW); optional ReLU/dual/add-in. float4.
template<bool RELU, bool DUAL, bool ADDIN>
__global__ __launch_bounds__(256) void instnorm_k(
    const float* __restrict__ in, float* __restrict__ out,
    float* __restrict__ out2, int HW)
{
    const int bc = blockIdx.x;
    const float4* p4 = (const float4*)(in + (size_t)bc * HW);
    const int n4 = HW >> 2;
    float s = 0.f, ss = 0.f;
    for (int i = threadIdx.x; i < n4; i += 256) {
        float4 v = p4[i];
        s  += v.x + v.y + v.z + v.w;
        ss += v.x * v.x + v.y * v.y + v.z * v.z + v.w * v.w;
    }
    __shared__ float rs[256], rq[256];
    rs[threadIdx.x] = s; rq[threadIdx.x] = ss;
    __syncthreads();
    for (int o = 128; o > 0; o >>= 1) {
        if (threadIdx.x < o) { rs[threadIdx.x] += rs[threadIdx.x + o]; rq[threadIdx.x] += rq[threadIdx.x + o]; }
        __syncthreads();
    }
    float mean = rs[0] / (float)HW;
    float var  = rq[0] / (float)HW - mean * mean;
    float inv  = rsqrtf(var + 1e-5f);
    float4* q4  = (float4*)(out + (size_t)bc * HW);
    float4* q24 = DUAL ? (float4*)(out2 + (size_t)bc * HW) : nullptr;
    for (int i = threadIdx.x; i < n4; i += 256) {
        float4 v = p4[i];
        v.x = (v.x - mean) * inv; v.y = (v.y - mean) * inv;
        v.z = (v.z - mean) * inv; v.w = (v.w - mean) * inv;
        if (RELU) {
            v.x = fmaxf(v.x, 0.f); v.y = fmaxf(v.y, 0.f);
            v.z = fmaxf(v.z, 0.f); v.w = fmaxf(v.w, 0.f);
        }
        if (ADDIN) {
            float4 o = q4[i];
            o.x += v.x; o.y += v.y; o.z += v.z; o.w += v.w;
            q4[i] = o;
        } else {
            q4[i] = v;
            if (DUAL) q24[i] = v;
        }
    }
}

// NHWC instance-norm stats: per (z, chunk of 1024 hw) partial s/ss per channel.
__global__ __launch_bounds__(256) void in_stats_nhwc(
    const float* __restrict__ X, float2* __restrict__ P, int HW)
{
    const int z = blockIdx.x, chunk = blockIdx.y;
    const int tid = threadIdx.x;
    const int cg = tid & 15, seg = tid >> 4;
    const int c0 = cg * 4;
    float4 s4 = make_float4(0.f, 0.f, 0.f, 0.f);
    float4 q4 = make_float4(0.f, 0.f, 0.f, 0.f);
    const float* base = X + ((size_t)z * HW + chunk * 1024) * 64;
    for (int hw = seg; hw < 1024; hw += 16) {
        float4 v = *(const float4*)(base + (size_t)hw * 64 + c0);
        s4.x += v.x; s4.y += v.y; s4.z += v.z; s4.w += v.w;
        q4.x += v.x * v.x; q4.y += v.y * v.y; q4.z += v.z * v.z; q4.w += v.w * v.w;
    }
    __shared__ float4 rs[256], rq[256];
    rs[tid] = s4; rq[tid] = q4;
    __syncthreads();
    if (tid < 16) {
        float4 S = rs[tid], Q = rq[tid];
        for (int g = 1; g < 16; ++g) {
            float4 a = rs[g * 16 + tid], b = rq[g * 16 + tid];
            S.x += a.x; S.y += a.y; S.z += a.z; S.w += a.w;
            Q.x += b.x; Q.y += b.y; Q.z += b.z; Q.w += b.w;
        }
        float2* po = P + ((size_t)z * 16 + chunk) * 64 + tid * 4;
        po[0] = make_float2(S.x, Q.x);
        po[1] = make_float2(S.y, Q.y);
        po[2] = make_float2(S.z, Q.z);
        po[3] = make_float2(S.w, Q.w);
    }
}

// NHWC normalize + ReLU, fp32 in -> bf16 out. grid (Z, 64 chunks of 256 hw).
__global__ __launch_bounds__(256) void in_norm_nhwc_bf16(
    const float2* __restrict__ P, const float* __restrict__ X,
    ush* __restrict__ Y, int HW)
{
    const int z = blockIdx.x, chunk = blockIdx.y;
    const int tid = threadIdx.x;
    __shared__ float2 mi[64];
    if (tid < 64) {
        float s = 0.f, q = 0.f;
        for (int g = 0; g < 16; ++g) {
            float2 p = P[((size_t)z * 16 + g) * 64 + tid];
            s += p.x; q += p.y;
        }
        float mean = s / (float)HW;
        float var  = q / (float)HW - mean * mean;
        mi[tid] = make_float2(mean, rsqrtf(var + 1e-5f));
    }
    __syncthreads();
    const float* bi = X + ((size_t)z * HW + chunk * 256) * 64;
    ush* bo = Y + ((size_t)z * HW + chunk * 256) * 64;
    for (int e = tid; e < 4096; e += 256) {
        int c0 = (e & 15) * 4;
        float4 v = *(const float4*)(bi + (size_t)e * 4);
        float2 m0 = mi[c0], m1 = mi[c0 + 1], m2 = mi[c0 + 2], m3 = mi[c0 + 3];
        sh4 o;
        o[0] = (short)f2bf(fmaxf((v.x - m0.x) * m0.y, 0.f));
        o[1] = (short)f2bf(fmaxf((v.y - m1.x) * m1.y, 0.f));
        o[2] = (short)f2bf(fmaxf((v.z - m2.x) * m2.y, 0.f));
        o[3] = (short)f2bf(fmaxf((v.w - m3.x) * m3.y, 0.f));
        *(sh4*)(bo + (size_t)e * 4) = o;
    }
}

// Tiled NCHW fp32 [Z][C][HW] -> NHWC bf16 [Z][HW][C]. grid (HW/64, C/64, Z).
__global__ __launch_bounds__(256) void transpose_chw_hwc_bf16(
    const float* __restrict__ src, ush* __restrict__ dst, int C, int HW)
{
    __shared__ float T[64][65];
    const int z = blockIdx.z, cb = blockIdx.y * 64, hb = blockIdx.x * 64;
    const int tid = threadIdx.x;
    for (int e = tid; e < 1024; e += 256) {
        int c = e >> 4, h4 = (e & 15) * 4;
        float4 v = *(const float4*)(src + ((size_t)z * C + cb + c) * HW + hb + h4);
        T[c][h4] = v.x; T[c][h4 + 1] = v.y; T[c][h4 + 2] = v.z; T[c][h4 + 3] = v.w;
    }
    __syncthreads();
    for (int e = tid; e < 1024; e += 256) {
        int h = e >> 4, c4 = (e & 15) * 4;
        sh4 o;
        o[0] = (short)f2bf(T[c4][h]);     o[1] = (short)f2bf(T[c4 + 1][h]);
        o[2] = (short)f2bf(T[c4 + 2][h]); o[3] = (short)f2bf(T[c4 + 3][h]);
        *(sh4*)(dst + ((size_t)z * HW + hb + h) * C + cb + c4) = o;
    }
}

extern "C" void kernel_launch(void* const* d_in, const int* in_sizes, int n_in,
                              void* d_out, int out_size, void* d_ws, size_t ws_size,
                              hipStream_t stream)
{
    const float* x      = (const float*)d_in[0];
    const float* w_off1 = (const float*)d_in[1];
    const float* b_off1 = (const float*)d_in[2];
    const float* w1     = (const float*)d_in[3];
    const float* b1     = (const float*)d_in[4];
    const float* w_off2 = (const float*)d_in[5];
    const float* b_off2 = (const float*)d_in[6];
    const float* w2     = (const float*)d_in[7];
    const float* b2     = (const float*)d_in[8];
    const float* w_off3 = (const float*)d_in[9];
    const float* b_off3 = (const float*)d_in[10];
    const float* w3     = (const float*)d_in[11];
    const float* b3     = (const float*)d_in[12];
    const float* rwa[2] = {(const float*)d_in[13], (const float*)d_in[17]};
    const float* rba[2] = {(const float*)d_in[14], (const float*)d_in[18]};
    const float* rwb[2] = {(const float*)d_in[15], (const float*)d_in[19]};
    const float* rbb[2] = {(const float*)d_in[16], (const float*)d_in[20]};

    float* out   = (float*)d_out;
    float* h_out = out;                         // [16,256,32,32]
    float* skip2 = out + 4194304;               // [16,128,64,64]
    float* skip3 = out + 4194304 + 8388608;     // [16,256,32,32]

    // workspace (floats), time-multiplexed.
    // R15: if ws permits ~151MB, stage-1 runs 2 chunks of 8 batches (om1 =
    // 19,267,584 floats; wprep/Pst relocated past it). Else 4 chunks of 4
    // (layout identical to R12/R14).
    float*  wsf    = (float*)d_ws;
    float*  h1     = wsf;
    float*  om2    = wsf + 8388608;
    ush*    skip2t = (ush*)wsf;
    float*  kp     = wsf + 8388608;
    float*  pool   = wsf + 16777216;
    float*  om1    = pool;
    ush*    h1b    = (ush*)pool;
    float*  om3    = pool + 8388608;
    float*  y1     = pool;
    float*  y2     = pool + 4194304;

    const bool big = ws_size >= (size_t)150863872;   // 37,715,968 floats
    const size_t wprep_off = big ? 19267584 : 9633792;
    ush*    wprep  = (ush*)(pool + wprep_off);
    float2* Pst    = (float2*)(pool + wprep_off + 1638400);

    // ---- Weight prep
    {
        PrepAll pd;
        const float* srcs[NWT] = {w_off1, w1, w_off2, w2, w_off3, w3,
                                  rwa[0], rwb[0], rwa[1], rwb[1]};
        const int Ms  [NWT] = {147, 64, 48, 128, 48, 256, 256, 256, 256, 256};
        const int Kts [NWT] = {147, 196, 1024, 1024, 2048, 2048, 2304, 2304, 2304, 2304};
        const int KTs [NWT] = {192, 256, 1024, 1024, 2048, 2048, 2304, 2304, 2304, 2304};
        const int Mbs [NWT] = {128, 64, 64, 128, 64, 128, 128, 128, 128, 128};
        const int sKs [NWT] = {147, 147, 1024, 1024, 2048, 2048, 2304, 2304, 2304, 2304};
        const int prm [NWT] = {0, 1, 2, 2, 2, 2, 0, 0, 0, 0};
        const int cns [NWT] = {3, 3, 64, 64, 128, 128, 256, 256, 256, 256};
        int sg = 0;
        pd.startG[0] = 0;
        for (int i = 0; i < NWT; ++i) {
            pd.src[i] = srcs[i];
            pd.M[i] = Ms[i]; pd.Ktot[i] = Kts[i]; pd.KT[i] = KTs[i];
            pd.Mblk[i] = Mbs[i]; pd.srcK[i] = sKs[i]; pd.perm[i] = prm[i];
            pd.cin[i] = cns[i];
            pd.dstOff[i] = (unsigned)sg * 8u;
            int mb = (Ms[i] + Mbs[i] - 1) / Mbs[i];
            sg += mb * (KTs[i] >> 6) * Mbs[i] * 8;
            pd.startG[i + 1] = sg;
        }
        prep_all_k<<<dim3((sg + 255) / 256), 256, 0, stream>>>(pd, wprep);
    }
    const ush* pw_off1 = wprep + 0;
    const ush* pw1     = wprep + 49152;
    const ush* pw_off2 = wprep + 65536;
    const ush* pw2     = wprep + 131072;
    const ush* pw_off3 = wprep + 262144;
    const ush* pw3     = wprep + 393216;
    const ush* prwa[2] = {wprep + 917504,  wprep + 2097152};
    const ush* prwb[2] = {wprep + 1507328, wprep + 2686976};

    // ---- Stage 1: 7x7 s1 p3, 3 -> 64ch @128x128; h1 written NHWC fp32
    if (big) {
        for (int c = 0; c < 2; ++c) {
            const float* xc = x + (size_t)c * 8 * 3 * 16384;
            conv_mfma<3,7,7,1,3,128,128,128,128,0,2,0,1,0,0,1><<<dim3(256, 2, 8), 256, 0, stream>>>(
                pw_off1, xc, nullptr, b_off1, om1, 147);
            conv_mfma<3,7,7,1,3,128,128,128,128,2,1,1,1,0,1,1><<<dim3(256, 1, 8), 256, 0, stream>>>(
                pw1, xc, om1, b1, h1 + (size_t)c * 8 * 16384 * 64, 64);
        }
    } else {
        for (int c = 0; c < 4; ++c) {
            const float* xc = x + (size_t)c * 4 * 3 * 16384;
            conv_mfma<3,7,7,1,3,128,128,128,128,0,2><<<dim3(256, 2, 4), 256, 0, stream>>>(
                pw_off1, xc, nullptr, b_off1, om1, 147);
            conv_mfma<3,7,7,1,3,128,128,128,128,2,1,1,1,0,1><<<dim3(256, 1, 4), 256, 0, stream>>>(
                pw1, xc, om1, b1, h1 + (size_t)c * 4 * 16384 * 64, 64);
        }
    }
    in_stats_nhwc<<<dim3(16, 16), 256, 0, stream>>>(h1, Pst, 16384);
    in_norm_nhwc_bf16<<<dim3(16, 64), 256, 0, stream>>>(Pst, h1, h1b, 16384);

    // ---- Stage 2: 4x4 s2 p1, 64 -> 128ch @64x64 (NHWC bf16 input, z-swizzle)
    conv_mfma<64,4,4,2,1,128,128,64,64,0,1,0,1,1,0,1><<<dim3(64, 1, 16), 256, 0, stream>>>(
        pw_off2, (const float*)h1b, nullptr, b_off2, om2, 48);
    conv_mfma<64,4,4,2,1,128,128,64,64,2,2,0,1,1,0,1><<<dim3(64, 1, 16), 256, 0, stream>>>(
        pw2, (const float*)h1b, om2, b2, skip2, 128);
    instnorm_k<true,false,false><<<16 * 128, 256, 0, stream>>>(skip2, skip2, nullptr, 4096);
    transpose_chw_hwc_bf16<<<dim3(64, 2, 16), 256, 0, stream>>>(skip2, skip2t, 128, 4096);

    // ---- Stage 3: 4x4 s2 p1, 128 -> 256ch @32x32 (NHWC bf16, K-split, z-swz)
    conv_mfma<128,4,4,2,1,64,64,32,32,0,1,0,4,1,0,1><<<dim3(16, 4, 16), 256, 0, stream>>>(
        pw_off3, (const float*)skip2t, nullptr, b_off3, kp, 48);
    reduce_bias_k<4><<<16 * 48, 256, 0, stream>>>(kp, 786432, b_off3, om3, 48, 1024);
    conv_mfma<128,4,4,2,1,64,64,32,32,2,2,0,2,1,0,1><<<dim3(16, 4, 16), 256, 0, stream>>>(
        pw3, (const float*)skip2t, om3, b3, kp, 256);
    reduce_bias_k<2><<<16 * 256, 256, 0, stream>>>(kp, 4194304, b3, skip3, 256, 1024);
    instnorm_k<true,true,false><<<16 * 256, 256, 0, stream>>>(skip3, skip3, h_out, 1024);

    // ---- Residual blocks: reflect 3x3, 256ch @32x32 (NCHW, K-split 2, z-swz)
    for (int r = 0; r < 2; ++r) {
        conv_mfma<256,3,3,1,1,32,32,32,32,1,2,0,2,0,0,1><<<dim3(16, 4, 16), 256, 0, stream>>>(
            prwa[r], h_out, nullptr, rba[r], kp, 256);
        reduce_bias_k<2><<<16 * 256, 256, 0, stream>>>(kp, 4194304, rba[r], y1, 256, 1024);
        instnorm_k<true,false,false><<<16 * 256, 256, 0, stream>>>(y1, y1, nullptr, 1024);
        conv_mfma<256,3,3,1,1,32,32,32,32,1,2,0,2,0,0,1><<<dim3(16, 4, 16), 256, 0, stream>>>(
            prwb[r], y1, nullptr, rbb[r], kp, 256);
        reduce_bias_k<2><<<16 * 256, 256, 0, stream>>>(kp, 4194304, rbb[r], y2, 256, 1024);
        instnorm_k<false,false,true><<<16 * 256, 256, 0, stream>>>(y2, h_out, nullptr, 1024);
    }
}

// Round 10
// 815.027 us; speedup vs baseline: 1.1860x; 1.1509x over previous
//
#include <hip/hip_runtime.h>
#include <math.h>

typedef __attribute__((ext_vector_type(8))) short short8;
typedef __attribute__((ext_vector_type(16))) short short16;
typedef __attribute__((ext_vector_type(4))) short sh4;
typedef __attribute__((ext_vector_type(4))) float floatx4;
typedef __attribute__((ext_vector_type(2))) _Float16 half2v;
typedef unsigned short ush;

__device__ __forceinline__ ush f2bf(float f) {
    unsigned u = __builtin_bit_cast(unsigned, f);
    u += 0x7FFFu + ((u >> 16) & 1u);   // RNE
    return (ush)(u >> 16);
}
__device__ __forceinline__ float bf2f(short s) {
    return __builtin_bit_cast(float, ((unsigned)(ush)s) << 16);
}

// ---------------------------------------------------------------------------
// Weights pre-converted ONCE per launch into bf16 tiles in the EXACT swizzled
// LDS image (R7). perm=1: stage-1 main k = r*4+ci (pad ci==3). perm=2:
// k = r*CIN + ci (NHWC convs: one tap r per 64-k step, contiguous channels).
// R16: residual weights also perm=2 (cin=256, Kk=9).
// ---------------------------------------------------------------------------
#define NWT 10
struct PrepAll {
    const float* src[NWT];
    unsigned int dstOff[NWT];
    int M[NWT], Ktot[NWT], KT[NWT], Mblk[NWT], srcK[NWT], perm[NWT], cin[NWT];
    int startG[NWT + 1];
};

__global__ __launch_bounds__(256) void prep_all_k(PrepAll d, ush* __restrict__ P)
{
    const int t = blockIdx.x * 256 + threadIdx.x;
    if (t >= d.startG[NWT]) return;
    int wi = 0;
#pragma unroll
    for (int i = 1; i < NWT; ++i) wi += (t >= d.startG[i]);
    const int g8   = t - d.startG[wi];
    const int Mblk = d.Mblk[wi];
    const int ksC  = d.KT[wi] >> 6;
    const int g    = g8 & 7;
    int rest = g8 >> 3;
    const int row = rest % Mblk; rest /= Mblk;
    const int ks  = rest % ksC;
    const int mb  = rest / ksC;
    const int kchunk = g ^ (row & 7);
    const int gm  = mb * Mblk + row;
    const int M = d.M[wi], Ktot = d.Ktot[wi], srcK = d.srcK[wi];
    const int prm = d.perm[wi], cin = d.cin[wi];
    const float* __restrict__ src = d.src[wi];
    short8 v;
#pragma unroll
    for (int j = 0; j < 8; ++j) {
        int gk = ks * 64 + kchunk * 8 + j;
        bool ok = (gm < M) && (gk < Ktot);
        int gs = gk;
        if (prm == 1) { int ci = gk & 3, rr = gk >> 2; ok = ok && (ci < 3); gs = ci * 49 + rr; }
        if (prm == 2) { int ci = gk % cin, rr = gk / cin; gs = ci * (Ktot / cin) + rr; }
        float f = ok ? src[(size_t)gm * srcK + gs] : 0.f;
        v[j] = (short)f2bf(f);
    }
    *(short8*)(P + d.dstOff[wi] + (size_t)g8 * 8) = v;
}

// Implicit-GEMM conv on bf16 MFMA. MODE 0 zero-pad / 1 reflect / 2 deform.
// Tile BM=64*MT, BN=64, BK=64; 256 threads = 4 waves.
// R14: counted-vmcnt pipeline for BP_L2 (8 B-loads stay in flight across the
// barrier + MFMA phase). R15: PIPE=BP_L2 only.
// R16: BP_L1 = NHWC bf16 reflect-pad (residuals): CIN%64==0 so a 64-k step
// stays within one tap r -> B-stage is ONE idx read + ONE 32B load + copy
// (the BP_L0 shape that was fastest).
template<int CIN,int KH,int KW,int STR,int PAD,int H,int W,int HO,int WO,
         int MODE,int MT,int PERM=0,int NKS=1,int LAYT=0,int ONHWC=0,int ZSWZ=0>
__global__ __launch_bounds__(256) void conv_mfma(
    const ush* __restrict__ Aprep,
    const float* __restrict__ X,      // NCHW fp32, or NHWC bf16 when LAYT
    const float* __restrict__ OM,     // [Z][3*Kk][HO][WO] (deform only)
    const float* __restrict__ bias,
    float* __restrict__ Out,          // [Z][M][HO*WO] (or NKS partials / NHWC)
    int M)
{
    constexpr int Kk   = KH*KW;
    constexpr int Ktot = PERM == 1 ? 4*Kk : CIN*Kk;
    constexpr int HWc  = H*W;
    constexpr int HOWO = HO*WO;
    constexpr int KT   = (Ktot + 63) & ~63;
    constexpr int KSC  = KT >> 6;
    constexpr int KSLICE = KT / NKS;
    constexpr bool KGUARD = (Ktot % 64 != 0);
    // live B-path selectors
    constexpr bool BP_L2  = LAYT && (MODE == 2);            // NHWC bf16 deform
    constexpr bool BP_L0  = LAYT && (MODE == 0);            // NHWC bf16 zero-pad
    constexpr bool BP_L1  = LAYT && (MODE == 1);            // NHWC bf16 reflect
    constexpr bool BP_M2P = (MODE == 2) && (PERM == 1);     // stage-1 deform
    constexpr bool BP_LUT = !LAYT && (MODE == 1 || MODE == 0); // NCHW im2col
    static_assert(BP_L2 || BP_L0 || BP_L1 || BP_M2P || BP_LUT, "");
    constexpr bool PIPE  = BP_L2;                           // counted-vmcnt loop
    constexpr bool META2 = BP_L2;                           // packed deform meta
    constexpr bool MLUTB = BP_L0 || BP_L1 || BP_LUT;        // idx LUT
    constexpr int KPAD = (Kk % 2 == 0) ? Kk + 1 : Kk;
    static_assert(KT % (64 * NKS) == 0, "");
    static_assert(PERM != 1 || (MODE == 2 && CIN == 3 && Kk == 49), "");
    static_assert(!LAYT || (CIN % 64 == 0 && (Kk == 16 || MODE == 1)), "");
    static_assert(!ONHWC || (MT == 1 && NKS == 1 && !PIPE), "");

    // ---- optional XCD-locality remap (bijective; needs gz%8==0, total%8==0)
    int bx = blockIdx.x, by = blockIdx.y, bz = blockIdx.z;
    if constexpr (ZSWZ) {
        const int gx = gridDim.x, gy = gridDim.y, gz = gridDim.z;
        const int gxy = gx * gy;
        int flat = bx + gx * (by + gy * bz);
        int xcd = flat & 7, rank = flat >> 3;
        int zloc = rank / gxy, rem = rank - zloc * gxy;
        bz = xcd * (gz >> 3) + zloc;
        by = rem / gx; bx = rem - (rem / gx) * gx;
    }

    const int z = bz;
    const float* __restrict__ Xb  = LAYT ? nullptr : (X + (size_t)z * CIN * HWc);
    const ush*   __restrict__ Xh  = LAYT ? ((const ush*)X + (size_t)z * CIN * HWc) : nullptr;
    const float* __restrict__ OMb = (MODE == 2) ? (OM + (size_t)z * 3 * Kk * HOWO) : nullptr;

    const int mtiles = gridDim.y / NKS;
    const int my = (NKS > 1) ? (by % mtiles) : by;
    const int ks = (NKS > 1) ? (by / mtiles) : 0;

    float* __restrict__ Outb;
    if constexpr (NKS > 1) {
        const size_t PS = (size_t)gridDim.z * (size_t)M * HOWO;
        Outb = Out + (size_t)ks * PS + (size_t)z * (size_t)M * HOWO;
    } else {
        Outb = Out + (size_t)z * (size_t)M * HOWO;
    }

    const int n0   = bx * 64;
    const int tid  = threadIdx.x;
    const int lane = tid & 63;
    const int wave = tid >> 6;
    const int quad = lane >> 4;
    const int l16  = lane & 15;

    const int bn2 = tid & 63;
    const int bkc = tid >> 6;
    const int gn2 = n0 + bn2;
    const int ho2 = gn2 / WO, wo2 = gn2 % WO;

    // ---- shared memory carve (Ts for ONHWC aliases As+Bs)
    constexpr int AB_BYTES = 64*MT*64*2 + 64*64*2;
    constexpr int TS_BYTES = ONHWC ? 64*64*4 : 0;
    constexpr int BASE_BYTES = AB_BYTES > TS_BYTES ? AB_BYTES : TS_BYTES;
    constexpr int MIB_OFF = BASE_BYTES;
    constexpr int MWH_OFF = MIB_OFF + (META2 ? 64*KPAD*4 : 0);
    constexpr int MI0_OFF = MWH_OFF + (META2 ? 64*KPAD*8 : 0);
    constexpr int SMEM_TOT = MI0_OFF + (MLUTB ? 64*KPAD*4 : 0);
    __shared__ __align__(16) char smem[SMEM_TOT];
    ush (*As)[64] = reinterpret_cast<ush(*)[64]>(smem);
    ush (*Bs)[64] = reinterpret_cast<ush(*)[64]>(smem + 64*MT*64*2);
    int*   MIb = reinterpret_cast<int*>(smem + MIB_OFF);
    uint2* MWh = reinterpret_cast<uint2*>(smem + MWH_OFF);
    int*   MI0 = reinterpret_cast<int*>(smem + MI0_OFF);
    float* Ts  = reinterpret_cast<float*>(smem);

    // ---- one-time LDS meta (deform Kk==16). n = e&63 -> coalesced OM reads.
    if constexpr (META2) {
        for (int e = tid; e < 64 * Kk; e += 256) {
            int n = e & 63, r = e >> 6;
            int gn = n0 + n, ho = gn / WO, wo = gn % WO;
            int ky = r / KW, kx = r % KW;
            float offy = OMb[(size_t)(2 * r) * HOWO + gn];
            float offx = OMb[(size_t)(2 * r + 1) * HOWO + gn];
            float ml   = OMb[(size_t)(2 * Kk + r) * HOWO + gn];
            float mask = 1.f / (1.f + expf(-ml));
            float ys = (float)(ho * STR - PAD + ky) + offy;
            float xs = (float)(wo * STR - PAD + kx) + offx;
            float y0f = floorf(ys), x0f = floorf(xs);
            float dy = ys - y0f, dx = xs - x0f;
            int y0 = (int)y0f, x0 = (int)x0f;
            int yc0 = min(max(y0, 0), H - 1);
            int yc1 = min(max(y0 + 1, 0), H - 1);
            int xc0 = min(max(x0, 0), W - 1);
            int xc1 = min(max(x0 + 1, 0), W - 1);
            bool y0ok = (y0 >= 0) & (y0 < H), y1ok = (y0 + 1 >= 0) & (y0 + 1 < H);
            bool x0ok = (x0 >= 0) & (x0 < W), x1ok = (x0 + 1 >= 0) & (x0 + 1 < W);
            half2v w01, w23;
            w01[0] = (_Float16)((y0ok && x0ok) ? (1.f - dy) * (1.f - dx) * mask : 0.f);
            w01[1] = (_Float16)((y0ok && x1ok) ? (1.f - dy) * dx * mask : 0.f);
            w23[0] = (_Float16)((y1ok && x0ok) ? dy * (1.f - dx) * mask : 0.f);
            w23[1] = (_Float16)((y1ok && x1ok) ? dy * dx * mask : 0.f);
            MIb[n * KPAD + r] = (yc0 * W + xc0) | ((xc1 - xc0) << 24) | ((yc1 - yc0) << 25);
            MWh[n * KPAD + r] = make_uint2(__builtin_bit_cast(unsigned, w01),
                                           __builtin_bit_cast(unsigned, w23));
        }
        __syncthreads();
    }
    if constexpr (MLUTB) {
        for (int e = tid; e < 64 * Kk; e += 256) {
            int n = e & 63, r = e >> 6;
            int gn = n0 + n, ho = gn / WO, wo = gn % WO;
            int ky = r / KW, kx = r % KW;
            int idx;
            if constexpr (MODE == 0) {
                int iy = ho * STR - PAD + ky;
                int ix = wo * STR - PAD + kx;
                idx = (iy >= 0 && iy < H && ix >= 0 && ix < W) ? iy * W + ix : -1;
            } else {
                int iy = ho - PAD + ky; iy = iy < 0 ? -iy : (iy >= H ? 2 * H - 2 - iy : iy);
                int ix = wo - PAD + kx; ix = ix < 0 ? -ix : (ix >= W ? 2 * W - 2 - ix : ix);
                idx = iy * W + ix;
            }
            MI0[n * KPAD + r] = idx;
        }
        __syncthreads();
    }

    floatx4 acc[MT][4];
#pragma unroll
    for (int s = 0; s < MT; ++s)
#pragma unroll
        for (int t = 0; t < 4; ++t) acc[s][t] = (floatx4){0.f, 0.f, 0.f, 0.f};

    const int kbeg = ks * KSLICE, kend = kbeg + KSLICE;

    // A-DMA helper (issues 2*MT global_load_lds, vmem ops)
    auto ADMA = [&](int k0) {
        const ush* At =
            Aprep + ((size_t)my * KSC + (k0 >> 6)) * (size_t)(64 * MT * 64);
#pragma unroll
        for (int c = 0; c < 2 * MT; ++c) {
            const int chunk = c * 4 + wave;
            __builtin_amdgcn_global_load_lds(
                (const __attribute__((address_space(1))) void*)(At + (size_t)chunk * 512 + lane * 8),
                (__attribute__((address_space(3))) void*)(&As[0][0] + chunk * 512),
                16, 0, 0);
        }
    };

    auto MFMA_PHASE = [&]() {
        const int mrow = wave * 16 + l16;
#pragma unroll
        for (int kk = 0; kk < 2; ++kk) {
            const int kg = kk * 4 + quad;
            short8 a[MT];
#pragma unroll
            for (int s = 0; s < MT; ++s)
                a[s] = *(const short8*)&As[s * 64 + mrow][((kg ^ (mrow & 7)) * 8)];
#pragma unroll
            for (int t = 0; t < 4; ++t) {
                const int ncol = t * 16 + l16;
                short8 b = *(const short8*)&Bs[ncol][((kg ^ (ncol & 7)) * 8)];
#pragma unroll
                for (int s = 0; s < MT; ++s)
                    acc[s][t] = __builtin_amdgcn_mfma_f32_16x16x32_bf16(a[s], b, acc[s][t], 0, 0, 0);
            }
        }
    };

    if constexpr (PIPE) {
        // ---- counted-vmcnt pipeline (NHWC bf16 deform)
        short16 pb0, pb1, pb2, pb3;
        unsigned pwx = 0, pwy = 0;

        auto LOADB = [&](int k0) {
            const int r   = k0 / CIN;              // wave-uniform
            const int ci0 = (k0 % CIN) + bkc * 16;
            int packed = MIb[bn2 * KPAD + r];
            uint2 ww   = MWh[bn2 * KPAD + r];
            pwx = ww.x; pwy = ww.y;
            int base = packed & 0xFFFFFF;
            int dX = ((packed >> 24) & 1) ? CIN : 0;
            int dY = ((packed >> 25) & 1) ? W * CIN : 0;
            const ush* p00 = Xh + (size_t)base * CIN + ci0;
            pb0 = *(const short16*)(p00);
            pb1 = *(const short16*)(p00 + dX);
            pb2 = *(const short16*)(p00 + dY);
            pb3 = *(const short16*)(p00 + dY + dX);
        };
        auto CONVB = [&](short8& s0, short8& s1) {
            half2v w01 = __builtin_bit_cast(half2v, pwx);
            half2v w23 = __builtin_bit_cast(half2v, pwy);
            float W00 = (float)w01[0], W01 = (float)w01[1];
            float W10 = (float)w23[0], W11 = (float)w23[1];
#pragma unroll
            for (int j = 0; j < 8; ++j) {
                s0[j] = (short)f2bf(W00 * bf2f(pb0[j]) + W01 * bf2f(pb1[j])
                                  + W10 * bf2f(pb2[j]) + W11 * bf2f(pb3[j]));
                s1[j] = (short)f2bf(W00 * bf2f(pb0[8 + j]) + W01 * bf2f(pb1[8 + j])
                                  + W10 * bf2f(pb2[8 + j]) + W11 * bf2f(pb3[8 + j]));
            }
        };

        LOADB(kbeg);
        for (int k0 = kbeg; k0 < kend; k0 += 64) {
            ADMA(k0);
            asm volatile("" ::: "memory");          // IR fence: B-loads stay below
            __builtin_amdgcn_sched_barrier(0);      // MIR fence

            short8 s0, s1;
            CONVB(s0, s1);                          // compiler waits pb* itself
            const bool more = (k0 + 64 < kend);
            if (more) LOADB(k0 + 64);               // 8 vmem ops, youngest
            const int g0 = (bkc * 2)     ^ (bn2 & 7);
            const int g1 = (bkc * 2 + 1) ^ (bn2 & 7);
            *(short8*)&Bs[bn2][g0 * 8] = s0;
            *(short8*)&Bs[bn2][g1 * 8] = s1;

            // barrier #1: ds_writes visible + A-DMA landed; B(k+1) stays in flight
            if (more)
                asm volatile("s_waitcnt vmcnt(8) lgkmcnt(0)" ::: "memory");
            else
                asm volatile("s_waitcnt vmcnt(0) lgkmcnt(0)" ::: "memory");
            __builtin_amdgcn_sched_barrier(0);
            __builtin_amdgcn_s_barrier();
            __builtin_amdgcn_sched_barrier(0);
            asm volatile("" ::: "memory");

            MFMA_PHASE();

            // barrier #2: own ds_reads complete before Bs/As overwritten
            asm volatile("s_waitcnt lgkmcnt(0)" ::: "memory");
            __builtin_amdgcn_sched_barrier(0);
            __builtin_amdgcn_s_barrier();
            __builtin_amdgcn_sched_barrier(0);
            asm volatile("" ::: "memory");
        }
    } else {
        // ---- plain loop (__syncthreads), inline staging
        for (int k0 = kbeg; k0 < kend; k0 += 64) {
            ADMA(k0);
            {
                short8 s0, s1;
                if constexpr (BP_L0) {
                    // NHWC bf16 zero-pad: direct copy, one dwordx4
                    const int r   = k0 / CIN;
                    const int ci0 = (k0 % CIN) + bkc * 16;
                    int idx = MI0[bn2 * KPAD + r];
                    const ush* p0 = Xh + (size_t)(idx < 0 ? 0 : idx) * CIN + ci0;
                    short16 v = *(const short16*)p0;
#pragma unroll
                    for (int j = 0; j < 8; ++j) { s0[j] = v[j]; s1[j] = v[8 + j]; }
                    if (idx < 0) {
#pragma unroll
                        for (int j = 0; j < 8; ++j) { s0[j] = 0; s1[j] = 0; }
                    }
                } else if constexpr (BP_L1) {
                    // NHWC bf16 reflect-pad: idx always valid, pure copy
                    const int r   = k0 / CIN;
                    const int ci0 = (k0 % CIN) + bkc * 16;
                    int idx = MI0[bn2 * KPAD + r];
                    const ush* p0 = Xh + (size_t)idx * CIN + ci0;
                    short16 v = *(const short16*)p0;
#pragma unroll
                    for (int j = 0; j < 8; ++j) { s0[j] = v[j]; s1[j] = v[8 + j]; }
                } else if constexpr (BP_M2P) {
                    // stage-1 deform, perm'd K: 4 slots share one r (3 planes + pad)
                    ush tmp[16];
                    const int kbase = k0 + bkc * 16;
                    const int rbase = kbase >> 2;
#pragma unroll
                    for (int u = 0; u < 4; ++u) {
                        const int r = rbase + u;
                        float v0 = 0.f, v1 = 0.f, v2 = 0.f;
                        if (r < Kk) {
                            const int ky = r / KW, kx = r - ky * KW;
                            float offy = OMb[(size_t)(2 * r) * HOWO + gn2];
                            float offx = OMb[(size_t)(2 * r + 1) * HOWO + gn2];
                            float ml   = OMb[(size_t)(2 * Kk + r) * HOWO + gn2];
                            float mask = 1.f / (1.f + expf(-ml));
                            float ys = (float)(ho2 * STR - PAD + ky) + offy;
                            float xs = (float)(wo2 * STR - PAD + kx) + offx;
                            float y0f = floorf(ys), x0f = floorf(xs);
                            float dy = ys - y0f, dx = xs - x0f;
                            int y0 = (int)y0f, x0 = (int)x0f;
                            int yc0 = min(max(y0, 0), H - 1);
                            int yc1 = min(max(y0 + 1, 0), H - 1);
                            int xc0 = min(max(x0, 0), W - 1);
                            int xc1 = min(max(x0 + 1, 0), W - 1);
                            bool y0ok = (y0 >= 0) & (y0 < H), y1ok = (y0 + 1 >= 0) & (y0 + 1 < H);
                            bool x0ok = (x0 >= 0) & (x0 < W), x1ok = (x0 + 1 >= 0) & (x0 + 1 < W);
                            float w00 = (y0ok && x0ok) ? (1.f - dy) * (1.f - dx) * mask : 0.f;
                            float w01 = (y0ok && x1ok) ? (1.f - dy) * dx * mask : 0.f;
                            float w10 = (y1ok && x0ok) ? dy * (1.f - dx) * mask : 0.f;
                            float w11 = (y1ok && x1ok) ? dy * dx * mask : 0.f;
                            int base = yc0 * W + xc0;
                            int dxs  = xc1 - xc0;
                            int dys  = (yc1 - yc0) ? W : 0;
                            float cc[12];
#pragma unroll
                            for (int ci = 0; ci < 3; ++ci) {
                                const float* img = Xb + (size_t)ci * HWc;
                                cc[ci * 4 + 0] = img[base];
                                cc[ci * 4 + 1] = img[base + dxs];
                                cc[ci * 4 + 2] = img[base + dys];
                                cc[ci * 4 + 3] = img[base + dys + dxs];
                            }
                            v0 = w00 * cc[0] + w01 * cc[1] + w10 * cc[2]  + w11 * cc[3];
                            v1 = w00 * cc[4] + w01 * cc[5] + w10 * cc[6]  + w11 * cc[7];
                            v2 = w00 * cc[8] + w01 * cc[9] + w10 * cc[10] + w11 * cc[11];
                        }
                        tmp[u * 4 + 0] = f2bf(v0);
                        tmp[u * 4 + 1] = f2bf(v1);
                        tmp[u * 4 + 2] = f2bf(v2);
                        tmp[u * 4 + 3] = 0;
                    }
#pragma unroll
                    for (int j = 0; j < 8; ++j) { s0[j] = (short)tmp[j]; s1[j] = (short)tmp[8 + j]; }
                } else {
                    // BP_LUT: batched idx reads then unconditional clamped gathers
                    ush tmp[16];
                    int idxs[16];
                    float raw[16];
#pragma unroll
                    for (int j = 0; j < 16; ++j) {
                        int gk = k0 + bkc * 16 + j;
                        int ci = gk / Kk;
                        int r  = gk - ci * Kk;
                        int idx = MI0[bn2 * KPAD + r];
                        if (KGUARD && gk >= Ktot) idx = -1;
                        idxs[j] = idx;
                    }
#pragma unroll
                    for (int j = 0; j < 16; ++j) {
                        int gk = k0 + bkc * 16 + j;
                        int ci = gk / Kk;
                        raw[j] = Xb[(size_t)ci * HWc + (idxs[j] < 0 ? 0 : idxs[j])];
                    }
#pragma unroll
                    for (int j = 0; j < 16; ++j)
                        tmp[j] = idxs[j] < 0 ? (ush)0 : f2bf(raw[j]);
#pragma unroll
                    for (int j = 0; j < 8; ++j) { s0[j] = (short)tmp[j]; s1[j] = (short)tmp[8 + j]; }
                }
                const int g0 = (bkc * 2)     ^ (bn2 & 7);
                const int g1 = (bkc * 2 + 1) ^ (bn2 & 7);
                *(short8*)&Bs[bn2][g0 * 8] = s0;
                *(short8*)&Bs[bn2][g1 * 8] = s1;
            }
            __syncthreads();
            MFMA_PHASE();
            __syncthreads();
        }
    }

    // ---- epilogue
    if constexpr (ONHWC) {
        // LDS transpose -> coalesced NHWC store (M==64, full tile)
#pragma unroll
        for (int t = 0; t < 4; ++t) {
            int n = t * 16 + l16;
#pragma unroll
            for (int i = 0; i < 4; ++i) {
                int m = wave * 16 + quad * 4 + i;
                Ts[n * 64 + (m ^ ((n & 7) << 3))] = acc[0][t][i] + bias[m];
            }
        }
        __syncthreads();
        float* Outc = Out + ((size_t)z * HOWO + n0) * 64;
        for (int e = tid; e < 1024; e += 256) {
            int n = e >> 4, m4 = (e & 15) * 4;
            float4 v = *(float4*)&Ts[n * 64 + (m4 ^ ((n & 7) << 3))];
            *(float4*)(Outc + n * 64 + m4) = v;
        }
    } else {
#pragma unroll
        for (int s = 0; s < MT; ++s) {
#pragma unroll
            for (int t = 0; t < 4; ++t) {
                const int ng = n0 + t * 16 + l16;
#pragma unroll
                for (int i = 0; i < 4; ++i) {
                    int mg = my * (64 * MT) + s * 64 + wave * 16 + quad * 4 + i;
                    if (mg < M) {
                        float v = acc[s][t][i];
                        if constexpr (NKS == 1) v += bias[mg];
                        Outb[(size_t)mg * HOWO + ng] = v;
                    }
                }
            }
        }
    }
}

// Sum NP partial planes (stride PS) + bias -> out. One block per (z,m) row.
template<int NP>
__global__ __launch_bounds__(256) void reduce_bias_k(
    const float* __restrict__ P, size_t PS, const float* __restrict__ bias,
    float* __restrict__ out, int M, int HOWO)
{
    const int bc = blockIdx.x;
    const int m  = bc % M;
    const float b = bias[m];
    const size_t off = (size_t)bc * HOWO;
    for (int i = threadIdx.x * 4; i < HOWO; i += 1024) {
        float4 a = *(const float4*)(P + off + i);
#pragma unroll
        for (int p = 1; p < NP; ++p) {
            float4 c = *(const float4*)(P + (size_t)p * PS + off + i);
            a.x += c.x; a.y += c.y; a.z += c.z; a.w += c.w;
        }
        a.x += b; a.y += b; a.z += b; a.w += b;
        *(float4*)(out + off + i) = a;
    }
}

// R16: fused partial-sum + bias + instance-norm for HOWO==1024 (stage-3 main
// and residual sites). One block per (z,m) row; the 1024 values live in
// registers (one float4/thread) across stats and normalize — removes the
// intermediate write+read and one launch per site.
template<int NP, bool RELU, bool DUAL, bool ADDIN>
__global__ __launch_bounds__(256) void reduce_in_k(
    const float* __restrict__ P, size_t PS, const float* __restrict__ bias,
    float* __restrict__ out, float* __restrict__ out2, int M)
{
    const int bc = blockIdx.x;
    const int m  = bc % M;
    const float b = bias[m];
    const size_t off = (size_t)bc * 1024 + threadIdx.x * 4;
    float4 a = *(const float4*)(P + off);
#pragma unroll
    for (int p = 1; p < NP; ++p) {
        float4 c = *(const float4*)(P + (size_t)p * PS + off);
        a.x += c.x; a.y += c.y; a.z += c.z; a.w += c.w;
    }
    a.x += b; a.y += b; a.z += b; a.w += b;
    float s = a.x + a.y + a.z + a.w;
    float q = a.x * a.x + a.y * a.y + a.z * a.z + a.w * a.w;
    __shared__ float rs[256], rq[256];
    rs[threadIdx.x] = s; rq[threadIdx.x] = q;
    __syncthreads();
    for (int o = 128; o > 0; o >>= 1) {
        if (threadIdx.x < o) { rs[threadIdx.x] += rs[threadIdx.x + o]; rq[threadIdx.x] += rq[threadIdx.x + o]; }
        __syncthreads();
    }
    float mean = rs[0] * (1.f / 1024.f);
    float var  = rq[0] * (1.f / 1024.f) - mean * mean;
    float inv  = rsqrtf(var + 1e-5f);
    a.x = (a.x - mean) * inv; a.y = (a.y - mean) * inv;
    a.z = (a.z - mean) * inv; a.w = (a.w - mean) * inv;
    if (RELU) {
        a.x = fmaxf(a.x, 0.f); a.y = fmaxf(a.y, 0.f);
        a.z = fmaxf(a.z, 0.f); a.w = fmaxf(a.w, 0.f);
    }
    if (ADDIN) {
        float4 o4 = *(const float4*)(out + off);
        o4.x += a.x; o4.y += a.y; o4.z += a.z; o4.w += a.w;
        *(float4*)(out + off) = o4;
    } else {
        *(float4*)(out + off) = a;
        if (DUAL) *(float4*)(out2 + off) = a;
    }
}

// NCHW instance norm (per (b,c) over HW); optional ReLU/dual/add-in. float4.
template<bool RELU, bool DUAL, bool ADDIN>
__global__ __launch_bounds__(256) void instnorm_k(
    const float* __restrict__ in, float* __restrict__ out,
    float* __restrict__ out2, int HW)
{
    const int bc = blockIdx.x;
    const float4* p4 = (const float4*)(in + (size_t)bc * HW);
    const int n4 = HW >> 2;
    float s = 0.f, ss = 0.f;
    for (int i = threadIdx.x; i < n4; i += 256) {
        float4 v = p4[i];
        s  += v.x + v.y + v.z + v.w;
        ss += v.x * v.x + v.y * v.y + v.z * v.z + v.w * v.w;
    }
    __shared__ float rs[256], rq[256];
    rs[threadIdx.x] = s; rq[threadIdx.x] = ss;
    __syncthreads();
    for (int o = 128; o > 0; o >>= 1) {
        if (threadIdx.x < o) { rs[threadIdx.x] += rs[threadIdx.x + o]; rq[threadIdx.x] += rq[threadIdx.x + o]; }
        __syncthreads();
    }
    float mean = rs[0] / (float)HW;
    float var  = rq[0] / (float)HW - mean * mean;
    float inv  = rsqrtf(var + 1e-5f);
    float4* q4  = (float4*)(out + (size_t)bc * HW);
    float4* q24 = DUAL ? (float4*)(out2 + (size_t)bc * HW) : nullptr;
    for (int i = threadIdx.x; i < n4; i += 256) {
        float4 v = p4[i];
        v.x = (v.x - mean) * inv; v.y = (v.y - mean) * inv;
        v.z = (v.z - mean) * inv; v.w = (v.w - mean) * inv;
        if (RELU) {
            v.x = fmaxf(v.x, 0.f); v.y = fmaxf(v.y, 0.f);
            v.z = fmaxf(v.z, 0.f); v.w = fmaxf(v.w, 0.f);
        }
        if (ADDIN) {
            float4 o = q4[i];
            o.x += v.x; o.y += v.y; o.z += v.z; o.w += v.w;
            q4[i] = o;
        } else {
            q4[i] = v;
            if (DUAL) q24[i] = v;
        }
    }
}

// NHWC instance-norm stats: per (z, chunk of 1024 hw) partial s/ss per channel.
__global__ __launch_bounds__(256) void in_stats_nhwc(
    const float* __restrict__ X, float2* __restrict__ P, int HW)
{
    const int z = blockIdx.x, chunk = blockIdx.y;
    const int tid = threadIdx.x;
    const int cg = tid & 15, seg = tid >> 4;
    const int c0 = cg * 4;
    float4 s4 = make_float4(0.f, 0.f, 0.f, 0.f);
    float4 q4 = make_float4(0.f, 0.f, 0.f, 0.f);
    const float* base = X + ((size_t)z * HW + chunk * 1024) * 64;
    for (int hw = seg; hw < 1024; hw += 16) {
        float4 v = *(const float4*)(base + (size_t)hw * 64 + c0);
        s4.x += v.x; s4.y += v.y; s4.z += v.z; s4.w += v.w;
        q4.x += v.x * v.x; q4.y += v.y * v.y; q4.z += v.z * v.z; q4.w += v.w * v.w;
    }
    __shared__ float4 rs[256], rq[256];
    rs[tid] = s4; rq[tid] = q4;
    __syncthreads();
    if (tid < 16) {
        float4 S = rs[tid], Q = rq[tid];
        for (int g = 1; g < 16; ++g) {
            float4 a = rs[g * 16 + tid], b = rq[g * 16 + tid];
            S.x += a.x; S.y += a.y; S.z += a.z; S.w += a.w;
            Q.x += b.x; Q.y += b.y; Q.z += b.z; Q.w += b.w;
        }
        float2* po = P + ((size_t)z * 16 + chunk) * 64 + tid * 4;
        po[0] = make_float2(S.x, Q.x);
        po[1] = make_float2(S.y, Q.y);
        po[2] = make_float2(S.z, Q.z);
        po[3] = make_float2(S.w, Q.w);
    }
}

// NHWC normalize + ReLU, fp32 in -> bf16 out. grid (Z, 64 chunks of 256 hw).
__global__ __launch_bounds__(256) void in_norm_nhwc_bf16(
    const float2* __restrict__ P, const float* __restrict__ X,
    ush* __restrict__ Y, int HW)
{
    const int z = blockIdx.x, chunk = blockIdx.y;
    const int tid = threadIdx.x;
    __shared__ float2 mi[64];
    if (tid < 64) {
        float s = 0.f, q = 0.f;
        for (int g = 0; g < 16; ++g) {
            float2 p = P[((size_t)z * 16 + g) * 64 + tid];
            s += p.x; q += p.y;
        }
        float mean = s / (float)HW;
        float var  = q / (float)HW - mean * mean;
        mi[tid] = make_float2(mean, rsqrtf(var + 1e-5f));
    }
    __syncthreads();
    const float* bi = X + ((size_t)z * HW + chunk * 256) * 64;
    ush* bo = Y + ((size_t)z * HW + chunk * 256) * 64;
    for (int e = tid; e < 4096; e += 256) {
        int c0 = (e & 15) * 4;
        float4 v = *(const float4*)(bi + (size_t)e * 4);
        float2 m0 = mi[c0], m1 = mi[c0 + 1], m2 = mi[c0 + 2], m3 = mi[c0 + 3];
        sh4 o;
        o[0] = (short)f2bf(fmaxf((v.x - m0.x) * m0.y, 0.f));
        o[1] = (short)f2bf(fmaxf((v.y - m1.x) * m1.y, 0.f));
        o[2] = (short)f2bf(fmaxf((v.z - m2.x) * m2.y, 0.f));
        o[3] = (short)f2bf(fmaxf((v.w - m3.x) * m3.y, 0.f));
        *(sh4*)(bo + (size_t)e * 4) = o;
    }
}

// Tiled NCHW fp32 [Z][C][HW] -> NHWC bf16 [Z][HW][C]. grid (HW/64, C/64, Z).
__global__ __launch_bounds__(256) void transpose_chw_hwc_bf16(
    const float* __restrict__ src, ush* __restrict__ dst, int C, int HW)
{
    __shared__ float T[64][65];
    const int z = blockIdx.z, cb = blockIdx.y * 64, hb = blockIdx.x * 64;
    const int tid = threadIdx.x;
    for (int e = tid; e < 1024; e += 256) {
        int c = e >> 4, h4 = (e & 15) * 4;
        float4 v = *(const float4*)(src + ((size_t)z * C + cb + c) * HW + hb + h4);
        T[c][h4] = v.x; T[c][h4 + 1] = v.y; T[c][h4 + 2] = v.z; T[c][h4 + 3] = v.w;
    }
    __syncthreads();
    for (int e = tid; e < 1024; e += 256) {
        int h = e >> 4, c4 = (e & 15) * 4;
        sh4 o;
        o[0] = (short)f2bf(T[c4][h]);     o[1] = (short)f2bf(T[c4 + 1][h]);
        o[2] = (short)f2bf(T[c4 + 2][h]); o[3] = (short)f2bf(T[c4 + 3][h]);
        *(sh4*)(dst + ((size_t)z * HW + hb + h) * C + cb + c4) = o;
    }
}

extern "C" void kernel_launch(void* const* d_in, const int* in_sizes, int n_in,
                              void* d_out, int out_size, void* d_ws, size_t ws_size,
                              hipStream_t stream)
{
    const float* x      = (const float*)d_in[0];
    const float* w_off1 = (const float*)d_in[1];
    const float* b_off1 = (const float*)d_in[2];
    const float* w1     = (const float*)d_in[3];
    const float* b1     = (const float*)d_in[4];
    const float* w_off2 = (const float*)d_in[5];
    const float* b_off2 = (const float*)d_in[6];
    const float* w2     = (const float*)d_in[7];
    const float* b2     = (const float*)d_in[8];
    const float* w_off3 = (const float*)d_in[9];
    const float* b_off3 = (const float*)d_in[10];
    const float* w3     = (const float*)d_in[11];
    const float* b3     = (const float*)d_in[12];
    const float* rwa[2] = {(const float*)d_in[13], (const float*)d_in[17]};
    const float* rba[2] = {(const float*)d_in[14], (const float*)d_in[18]};
    const float* rwb[2] = {(const float*)d_in[15], (const float*)d_in[19]};
    const float* rbb[2] = {(const float*)d_in[16], (const float*)d_in[20]};

    float* out   = (float*)d_out;
    float* h_out = out;                         // [16,256,32,32]
    float* skip2 = out + 4194304;               // [16,128,64,64]
    float* skip3 = out + 4194304 + 8388608;     // [16,256,32,32]

    // workspace (floats), time-multiplexed.
    // stage1: h1 fp32 NHWC [0..16.77M) | om1 pool[0..) | big: om1 19.27M
    // stage2: h1b bf16 pool[0..8.39M) | om2 wsf+8.39M
    // stage3: skip2t bf16 wsf[0..4.19M) | om3 pool+8.39M | kp wsf+8.39M
    // residuals: hb bf16 wsf[0..2.10M) | y1b bf16 wsf[2.10M..4.19M) |
    //            y1 pool[0..4.19M) | kp wsf+8.39M
    float*  wsf    = (float*)d_ws;
    float*  h1     = wsf;
    float*  om2    = wsf + 8388608;
    ush*    skip2t = (ush*)wsf;
    ush*    hb     = (ush*)wsf;
    ush*    y1b    = (ush*)(wsf + 2097152);
    float*  kp     = wsf + 8388608;
    float*  pool   = wsf + 16777216;
    float*  om1    = pool;
    ush*    h1b    = (ush*)pool;
    float*  om3    = pool + 8388608;
    float*  y1     = pool;

    const bool big = ws_size >= (size_t)150863872;   // 37,715,968 floats
    const size_t wprep_off = big ? 19267584 : 9633792;
    ush*    wprep  = (ush*)(pool + wprep_off);
    float2* Pst    = (float2*)(pool + wprep_off + 1638400);

    // ---- Weight prep
    {
        PrepAll pd;
        const float* srcs[NWT] = {w_off1, w1, w_off2, w2, w_off3, w3,
                                  rwa[0], rwb[0], rwa[1], rwb[1]};
        const int Ms  [NWT] = {147, 64, 48, 128, 48, 256, 256, 256, 256, 256};
        const int Kts [NWT] = {147, 196, 1024, 1024, 2048, 2048, 2304, 2304, 2304, 2304};
        const int KTs [NWT] = {192, 256, 1024, 1024, 2048, 2048, 2304, 2304, 2304, 2304};
        const int Mbs [NWT] = {128, 64, 64, 128, 64, 128, 128, 128, 128, 128};
        const int sKs [NWT] = {147, 147, 1024, 1024, 2048, 2048, 2304, 2304, 2304, 2304};
        const int prm [NWT] = {0, 1, 2, 2, 2, 2, 2, 2, 2, 2};
        const int cns [NWT] = {3, 3, 64, 64, 128, 128, 256, 256, 256, 256};
        int sg = 0;
        pd.startG[0] = 0;
        for (int i = 0; i < NWT; ++i) {
            pd.src[i] = srcs[i];
            pd.M[i] = Ms[i]; pd.Ktot[i] = Kts[i]; pd.KT[i] = KTs[i];
            pd.Mblk[i] = Mbs[i]; pd.srcK[i] = sKs[i]; pd.perm[i] = prm[i];
            pd.cin[i] = cns[i];
            pd.dstOff[i] = (unsigned)sg * 8u;
            int mb = (Ms[i] + Mbs[i] - 1) / Mbs[i];
            sg += mb * (KTs[i] >> 6) * Mbs[i] * 8;
            pd.startG[i + 1] = sg;
        }
        prep_all_k<<<dim3((sg + 255) / 256), 256, 0, stream>>>(pd, wprep);
    }
    const ush* pw_off1 = wprep + 0;
    const ush* pw1     = wprep + 49152;
    const ush* pw_off2 = wprep + 65536;
    const ush* pw2     = wprep + 131072;
    const ush* pw_off3 = wprep + 262144;
    const ush* pw3     = wprep + 393216;
    const ush* prwa[2] = {wprep + 917504,  wprep + 2097152};
    const ush* prwb[2] = {wprep + 1507328, wprep + 2686976};

    // ---- Stage 1: 7x7 s1 p3, 3 -> 64ch @128x128; h1 written NHWC fp32
    if (big) {
        for (int c = 0; c < 2; ++c) {
            const float* xc = x + (size_t)c * 8 * 3 * 16384;
            conv_mfma<3,7,7,1,3,128,128,128,128,0,2,0,1,0,0,1><<<dim3(256, 2, 8), 256, 0, stream>>>(
                pw_off1, xc, nullptr, b_off1, om1, 147);
            conv_mfma<3,7,7,1,3,128,128,128,128,2,1,1,1,0,1,1><<<dim3(256, 1, 8), 256, 0, stream>>>(
                pw1, xc, om1, b1, h1 + (size_t)c * 8 * 16384 * 64, 64);
        }
    } else {
        for (int c = 0; c < 4; ++c) {
            const float* xc = x + (size_t)c * 4 * 3 * 16384;
            conv_mfma<3,7,7,1,3,128,128,128,128,0,2><<<dim3(256, 2, 4), 256, 0, stream>>>(
                pw_off1, xc, nullptr, b_off1, om1, 147);
            conv_mfma<3,7,7,1,3,128,128,128,128,2,1,1,1,0,1><<<dim3(256, 1, 4), 256, 0, stream>>>(
                pw1, xc, om1, b1, h1 + (size_t)c * 4 * 16384 * 64, 64);
        }
    }
    in_stats_nhwc<<<dim3(16, 16), 256, 0, stream>>>(h1, Pst, 16384);
    in_norm_nhwc_bf16<<<dim3(16, 64), 256, 0, stream>>>(Pst, h1, h1b, 16384);

    // ---- Stage 2: 4x4 s2 p1, 64 -> 128ch @64x64 (NHWC bf16 input, z-swizzle)
    conv_mfma<64,4,4,2,1,128,128,64,64,0,1,0,1,1,0,1><<<dim3(64, 1, 16), 256, 0, stream>>>(
        pw_off2, (const float*)h1b, nullptr, b_off2, om2, 48);
    conv_mfma<64,4,4,2,1,128,128,64,64,2,2,0,1,1,0,1><<<dim3(64, 1, 16), 256, 0, stream>>>(
        pw2, (const float*)h1b, om2, b2, skip2, 128);
    instnorm_k<true,false,false><<<16 * 128, 256, 0, stream>>>(skip2, skip2, nullptr, 4096);
    transpose_chw_hwc_bf16<<<dim3(64, 2, 16), 256, 0, stream>>>(skip2, skip2t, 128, 4096);

    // ---- Stage 3: 4x4 s2 p1, 128 -> 256ch @32x32 (NHWC bf16, K-split, z-swz)
    conv_mfma<128,4,4,2,1,64,64,32,32,0,1,0,4,1,0,1><<<dim3(16, 4, 16), 256, 0, stream>>>(
        pw_off3, (const float*)skip2t, nullptr, b_off3, kp, 48);
    reduce_bias_k<4><<<16 * 48, 256, 0, stream>>>(kp, 786432, b_off3, om3, 48, 1024);
    conv_mfma<128,4,4,2,1,64,64,32,32,2,2,0,2,1,0,1><<<dim3(16, 4, 16), 256, 0, stream>>>(
        pw3, (const float*)skip2t, om3, b3, kp, 256);
    reduce_in_k<2,true,true,false><<<16 * 256, 256, 0, stream>>>(
        kp, 4194304, b3, skip3, h_out, 256);

    // ---- Residual blocks: reflect 3x3, 256ch @32x32 — NHWC bf16 inputs
    // (BP_L1 trivial-copy B-stage), fused reduce+instnorm, NCHW->NHWC shadows.
    transpose_chw_hwc_bf16<<<dim3(16, 4, 16), 256, 0, stream>>>(h_out, hb, 256, 1024);
    for (int r = 0; r < 2; ++r) {
        conv_mfma<256,3,3,1,1,32,32,32,32,1,2,0,2,1,0,1><<<dim3(16, 4, 16), 256, 0, stream>>>(
            prwa[r], (const float*)hb, nullptr, rba[r], kp, 256);
        reduce_in_k<2,true,false,false><<<16 * 256, 256, 0, stream>>>(
            kp, 4194304, rba[r], y1, nullptr, 256);
        transpose_chw_hwc_bf16<<<dim3(16, 4, 16), 256, 0, stream>>>(y1, y1b, 256, 1024);
        conv_mfma<256,3,3,1,1,32,32,32,32,1,2,0,2,1,0,1><<<dim3(16, 4, 16), 256, 0, stream>>>(
            prwb[r], (const float*)y1b, nullptr, rbb[r], kp, 256);
        reduce_in_k<2,false,false,true><<<16 * 256, 256, 0, stream>>>(
            kp, 4194304, rbb[r], h_out, nullptr, 256);
        if (r == 0)
            transpose_chw_hwc_bf16<<<dim3(16, 4, 16), 256, 0, stream>>>(h_out, hb, 256, 1024);
    }
}

// Round 11
// 739.872 us; speedup vs baseline: 1.3064x; 1.1016x over previous
//
#include <hip/hip_runtime.h>
#include <math.h>

typedef __attribute__((ext_vector_type(8))) short short8;
typedef __attribute__((ext_vector_type(16))) short short16;
typedef __attribute__((ext_vector_type(4))) short sh4;
typedef __attribute__((ext_vector_type(4))) float floatx4;
typedef __attribute__((ext_vector_type(2))) _Float16 half2v;
typedef unsigned short ush;

__device__ __forceinline__ ush f2bf(float f) {
    unsigned u = __builtin_bit_cast(unsigned, f);
    u += 0x7FFFu + ((u >> 16) & 1u);   // RNE
    return (ush)(u >> 16);
}
__device__ __forceinline__ float bf2f(short s) {
    return __builtin_bit_cast(float, ((unsigned)(ush)s) << 16);
}

// ---------------------------------------------------------------------------
// Weights pre-converted ONCE per launch into bf16 tiles in the EXACT swizzled
// LDS image (R7). perm=1: stage-1 main k = r*4+ci (pad ci==3). perm=2:
// k = r*CIN + ci (NHWC convs: one tap r per 64-k step, contiguous channels).
// ---------------------------------------------------------------------------
#define NWT 10
struct PrepAll {
    const float* src[NWT];
    unsigned int dstOff[NWT];
    int M[NWT], Ktot[NWT], KT[NWT], Mblk[NWT], srcK[NWT], perm[NWT], cin[NWT];
    int startG[NWT + 1];
};

__global__ __launch_bounds__(256) void prep_all_k(PrepAll d, ush* __restrict__ P)
{
    const int t = blockIdx.x * 256 + threadIdx.x;
    if (t >= d.startG[NWT]) return;
    int wi = 0;
#pragma unroll
    for (int i = 1; i < NWT; ++i) wi += (t >= d.startG[i]);
    const int g8   = t - d.startG[wi];
    const int Mblk = d.Mblk[wi];
    const int ksC  = d.KT[wi] >> 6;
    const int g    = g8 & 7;
    int rest = g8 >> 3;
    const int row = rest % Mblk; rest /= Mblk;
    const int ks  = rest % ksC;
    const int mb  = rest / ksC;
    const int kchunk = g ^ (row & 7);
    const int gm  = mb * Mblk + row;
    const int M = d.M[wi], Ktot = d.Ktot[wi], srcK = d.srcK[wi];
    const int prm = d.perm[wi], cin = d.cin[wi];
    const float* __restrict__ src = d.src[wi];
    short8 v;
#pragma unroll
    for (int j = 0; j < 8; ++j) {
        int gk = ks * 64 + kchunk * 8 + j;
        bool ok = (gm < M) && (gk < Ktot);
        int gs = gk;
        if (prm == 1) { int ci = gk & 3, rr = gk >> 2; ok = ok && (ci < 3); gs = ci * 49 + rr; }
        if (prm == 2) { int ci = gk % cin, rr = gk / cin; gs = ci * (Ktot / cin) + rr; }
        float f = ok ? src[(size_t)gm * srcK + gs] : 0.f;
        v[j] = (short)f2bf(f);
    }
    *(short8*)(P + d.dstOff[wi] + (size_t)g8 * 8) = v;
}

// Implicit-GEMM conv on bf16 MFMA. MODE 0 zero-pad / 1 reflect / 2 deform.
// Tile BM=64*MT, BN=64, BK=64; 256 threads = 4 waves.
// R14: counted-vmcnt pipeline for BP_L2. R15: PIPE=BP_L2 only.
// R16: BP_L1 NHWC reflect (residuals), trivial-copy B-stage.
// R17: LAYT B-stage thread remap bn2=tid>>2, bkc=tid&3 — 4 consecutive lanes
// read 4 consecutive 32B slices of ONE pixel record, so each B-load wave-inst
// touches 16 contiguous 128B segments instead of 64 scattered 32B ones
// (VMEM request-issue was the 13.8k-cy/k-step budget hole; ~4x fewer slots).
// Same (bn2,bkc) coverage; LDS write pattern identical; meta reads broadcast.
template<int CIN,int KH,int KW,int STR,int PAD,int H,int W,int HO,int WO,
         int MODE,int MT,int PERM=0,int NKS=1,int LAYT=0,int ONHWC=0,int ZSWZ=0>
__global__ __launch_bounds__(256) void conv_mfma(
    const ush* __restrict__ Aprep,
    const float* __restrict__ X,      // NCHW fp32, or NHWC bf16 when LAYT
    const float* __restrict__ OM,     // [Z][3*Kk][HO][WO] (deform only)
    const float* __restrict__ bias,
    float* __restrict__ Out,          // [Z][M][HO*WO] (or NKS partials / NHWC)
    int M)
{
    constexpr int Kk   = KH*KW;
    constexpr int Ktot = PERM == 1 ? 4*Kk : CIN*Kk;
    constexpr int HWc  = H*W;
    constexpr int HOWO = HO*WO;
    constexpr int KT   = (Ktot + 63) & ~63;
    constexpr int KSC  = KT >> 6;
    constexpr int KSLICE = KT / NKS;
    constexpr bool KGUARD = (Ktot % 64 != 0);
    // live B-path selectors
    constexpr bool BP_L2  = LAYT && (MODE == 2);            // NHWC bf16 deform
    constexpr bool BP_L0  = LAYT && (MODE == 0);            // NHWC bf16 zero-pad
    constexpr bool BP_L1  = LAYT && (MODE == 1);            // NHWC bf16 reflect
    constexpr bool BP_M2P = (MODE == 2) && (PERM == 1);     // stage-1 deform
    constexpr bool BP_LUT = !LAYT && (MODE == 1 || MODE == 0); // NCHW im2col
    static_assert(BP_L2 || BP_L0 || BP_L1 || BP_M2P || BP_LUT, "");
    constexpr bool PIPE  = BP_L2;                           // counted-vmcnt loop
    constexpr bool META2 = BP_L2;                           // packed deform meta
    constexpr bool MLUTB = BP_L0 || BP_L1 || BP_LUT;        // idx LUT
    constexpr int KPAD = (Kk % 2 == 0) ? Kk + 1 : Kk;
    static_assert(KT % (64 * NKS) == 0, "");
    static_assert(PERM != 1 || (MODE == 2 && CIN == 3 && Kk == 49), "");
    static_assert(!LAYT || (CIN % 64 == 0 && (Kk == 16 || MODE == 1)), "");
    static_assert(!ONHWC || (MT == 1 && NKS == 1 && !PIPE), "");

    // ---- optional XCD-locality remap (bijective; needs gz%8==0, total%8==0)
    int bx = blockIdx.x, by = blockIdx.y, bz = blockIdx.z;
    if constexpr (ZSWZ) {
        const int gx = gridDim.x, gy = gridDim.y, gz = gridDim.z;
        const int gxy = gx * gy;
        int flat = bx + gx * (by + gy * bz);
        int xcd = flat & 7, rank = flat >> 3;
        int zloc = rank / gxy, rem = rank - zloc * gxy;
        bz = xcd * (gz >> 3) + zloc;
        by = rem / gx; bx = rem - (rem / gx) * gx;
    }

    const int z = bz;
    const float* __restrict__ Xb  = LAYT ? nullptr : (X + (size_t)z * CIN * HWc);
    const ush*   __restrict__ Xh  = LAYT ? ((const ush*)X + (size_t)z * CIN * HWc) : nullptr;
    const float* __restrict__ OMb = (MODE == 2) ? (OM + (size_t)z * 3 * Kk * HOWO) : nullptr;

    const int mtiles = gridDim.y / NKS;
    const int my = (NKS > 1) ? (by % mtiles) : by;
    const int ks = (NKS > 1) ? (by / mtiles) : 0;

    float* __restrict__ Outb;
    if constexpr (NKS > 1) {
        const size_t PS = (size_t)gridDim.z * (size_t)M * HOWO;
        Outb = Out + (size_t)ks * PS + (size_t)z * (size_t)M * HOWO;
    } else {
        Outb = Out + (size_t)z * (size_t)M * HOWO;
    }

    const int n0   = bx * 64;
    const int tid  = threadIdx.x;
    const int lane = tid & 63;
    const int wave = tid >> 6;
    const int quad = lane >> 4;
    const int l16  = lane & 15;

    // R17: LAYT paths -> 4 consecutive lanes per pixel record (coalesced);
    // non-LAYT keep lane = pixel (coalesced for LUT gathers by construction).
    const int bn2 = LAYT ? (tid >> 2) : (tid & 63);
    const int bkc = LAYT ? (tid & 3)  : (tid >> 6);
    const int gn2 = n0 + bn2;
    const int ho2 = gn2 / WO, wo2 = gn2 % WO;

    // ---- shared memory carve (Ts for ONHWC aliases As+Bs)
    constexpr int AB_BYTES = 64*MT*64*2 + 64*64*2;
    constexpr int TS_BYTES = ONHWC ? 64*64*4 : 0;
    constexpr int BASE_BYTES = AB_BYTES > TS_BYTES ? AB_BYTES : TS_BYTES;
    constexpr int MIB_OFF = BASE_BYTES;
    constexpr int MWH_OFF = MIB_OFF + (META2 ? 64*KPAD*4 : 0);
    constexpr int MI0_OFF = MWH_OFF + (META2 ? 64*KPAD*8 : 0);
    constexpr int SMEM_TOT = MI0_OFF + (MLUTB ? 64*KPAD*4 : 0);
    __shared__ __align__(16) char smem[SMEM_TOT];
    ush (*As)[64] = reinterpret_cast<ush(*)[64]>(smem);
    ush (*Bs)[64] = reinterpret_cast<ush(*)[64]>(smem + 64*MT*64*2);
    int*   MIb = reinterpret_cast<int*>(smem + MIB_OFF);
    uint2* MWh = reinterpret_cast<uint2*>(smem + MWH_OFF);
    int*   MI0 = reinterpret_cast<int*>(smem + MI0_OFF);
    float* Ts  = reinterpret_cast<float*>(smem);

    // ---- one-time LDS meta (deform Kk==16). n = e&63 -> coalesced OM reads.
    if constexpr (META2) {
        for (int e = tid; e < 64 * Kk; e += 256) {
            int n = e & 63, r = e >> 6;
            int gn = n0 + n, ho = gn / WO, wo = gn % WO;
            int ky = r / KW, kx = r % KW;
            float offy = OMb[(size_t)(2 * r) * HOWO + gn];
            float offx = OMb[(size_t)(2 * r + 1) * HOWO + gn];
            float ml   = OMb[(size_t)(2 * Kk + r) * HOWO + gn];
            float mask = 1.f / (1.f + expf(-ml));
            float ys = (float)(ho * STR - PAD + ky) + offy;
            float xs = (float)(wo * STR - PAD + kx) + offx;
            float y0f = floorf(ys), x0f = floorf(xs);
            float dy = ys - y0f, dx = xs - x0f;
            int y0 = (int)y0f, x0 = (int)x0f;
            int yc0 = min(max(y0, 0), H - 1);
            int yc1 = min(max(y0 + 1, 0), H - 1);
            int xc0 = min(max(x0, 0), W - 1);
            int xc1 = min(max(x0 + 1, 0), W - 1);
            bool y0ok = (y0 >= 0) & (y0 < H), y1ok = (y0 + 1 >= 0) & (y0 + 1 < H);
            bool x0ok = (x0 >= 0) & (x0 < W), x1ok = (x0 + 1 >= 0) & (x0 + 1 < W);
            half2v w01, w23;
            w01[0] = (_Float16)((y0ok && x0ok) ? (1.f - dy) * (1.f - dx) * mask : 0.f);
            w01[1] = (_Float16)((y0ok && x1ok) ? (1.f - dy) * dx * mask : 0.f);
            w23[0] = (_Float16)((y1ok && x0ok) ? dy * (1.f - dx) * mask : 0.f);
            w23[1] = (_Float16)((y1ok && x1ok) ? dy * dx * mask : 0.f);
            MIb[n * KPAD + r] = (yc0 * W + xc0) | ((xc1 - xc0) << 24) | ((yc1 - yc0) << 25);
            MWh[n * KPAD + r] = make_uint2(__builtin_bit_cast(unsigned, w01),
                                           __builtin_bit_cast(unsigned, w23));
        }
        __syncthreads();
    }
    if constexpr (MLUTB) {
        for (int e = tid; e < 64 * Kk; e += 256) {
            int n = e & 63, r = e >> 6;
            int gn = n0 + n, ho = gn / WO, wo = gn % WO;
            int ky = r / KW, kx = r % KW;
            int idx;
            if constexpr (MODE == 0) {
                int iy = ho * STR - PAD + ky;
                int ix = wo * STR - PAD + kx;
                idx = (iy >= 0 && iy < H && ix >= 0 && ix < W) ? iy * W + ix : -1;
            } else {
                int iy = ho - PAD + ky; iy = iy < 0 ? -iy : (iy >= H ? 2 * H - 2 - iy : iy);
                int ix = wo - PAD + kx; ix = ix < 0 ? -ix : (ix >= W ? 2 * W - 2 - ix : ix);
                idx = iy * W + ix;
            }
            MI0[n * KPAD + r] = idx;
        }
        __syncthreads();
    }

    floatx4 acc[MT][4];
#pragma unroll
    for (int s = 0; s < MT; ++s)
#pragma unroll
        for (int t = 0; t < 4; ++t) acc[s][t] = (floatx4){0.f, 0.f, 0.f, 0.f};

    const int kbeg = ks * KSLICE, kend = kbeg + KSLICE;

    // A-DMA helper (issues 2*MT global_load_lds, vmem ops)
    auto ADMA = [&](int k0) {
        const ush* At =
            Aprep + ((size_t)my * KSC + (k0 >> 6)) * (size_t)(64 * MT * 64);
#pragma unroll
        for (int c = 0; c < 2 * MT; ++c) {
            const int chunk = c * 4 + wave;
            __builtin_amdgcn_global_load_lds(
                (const __attribute__((address_space(1))) void*)(At + (size_t)chunk * 512 + lane * 8),
                (__attribute__((address_space(3))) void*)(&As[0][0] + chunk * 512),
                16, 0, 0);
        }
    };

    auto MFMA_PHASE = [&]() {
        const int mrow = wave * 16 + l16;
#pragma unroll
        for (int kk = 0; kk < 2; ++kk) {
            const int kg = kk * 4 + quad;
            short8 a[MT];
#pragma unroll
            for (int s = 0; s < MT; ++s)
                a[s] = *(const short8*)&As[s * 64 + mrow][((kg ^ (mrow & 7)) * 8)];
#pragma unroll
            for (int t = 0; t < 4; ++t) {
                const int ncol = t * 16 + l16;
                short8 b = *(const short8*)&Bs[ncol][((kg ^ (ncol & 7)) * 8)];
#pragma unroll
                for (int s = 0; s < MT; ++s)
                    acc[s][t] = __builtin_amdgcn_mfma_f32_16x16x32_bf16(a[s], b, acc[s][t], 0, 0, 0);
            }
        }
    };

    if constexpr (PIPE) {
        // ---- counted-vmcnt pipeline (NHWC bf16 deform)
        short16 pb0, pb1, pb2, pb3;
        unsigned pwx = 0, pwy = 0;

        auto LOADB = [&](int k0) {
            const int r   = k0 / CIN;              // wave-uniform
            const int ci0 = (k0 % CIN) + bkc * 16;
            int packed = MIb[bn2 * KPAD + r];      // broadcast across 4 lanes
            uint2 ww   = MWh[bn2 * KPAD + r];
            pwx = ww.x; pwy = ww.y;
            int base = packed & 0xFFFFFF;
            int dX = ((packed >> 24) & 1) ? CIN : 0;
            int dY = ((packed >> 25) & 1) ? W * CIN : 0;
            const ush* p00 = Xh + (size_t)base * CIN + ci0;
            pb0 = *(const short16*)(p00);
            pb1 = *(const short16*)(p00 + dX);
            pb2 = *(const short16*)(p00 + dY);
            pb3 = *(const short16*)(p00 + dY + dX);
        };
        auto CONVB = [&](short8& s0, short8& s1) {
            half2v w01 = __builtin_bit_cast(half2v, pwx);
            half2v w23 = __builtin_bit_cast(half2v, pwy);
            float W00 = (float)w01[0], W01 = (float)w01[1];
            float W10 = (float)w23[0], W11 = (float)w23[1];
#pragma unroll
            for (int j = 0; j < 8; ++j) {
                s0[j] = (short)f2bf(W00 * bf2f(pb0[j]) + W01 * bf2f(pb1[j])
                                  + W10 * bf2f(pb2[j]) + W11 * bf2f(pb3[j]));
                s1[j] = (short)f2bf(W00 * bf2f(pb0[8 + j]) + W01 * bf2f(pb1[8 + j])
                                  + W10 * bf2f(pb2[8 + j]) + W11 * bf2f(pb3[8 + j]));
            }
        };

        LOADB(kbeg);
        for (int k0 = kbeg; k0 < kend; k0 += 64) {
            ADMA(k0);
            asm volatile("" ::: "memory");          // IR fence: B-loads stay below
            __builtin_amdgcn_sched_barrier(0);      // MIR fence

            short8 s0, s1;
            CONVB(s0, s1);                          // compiler waits pb* itself
            const bool more = (k0 + 64 < kend);
            if (more) LOADB(k0 + 64);               // 8 vmem ops, youngest
            const int g0 = (bkc * 2)     ^ (bn2 & 7);
            const int g1 = (bkc * 2 + 1) ^ (bn2 & 7);
            *(short8*)&Bs[bn2][g0 * 8] = s0;
            *(short8*)&Bs[bn2][g1 * 8] = s1;

            // barrier #1: ds_writes visible + A-DMA landed; B(k+1) stays in flight
            if (more)
                asm volatile("s_waitcnt vmcnt(8) lgkmcnt(0)" ::: "memory");
            else
                asm volatile("s_waitcnt vmcnt(0) lgkmcnt(0)" ::: "memory");
            __builtin_amdgcn_sched_barrier(0);
            __builtin_amdgcn_s_barrier();
            __builtin_amdgcn_sched_barrier(0);
            asm volatile("" ::: "memory");

            MFMA_PHASE();

            // barrier #2: own ds_reads complete before Bs/As overwritten
            asm volatile("s_waitcnt lgkmcnt(0)" ::: "memory");
            __builtin_amdgcn_sched_barrier(0);
            __builtin_amdgcn_s_barrier();
            __builtin_amdgcn_sched_barrier(0);
            asm volatile("" ::: "memory");
        }
    } else {
        // ---- plain loop (__syncthreads), inline staging
        for (int k0 = kbeg; k0 < kend; k0 += 64) {
            ADMA(k0);
            {
                short8 s0, s1;
                if constexpr (BP_L0) {
                    // NHWC bf16 zero-pad: direct copy, one 32B slice
                    const int r   = k0 / CIN;
                    const int ci0 = (k0 % CIN) + bkc * 16;
                    int idx = MI0[bn2 * KPAD + r];
                    const ush* p0 = Xh + (size_t)(idx < 0 ? 0 : idx) * CIN + ci0;
                    short16 v = *(const short16*)p0;
#pragma unroll
                    for (int j = 0; j < 8; ++j) { s0[j] = v[j]; s1[j] = v[8 + j]; }
                    if (idx < 0) {
#pragma unroll
                        for (int j = 0; j < 8; ++j) { s0[j] = 0; s1[j] = 0; }
                    }
                } else if constexpr (BP_L1) {
                    // NHWC bf16 reflect-pad: idx always valid, pure copy
                    const int r   = k0 / CIN;
                    const int ci0 = (k0 % CIN) + bkc * 16;
                    int idx = MI0[bn2 * KPAD + r];
                    const ush* p0 = Xh + (size_t)idx * CIN + ci0;
                    short16 v = *(const short16*)p0;
#pragma unroll
                    for (int j = 0; j < 8; ++j) { s0[j] = v[j]; s1[j] = v[8 + j]; }
                } else if constexpr (BP_M2P) {
                    // stage-1 deform, perm'd K: 4 slots share one r (3 planes + pad)
                    ush tmp[16];
                    const int kbase = k0 + bkc * 16;
                    const int rbase = kbase >> 2;
#pragma unroll
                    for (int u = 0; u < 4; ++u) {
                        const int r = rbase + u;
                        float v0 = 0.f, v1 = 0.f, v2 = 0.f;
                        if (r < Kk) {
                            const int ky = r / KW, kx = r - ky * KW;
                            float offy = OMb[(size_t)(2 * r) * HOWO + gn2];
                            float offx = OMb[(size_t)(2 * r + 1) * HOWO + gn2];
                            float ml   = OMb[(size_t)(2 * Kk + r) * HOWO + gn2];
                            float mask = 1.f / (1.f + expf(-ml));
                            float ys = (float)(ho2 * STR - PAD + ky) + offy;
                            float xs = (float)(wo2 * STR - PAD + kx) + offx;
                            float y0f = floorf(ys), x0f = floorf(xs);
                            float dy = ys - y0f, dx = xs - x0f;
                            int y0 = (int)y0f, x0 = (int)x0f;
                            int yc0 = min(max(y0, 0), H - 1);
                            int yc1 = min(max(y0 + 1, 0), H - 1);
                            int xc0 = min(max(x0, 0), W - 1);
                            int xc1 = min(max(x0 + 1, 0), W - 1);
                            bool y0ok = (y0 >= 0) & (y0 < H), y1ok = (y0 + 1 >= 0) & (y0 + 1 < H);
                            bool x0ok = (x0 >= 0) & (x0 < W), x1ok = (x0 + 1 >= 0) & (x0 + 1 < W);
                            float w00 = (y0ok && x0ok) ? (1.f - dy) * (1.f - dx) * mask : 0.f;
                            float w01 = (y0ok && x1ok) ? (1.f - dy) * dx * mask : 0.f;
                            float w10 = (y1ok && x0ok) ? dy * (1.f - dx) * mask : 0.f;
                            float w11 = (y1ok && x1ok) ? dy * dx * mask : 0.f;
                            int base = yc0 * W + xc0;
                            int dxs  = xc1 - xc0;
                            int dys  = (yc1 - yc0) ? W : 0;
                            float cc[12];
#pragma unroll
                            for (int ci = 0; ci < 3; ++ci) {
                                const float* img = Xb + (size_t)ci * HWc;
                                cc[ci * 4 + 0] = img[base];
                                cc[ci * 4 + 1] = img[base + dxs];
                                cc[ci * 4 + 2] = img[base + dys];
                                cc[ci * 4 + 3] = img[base + dys + dxs];
                            }
                            v0 = w00 * cc[0] + w01 * cc[1] + w10 * cc[2]  + w11 * cc[3];
                            v1 = w00 * cc[4] + w01 * cc[5] + w10 * cc[6]  + w11 * cc[7];
                            v2 = w00 * cc[8] + w01 * cc[9] + w10 * cc[10] + w11 * cc[11];
                        }
                        tmp[u * 4 + 0] = f2bf(v0);
                        tmp[u * 4 + 1] = f2bf(v1);
                        tmp[u * 4 + 2] = f2bf(v2);
                        tmp[u * 4 + 3] = 0;
                    }
#pragma unroll
                    for (int j = 0; j < 8; ++j) { s0[j] = (short)tmp[j]; s1[j] = (short)tmp[8 + j]; }
                } else {
                    // BP_LUT: batched idx reads then unconditional clamped gathers
                    ush tmp[16];
                    int idxs[16];
                    float raw[16];
#pragma unroll
                    for (int j = 0; j < 16; ++j) {
                        int gk = k0 + bkc * 16 + j;
                        int ci = gk / Kk;
                        int r  = gk - ci * Kk;
                        int idx = MI0[bn2 * KPAD + r];
                        if (KGUARD && gk >= Ktot) idx = -1;
                        idxs[j] = idx;
                    }
#pragma unroll
                    for (int j = 0; j < 16; ++j) {
                        int gk = k0 + bkc * 16 + j;
                        int ci = gk / Kk;
                        raw[j] = Xb[(size_t)ci * HWc + (idxs[j] < 0 ? 0 : idxs[j])];
                    }
#pragma unroll
                    for (int j = 0; j < 16; ++j)
                        tmp[j] = idxs[j] < 0 ? (ush)0 : f2bf(raw[j]);
#pragma unroll
                    for (int j = 0; j < 8; ++j) { s0[j] = (short)tmp[j]; s1[j] = (short)tmp[8 + j]; }
                }
                const int g0 = (bkc * 2)     ^ (bn2 & 7);
                const int g1 = (bkc * 2 + 1) ^ (bn2 & 7);
                *(short8*)&Bs[bn2][g0 * 8] = s0;
                *(short8*)&Bs[bn2][g1 * 8] = s1;
            }
            __syncthreads();
            MFMA_PHASE();
            __syncthreads();
        }
    }

    // ---- epilogue
    if constexpr (ONHWC) {
        // LDS transpose -> coalesced NHWC store (M==64, full tile)
#pragma unroll
        for (int t = 0; t < 4; ++t) {
            int n = t * 16 + l16;
#pragma unroll
            for (int i = 0; i < 4; ++i) {
                int m = wave * 16 + quad * 4 + i;
                Ts[n * 64 + (m ^ ((n & 7) << 3))] = acc[0][t][i] + bias[m];
            }
        }
        __syncthreads();
        float* Outc = Out + ((size_t)z * HOWO + n0) * 64;
        for (int e = tid; e < 1024; e += 256) {
            int n = e >> 4, m4 = (e & 15) * 4;
            float4 v = *(float4*)&Ts[n * 64 + (m4 ^ ((n & 7) << 3))];
            *(float4*)(Outc + n * 64 + m4) = v;
        }
    } else {
#pragma unroll
        for (int s = 0; s < MT; ++s) {
#pragma unroll
            for (int t = 0; t < 4; ++t) {
                const int ng = n0 + t * 16 + l16;
#pragma unroll
                for (int i = 0; i < 4; ++i) {
                    int mg = my * (64 * MT) + s * 64 + wave * 16 + quad * 4 + i;
                    if (mg < M) {
                        float v = acc[s][t][i];
                        if constexpr (NKS == 1) v += bias[mg];
                        Outb[(size_t)mg * HOWO + ng] = v;
                    }
                }
            }
        }
    }
}

// Sum NP partial planes (stride PS) + bias -> out. One block per (z,m) row.
template<int NP>
__global__ __launch_bounds__(256) void reduce_bias_k(
    const float* __restrict__ P, size_t PS, const float* __restrict__ bias,
    float* __restrict__ out, int M, int HOWO)
{
    const int bc = blockIdx.x;
    const int m  = bc % M;
    const float b = bias[m];
    const size_t off = (size_t)bc * HOWO;
    for (int i = threadIdx.x * 4; i < HOWO; i += 1024) {
        float4 a = *(const float4*)(P + off + i);
#pragma unroll
        for (int p = 1; p < NP; ++p) {
            float4 c = *(const float4*)(P + (size_t)p * PS + off + i);
            a.x += c.x; a.y += c.y; a.z += c.z; a.w += c.w;
        }
        a.x += b; a.y += b; a.z += b; a.w += b;
        *(float4*)(out + off + i) = a;
    }
}

// Fused partial-sum + bias + instance-norm for HOWO==1024. One block per
// (z,m) row; values live in registers across stats and normalize.
template<int NP, bool RELU, bool DUAL, bool ADDIN>
__global__ __launch_bounds__(256) void reduce_in_k(
    const float* __restrict__ P, size_t PS, const float* __restrict__ bias,
    float* __restrict__ out, float* __restrict__ out2, int M)
{
    const int bc = blockIdx.x;
    const int m  = bc % M;
    const float b = bias[m];
    const size_t off = (size_t)bc * 1024 + threadIdx.x * 4;
    float4 a = *(const float4*)(P + off);
#pragma unroll
    for (int p = 1; p < NP; ++p) {
        float4 c = *(const float4*)(P + (size_t)p * PS + off);
        a.x += c.x; a.y += c.y; a.z += c.z; a.w += c.w;
    }
    a.x += b; a.y += b; a.z += b; a.w += b;
    float s = a.x + a.y + a.z + a.w;
    float q = a.x * a.x + a.y * a.y + a.z * a.z + a.w * a.w;
    __shared__ float rs[256], rq[256];
    rs[threadIdx.x] = s; rq[threadIdx.x] = q;
    __syncthreads();
    for (int o = 128; o > 0; o >>= 1) {
        if (threadIdx.x < o) { rs[threadIdx.x] += rs[threadIdx.x + o]; rq[threadIdx.x] += rq[threadIdx.x + o]; }
        __syncthreads();
    }
    float mean = rs[0] * (1.f / 1024.f);
    float var  = rq[0] * (1.f / 1024.f) - mean * mean;
    float inv  = rsqrtf(var + 1e-5f);
    a.x = (a.x - mean) * inv; a.y = (a.y - mean) * inv;
    a.z = (a.z - mean) * inv; a.w = (a.w - mean) * inv;
    if (RELU) {
        a.x = fmaxf(a.x, 0.f); a.y = fmaxf(a.y, 0.f);
        a.z = fmaxf(a.z, 0.f); a.w = fmaxf(a.w, 0.f);
    }
    if (ADDIN) {
        float4 o4 = *(const float4*)(out + off);
        o4.x += a.x; o4.y += a.y; o4.z += a.z; o4.w += a.w;
        *(float4*)(out + off) = o4;
    } else {
        *(float4*)(out + off) = a;
        if (DUAL) *(float4*)(out2 + off) = a;
    }
}

// NCHW instance norm (per (b,c) over HW); optional ReLU/dual/add-in. float4.
template<bool RELU, bool DUAL, bool ADDIN>
__global__ __launch_bounds__(256) void instnorm_k(
    const float* __restrict__ in, float* __restrict__ out,
    float* __restrict__ out2, int HW)
{
    const int bc = blockIdx.x;
    const float4* p4 = (const float4*)(in + (size_t)bc * HW);
    const int n4 = HW >> 2;
    float s = 0.f, ss = 0.f;
    for (int i = threadIdx.x; i < n4; i += 256) {
        float4 v = p4[i];
        s  += v.x + v.y + v.z + v.w;
        ss += v.x * v.x + v.y * v.y + v.z * v.z + v.w * v.w;
    }
    __shared__ float rs[256], rq[256];
    rs[threadIdx.x] = s; rq[threadIdx.x] = ss;
    __syncthreads();
    for (int o = 128; o > 0; o >>= 1) {
        if (threadIdx.x < o) { rs[threadIdx.x] += rs[threadIdx.x + o]; rq[threadIdx.x] += rq[threadIdx.x + o]; }
        __syncthreads();
    }
    float mean = rs[0] / (float)HW;
    float var  = rq[0] / (float)HW - mean * mean;
    float inv  = rsqrtf(var + 1e-5f);
    float4* q4  = (float4*)(out + (size_t)bc * HW);
    float4* q24 = DUAL ? (float4*)(out2 + (size_t)bc * HW) : nullptr;
    for (int i = threadIdx.x; i < n4; i += 256) {
        float4 v = p4[i];
        v.x = (v.x - mean) * inv; v.y = (v.y - mean) * inv;
        v.z = (v.z - mean) * inv; v.w = (v.w - mean) * inv;
        if (RELU) {
            v.x = fmaxf(v.x, 0.f); v.y = fmaxf(v.y, 0.f);
            v.z = fmaxf(v.z, 0.f); v.w = fmaxf(v.w, 0.f);
        }
        if (ADDIN) {
            float4 o = q4[i];
            o.x += v.x; o.y += v.y; o.z += v.z; o.w += v.w;
            q4[i] = o;
        } else {
            q4[i] = v;
            if (DUAL) q24[i] = v;
        }
    }
}

// NHWC instance-norm stats: per (z, chunk of 1024 hw) partial s/ss per channel.
__global__ __launch_bounds__(256) void in_stats_nhwc(
    const float* __restrict__ X, float2* __restrict__ P, int HW)
{
    const int z = blockIdx.x, chunk = blockIdx.y;
    const int tid = threadIdx.x;
    const int cg = tid & 15, seg = tid >> 4;
    const int c0 = cg * 4;
    float4 s4 = make_float4(0.f, 0.f, 0.f, 0.f);
    float4 q4 = make_float4(0.f, 0.f, 0.f, 0.f);
    const float* base = X + ((size_t)z * HW + chunk * 1024) * 64;
    for (int hw = seg; hw < 1024; hw += 16) {
        float4 v = *(const float4*)(base + (size_t)hw * 64 + c0);
        s4.x += v.x; s4.y += v.y; s4.z += v.z; s4.w += v.w;
        q4.x += v.x * v.x; q4.y += v.y * v.y; q4.z += v.z * v.z; q4.w += v.w * v.w;
    }
    __shared__ float4 rs[256], rq[256];
    rs[tid] = s4; rq[tid] = q4;
    __syncthreads();
    if (tid < 16) {
        float4 S = rs[tid], Q = rq[tid];
        for (int g = 1; g < 16; ++g) {
            float4 a = rs[g * 16 + tid], b = rq[g * 16 + tid];
            S.x += a.x; S.y += a.y; S.z += a.z; S.w += a.w;
            Q.x += b.x; Q.y += b.y; Q.z += b.z; Q.w += b.w;
        }
        float2* po = P + ((size_t)z * 16 + chunk) * 64 + tid * 4;
        po[0] = make_float2(S.x, Q.x);
        po[1] = make_float2(S.y, Q.y);
        po[2] = make_float2(S.z, Q.z);
        po[3] = make_float2(S.w, Q.w);
    }
}

// NHWC normalize + ReLU, fp32 in -> bf16 out. grid (Z, 64 chunks of 256 hw).
__global__ __launch_bounds__(256) void in_norm_nhwc_bf16(
    const float2* __restrict__ P, const float* __restrict__ X,
    ush* __restrict__ Y, int HW)
{
    const int z = blockIdx.x, chunk = blockIdx.y;
    const int tid = threadIdx.x;
    __shared__ float2 mi[64];
    if (tid < 64) {
        float s = 0.f, q = 0.f;
        for (int g = 0; g < 16; ++g) {
            float2 p = P[((size_t)z * 16 + g) * 64 + tid];
            s += p.x; q += p.y;
        }
        float mean = s / (float)HW;
        float var  = q / (float)HW - mean * mean;
        mi[tid] = make_float2(mean, rsqrtf(var + 1e-5f));
    }
    __syncthreads();
    const float* bi = X + ((size_t)z * HW + chunk * 256) * 64;
    ush* bo = Y + ((size_t)z * HW + chunk * 256) * 64;
    for (int e = tid; e < 4096; e += 256) {
        int c0 = (e & 15) * 4;
        float4 v = *(const float4*)(bi + (size_t)e * 4);
        float2 m0 = mi[c0], m1 = mi[c0 + 1], m2 = mi[c0 + 2], m3 = mi[c0 + 3];
        sh4 o;
        o[0] = (short)f2bf(fmaxf((v.x - m0.x) * m0.y, 0.f));
        o[1] = (short)f2bf(fmaxf((v.y - m1.x) * m1.y, 0.f));
        o[2] = (short)f2bf(fmaxf((v.z - m2.x) * m2.y, 0.f));
        o[3] = (short)f2bf(fmaxf((v.w - m3.x) * m3.y, 0.f));
        *(sh4*)(bo + (size_t)e * 4) = o;
    }
}

// Tiled NCHW fp32 [Z][C][HW] -> NHWC bf16 [Z][HW][C]. grid (HW/64, C/64, Z).
__global__ __launch_bounds__(256) void transpose_chw_hwc_bf16(
    const float* __restrict__ src, ush* __restrict__ dst, int C, int HW)
{
    __shared__ float T[64][65];
    const int z = blockIdx.z, cb = blockIdx.y * 64, hb = blockIdx.x * 64;
    const int tid = threadIdx.x;
    for (int e = tid; e < 1024; e += 256) {
        int c = e >> 4, h4 = (e & 15) * 4;
        float4 v = *(const float4*)(src + ((size_t)z * C + cb + c) * HW + hb + h4);
        T[c][h4] = v.x; T[c][h4 + 1] = v.y; T[c][h4 + 2] = v.z; T[c][h4 + 3] = v.w;
    }
    __syncthreads();
    for (int e = tid; e < 1024; e += 256) {
        int h = e >> 4, c4 = (e & 15) * 4;
        sh4 o;
        o[0] = (short)f2bf(T[c4][h]);     o[1] = (short)f2bf(T[c4 + 1][h]);
        o[2] = (short)f2bf(T[c4 + 2][h]); o[3] = (short)f2bf(T[c4 + 3][h]);
        *(sh4*)(dst + ((size_t)z * HW + hb + h) * C + cb + c4) = o;
    }
}

extern "C" void kernel_launch(void* const* d_in, const int* in_sizes, int n_in,
                              void* d_out, int out_size, void* d_ws, size_t ws_size,
                              hipStream_t stream)
{
    const float* x      = (const float*)d_in[0];
    const float* w_off1 = (const float*)d_in[1];
    const float* b_off1 = (const float*)d_in[2];
    const float* w1     = (const float*)d_in[3];
    const float* b1     = (const float*)d_in[4];
    const float* w_off2 = (const float*)d_in[5];
    const float* b_off2 = (const float*)d_in[6];
    const float* w2     = (const float*)d_in[7];
    const float* b2     = (const float*)d_in[8];
    const float* w_off3 = (const float*)d_in[9];
    const float* b_off3 = (const float*)d_in[10];
    const float* w3     = (const float*)d_in[11];
    const float* b3     = (const float*)d_in[12];
    const float* rwa[2] = {(const float*)d_in[13], (const float*)d_in[17]};
    const float* rba[2] = {(const float*)d_in[14], (const float*)d_in[18]};
    const float* rwb[2] = {(const float*)d_in[15], (const float*)d_in[19]};
    const float* rbb[2] = {(const float*)d_in[16], (const float*)d_in[20]};

    float* out   = (float*)d_out;
    float* h_out = out;                         // [16,256,32,32]
    float* skip2 = out + 4194304;               // [16,128,64,64]
    float* skip3 = out + 4194304 + 8388608;     // [16,256,32,32]

    // workspace (floats), time-multiplexed (identical to R16).
    float*  wsf    = (float*)d_ws;
    float*  h1     = wsf;
    float*  om2    = wsf + 8388608;
    ush*    skip2t = (ush*)wsf;
    ush*    hb     = (ush*)wsf;
    ush*    y1b    = (ush*)(wsf + 2097152);
    float*  kp     = wsf + 8388608;
    float*  pool   = wsf + 16777216;
    float*  om1    = pool;
    ush*    h1b    = (ush*)pool;
    float*  om3    = pool + 8388608;
    float*  y1     = pool;

    const bool big = ws_size >= (size_t)150863872;   // 37,715,968 floats
    const size_t wprep_off = big ? 19267584 : 9633792;
    ush*    wprep  = (ush*)(pool + wprep_off);
    float2* Pst    = (float2*)(pool + wprep_off + 1638400);

    // ---- Weight prep
    {
        PrepAll pd;
        const float* srcs[NWT] = {w_off1, w1, w_off2, w2, w_off3, w3,
                                  rwa[0], rwb[0], rwa[1], rwb[1]};
        const int Ms  [NWT] = {147, 64, 48, 128, 48, 256, 256, 256, 256, 256};
        const int Kts [NWT] = {147, 196, 1024, 1024, 2048, 2048, 2304, 2304, 2304, 2304};
        const int KTs [NWT] = {192, 256, 1024, 1024, 2048, 2048, 2304, 2304, 2304, 2304};
        const int Mbs [NWT] = {128, 64, 64, 128, 64, 128, 128, 128, 128, 128};
        const int sKs [NWT] = {147, 147, 1024, 1024, 2048, 2048, 2304, 2304, 2304, 2304};
        const int prm [NWT] = {0, 1, 2, 2, 2, 2, 2, 2, 2, 2};
        const int cns [NWT] = {3, 3, 64, 64, 128, 128, 256, 256, 256, 256};
        int sg = 0;
        pd.startG[0] = 0;
        for (int i = 0; i < NWT; ++i) {
            pd.src[i] = srcs[i];
            pd.M[i] = Ms[i]; pd.Ktot[i] = Kts[i]; pd.KT[i] = KTs[i];
            pd.Mblk[i] = Mbs[i]; pd.srcK[i] = sKs[i]; pd.perm[i] = prm[i];
            pd.cin[i] = cns[i];
            pd.dstOff[i] = (unsigned)sg * 8u;
            int mb = (Ms[i] + Mbs[i] - 1) / Mbs[i];
            sg += mb * (KTs[i] >> 6) * Mbs[i] * 8;
            pd.startG[i + 1] = sg;
        }
        prep_all_k<<<dim3((sg + 255) / 256), 256, 0, stream>>>(pd, wprep);
    }
    const ush* pw_off1 = wprep + 0;
    const ush* pw1     = wprep + 49152;
    const ush* pw_off2 = wprep + 65536;
    const ush* pw2     = wprep + 131072;
    const ush* pw_off3 = wprep + 262144;
    const ush* pw3     = wprep + 393216;
    const ush* prwa[2] = {wprep + 917504,  wprep + 2097152};
    const ush* prwb[2] = {wprep + 1507328, wprep + 2686976};

    // ---- Stage 1: 7x7 s1 p3, 3 -> 64ch @128x128; h1 written NHWC fp32
    if (big) {
        for (int c = 0; c < 2; ++c) {
            const float* xc = x + (size_t)c * 8 * 3 * 16384;
            conv_mfma<3,7,7,1,3,128,128,128,128,0,2,0,1,0,0,1><<<dim3(256, 2, 8), 256, 0, stream>>>(
                pw_off1, xc, nullptr, b_off1, om1, 147);
            conv_mfma<3,7,7,1,3,128,128,128,128,2,1,1,1,0,1,1><<<dim3(256, 1, 8), 256, 0, stream>>>(
                pw1, xc, om1, b1, h1 + (size_t)c * 8 * 16384 * 64, 64);
        }
    } else {
        for (int c = 0; c < 4; ++c) {
            const float* xc = x + (size_t)c * 4 * 3 * 16384;
            conv_mfma<3,7,7,1,3,128,128,128,128,0,2><<<dim3(256, 2, 4), 256, 0, stream>>>(
                pw_off1, xc, nullptr, b_off1, om1, 147);
            conv_mfma<3,7,7,1,3,128,128,128,128,2,1,1,1,0,1><<<dim3(256, 1, 4), 256, 0, stream>>>(
                pw1, xc, om1, b1, h1 + (size_t)c * 4 * 16384 * 64, 64);
        }
    }
    in_stats_nhwc<<<dim3(16, 16), 256, 0, stream>>>(h1, Pst, 16384);
    in_norm_nhwc_bf16<<<dim3(16, 64), 256, 0, stream>>>(Pst, h1, h1b, 16384);

    // ---- Stage 2: 4x4 s2 p1, 64 -> 128ch @64x64 (NHWC bf16 input, z-swizzle)
    conv_mfma<64,4,4,2,1,128,128,64,64,0,1,0,1,1,0,1><<<dim3(64, 1, 16), 256, 0, stream>>>(
        pw_off2, (const float*)h1b, nullptr, b_off2, om2, 48);
    conv_mfma<64,4,4,2,1,128,128,64,64,2,2,0,1,1,0,1><<<dim3(64, 1, 16), 256, 0, stream>>>(
        pw2, (const float*)h1b, om2, b2, skip2, 128);
    instnorm_k<true,false,false><<<16 * 128, 256, 0, stream>>>(skip2, skip2, nullptr, 4096);
    transpose_chw_hwc_bf16<<<dim3(64, 2, 16), 256, 0, stream>>>(skip2, skip2t, 128, 4096);

    // ---- Stage 3: 4x4 s2 p1, 128 -> 256ch @32x32 (NHWC bf16, K-split, z-swz)
    conv_mfma<128,4,4,2,1,64,64,32,32,0,1,0,4,1,0,1><<<dim3(16, 4, 16), 256, 0, stream>>>(
        pw_off3, (const float*)skip2t, nullptr, b_off3, kp, 48);
    reduce_bias_k<4><<<16 * 48, 256, 0, stream>>>(kp, 786432, b_off3, om3, 48, 1024);
    conv_mfma<128,4,4,2,1,64,64,32,32,2,2,0,2,1,0,1><<<dim3(16, 4, 16), 256, 0, stream>>>(
        pw3, (const float*)skip2t, om3, b3, kp, 256);
    reduce_in_k<2,true,true,false><<<16 * 256, 256, 0, stream>>>(
        kp, 4194304, b3, skip3, h_out, 256);

    // ---- Residual blocks: reflect 3x3, 256ch @32x32 — NHWC bf16 inputs
    // (BP_L1 trivial-copy B-stage), fused reduce+instnorm, NCHW->NHWC shadows.
    transpose_chw_hwc_bf16<<<dim3(16, 4, 16), 256, 0, stream>>>(h_out, hb, 256, 1024);
    for (int r = 0; r < 2; ++r) {
        conv_mfma<256,3,3,1,1,32,32,32,32,1,2,0,2,1,0,1><<<dim3(16, 4, 16), 256, 0, stream>>>(
            prwa[r], (const float*)hb, nullptr, rba[r], kp, 256);
        reduce_in_k<2,true,false,false><<<16 * 256, 256, 0, stream>>>(
            kp, 4194304, rba[r], y1, nullptr, 256);
        transpose_chw_hwc_bf16<<<dim3(16, 4, 16), 256, 0, stream>>>(y1, y1b, 256, 1024);
        conv_mfma<256,3,3,1,1,32,32,32,32,1,2,0,2,1,0,1><<<dim3(16, 4, 16), 256, 0, stream>>>(
            prwb[r], (const float*)y1b, nullptr, rbb[r], kp, 256);
        reduce_in_k<2,false,false,true><<<16 * 256, 256, 0, stream>>>(
            kp, 4194304, rbb[r], h_out, nullptr, 256);
        if (r == 0)
            transpose_chw_hwc_bf16<<<dim3(16, 4, 16), 256, 0, stream>>>(h_out, hb, 256, 1024);
    }
}